// Round 7
// baseline (9396.069 us; speedup 1.0000x reference)
//
#include <hip/hip_runtime.h>
#include <math.h>

// ---------- helpers ----------
__device__ inline int guard_int(int raw, int lo, int hi) {
    if (raw >= lo && raw <= hi) return raw;
    float f = __int_as_float(raw);
    int v = (int)f;
    return (v >= lo && v <= hi) ? v : lo;
}

// ---------- threefry2x32 (JAX-compatible) ----------
__device__ inline void tf2x32(unsigned k0, unsigned k1, unsigned x0, unsigned x1,
                              unsigned& o0, unsigned& o1) {
    unsigned ks2 = k0 ^ k1 ^ 0x1BD11BDAu;
    x0 += k0; x1 += k1;
#define TFR(r) { x0 += x1; x1 = (x1 << (r)) | (x1 >> (32 - (r))); x1 ^= x0; }
    TFR(13) TFR(15) TFR(26) TFR(6)  x0 += k1;  x1 += ks2 + 1u;
    TFR(17) TFR(29) TFR(16) TFR(24) x0 += ks2; x1 += k0 + 2u;
    TFR(13) TFR(15) TFR(26) TFR(6)  x0 += k0;  x1 += k1 + 3u;
    TFR(17) TFR(29) TFR(16) TFR(24) x0 += k1;  x1 += ks2 + 4u;
    TFR(13) TFR(15) TFR(26) TFR(6)  x0 += ks2; x1 += k0 + 5u;
#undef TFR
    o0 = x0; o1 = x1;
}

#define SAMPLE_SCHEME 1   // 1: partitionable threefry (o0^o1); 0: legacy split-halves

// ---------- sentinel / diagnostics (fp32 output now) ----------
__global__ void k_sentinel(float* __restrict__ out, float val, int n) {
    int i = blockIdx.x * 128 + threadIdx.x;
    if (i < n) out[i] = val;
}

__global__ __launch_bounds__(256) void k_scan_f32(const float* __restrict__ p, int n,
                                                  int stage, int* __restrict__ flags) {
    bool bad = false;
    for (int i = blockIdx.x * 256 + threadIdx.x; i < n; i += gridDim.x * 256) {
        unsigned u = __float_as_uint(p[i]);
        if (((u >> 23) & 0xFFu) == 0xFFu) { bad = true; break; }
    }
    if (bad) atomicCAS(&flags[1], 0, stage);
}
__global__ void k_finalize(float* __restrict__ out, int n, const int* __restrict__ flags) {
    if (flags[1] == 0) return;
    float s = -(1024.0f + 32.0f * (float)flags[1]);
    int i = blockIdx.x * 128 + threadIdx.x;
    if (i < n) out[i] = s;
}

// ---------- diffusion categorical sampling -> one-hot X ----------
__global__ __launch_bounds__(256) void k_sample(const float* __restrict__ x,
                                                const int* __restrict__ t_ptr,
                                                float* __restrict__ X) {
    int i = blockIdx.x * 256 + threadIdx.x;
    if (i >= 4096) return;
    int tval = guard_int(t_ptr[0], 0, 500);
    double tf = (double)tval / 500.0;
    const double sc = 0.008;
    const double PI_HALF = 1.5707963267948966;
    double num = cos((tf + sc) / (1.0 + sc) * PI_HALF);
    double den = cos(sc / (1.0 + sc) * PI_HALF);
    float ab = (float)((num * num) / (den * den));
    float phi = (1.0f - ab) / 20.0f;
    float xv[20]; float sx = 0.f;
    for (int j = 0; j < 20; ++j) { xv[j] = x[i * 20 + j]; sx += xv[j]; }
    float best = -1e30f; int bj = 0;
    for (int j = 0; j < 20; ++j) {
        float prob = fmaxf(ab * xv[j] + phi * sx, 0.0f);
        float lp = logf(prob + 1e-9f);
        unsigned m = (unsigned)(i * 20 + j);
        unsigned o0, o1, bits;
#if SAMPLE_SCHEME == 0
        if (m < 40960u) { tf2x32(0u, 42u, m, m + 40960u, o0, o1); bits = o0; }
        else            { tf2x32(0u, 42u, m - 40960u, m, o0, o1); bits = o1; }
#elif SAMPLE_SCHEME == 1
        tf2x32(0u, 42u, 0u, m, o0, o1); bits = o0 ^ o1;
#else
        tf2x32(0u, 42u, 0u, m, o0, o1); bits = o0;
#endif
        float u = __uint_as_float((bits >> 9) | 0x3f800000u) - 1.0f;
        if (u < 1.1754943508222875e-38f) u = 1.1754943508222875e-38f;
        float gmb = -logf(-logf(u));
        float z = lp + gmb;
        if (z > best) { best = z; bj = j; }
    }
    for (int j = 0; j < 20; ++j) X[i * 20 + j] = (j == bj) ? 1.0f : 0.0f;
}

// ---------- small utility kernels ----------
__global__ __launch_bounds__(256) void k_gather_fp(const float* __restrict__ emb,
                                                   const int* __restrict__ idx,
                                                   float* __restrict__ out) {
    int i = blockIdx.x * 256 + threadIdx.x;
    if (i >= 256 * 20) return;
    int a = i / 20, d = i % 20;
    out[i] = emb[(size_t)idx[a] * 20 + d];
}

__global__ __launch_bounds__(256) void k_scatter_bits(const int* __restrict__ ei,
                                                      unsigned* __restrict__ bits) {
    int e = blockIdx.x * 256 + threadIdx.x;
    if (e >= 65536) return;
    int r = ei[e], c = ei[65536 + e];
    atomicOr(&bits[(size_t)r * 128 + (c >> 5)], 1u << (c & 31));
}

__global__ __launch_bounds__(256) void k_embed(const float* __restrict__ embw,
                                               const int* __restrict__ words,
                                               float* __restrict__ H) {
    int idx = blockIdx.x * 256 + threadIdx.x;
    if (idx >= 4096 * 512) return;
    int pos = idx >> 9, d = idx & 511;
    float e = embw[(size_t)words[pos] * 512 + d];
    int i = d >> 1;
    float expo = (2.0f * (float)i) / 512.0f;
    float ang = (float)pos / powf(10000.0f, expo);
    float pe = (d & 1) ? cosf(ang) : sinf(ang);
    H[idx] = e + pe;
}

__global__ __launch_bounds__(256) void k_colmean(const float* __restrict__ M, int R, int C,
                                                 float* __restrict__ out) {
    __shared__ float red[256];
    int c = blockIdx.x, t = threadIdx.x;
    float s = 0.f;
    for (int r = t; r < R; r += 256) s += M[(size_t)r * C + c];
    red[t] = s; __syncthreads();
    for (int o = 128; o; o >>= 1) { if (t < o) red[t] += red[t + o]; __syncthreads(); }
    if (t == 0) out[c] = red[0] / (float)R;
}

// ---------- GEMM (all fp32): C[M,N] = [C +] A@B + bias, optional relu ----------
template<bool RELU, bool ACC>
__global__ __launch_bounds__(256) void k_gemm_nn(int M, int N, int K,
        const float* __restrict__ A, int lda,
        const float* __restrict__ B, int ldb,
        float* __restrict__ C, int ldc,
        const float* __restrict__ bias) {
    __shared__ float As[16][65];
    __shared__ float Bs[16][65];
    int tid = threadIdx.x;
    int tx = tid & 15, ty = tid >> 4;
    int br = blockIdx.y * 64, bc = blockIdx.x * 64;
    float acc[4][4] = {};
    for (int k0 = 0; k0 < K; k0 += 16) {
#pragma unroll
        for (int c0 = 0; c0 < 4; ++c0) {
            int r = (tid >> 4) + c0 * 16, kk = tid & 15;
            int gr = br + r, gk = k0 + kk;
            As[kk][r] = (gr < M && gk < K) ? A[(size_t)gr * lda + gk] : 0.f;
        }
#pragma unroll
        for (int c0 = 0; c0 < 4; ++c0) {
            int col = tid & 63, kk = (tid >> 6) + c0 * 4;
            int gc = bc + col, gk = k0 + kk;
            Bs[kk][col] = (gc < N && gk < K) ? B[(size_t)gk * ldb + gc] : 0.f;
        }
        __syncthreads();
#pragma unroll
        for (int kk = 0; kk < 16; ++kk) {
            float av[4], bv[4];
#pragma unroll
            for (int i2 = 0; i2 < 4; ++i2) av[i2] = As[kk][ty + 16 * i2];
#pragma unroll
            for (int j2 = 0; j2 < 4; ++j2) bv[j2] = Bs[kk][tx + 16 * j2];
#pragma unroll
            for (int i2 = 0; i2 < 4; ++i2)
#pragma unroll
                for (int j2 = 0; j2 < 4; ++j2) acc[i2][j2] += av[i2] * bv[j2];
        }
        __syncthreads();
    }
#pragma unroll
    for (int i2 = 0; i2 < 4; ++i2)
#pragma unroll
        for (int j2 = 0; j2 < 4; ++j2) {
            int r = br + ty + 16 * i2, c = bc + tx + 16 * j2;
            if (r < M && c < N) {
                float v = acc[i2][j2];
                if (ACC) v += C[(size_t)r * ldc + c];
                if (bias) v += bias[c];
                if (RELU) v = fmaxf(v, 0.f);
                C[(size_t)r * ldc + c] = v;
            }
        }
}

// ---------- SpMM from bit-packed adjacency: C[4096,N] = BITS @ B ----------
__global__ __launch_bounds__(256) void k_gemm_bits(int N,
        const unsigned* __restrict__ BITS,
        const float* __restrict__ B, int ldb,
        float* __restrict__ C, int ldc) {
    __shared__ float As[16][65];
    __shared__ float Bs[16][65];
    int tid = threadIdx.x;
    int tx = tid & 15, ty = tid >> 4;
    int br = blockIdx.y * 64, bc = blockIdx.x * 64;
    float acc[4][4] = {};
    for (int k0 = 0; k0 < 4096; k0 += 16) {
#pragma unroll
        for (int c0 = 0; c0 < 4; ++c0) {
            int r = (tid >> 4) + c0 * 16, kk = tid & 15;
            int gk = k0 + kk;
            As[kk][r] = (float)((BITS[(size_t)(br + r) * 128 + (gk >> 5)] >> (gk & 31)) & 1u);
        }
#pragma unroll
        for (int c0 = 0; c0 < 4; ++c0) {
            int col = tid & 63, kk = (tid >> 6) + c0 * 4;
            int gc = bc + col, gk = k0 + kk;
            Bs[kk][col] = (gc < N) ? B[(size_t)gk * ldb + gc] : 0.f;
        }
        __syncthreads();
#pragma unroll
        for (int kk = 0; kk < 16; ++kk) {
            float av[4], bv[4];
#pragma unroll
            for (int i2 = 0; i2 < 4; ++i2) av[i2] = As[kk][ty + 16 * i2];
#pragma unroll
            for (int j2 = 0; j2 < 4; ++j2) bv[j2] = Bs[kk][tx + 16 * j2];
#pragma unroll
            for (int i2 = 0; i2 < 4; ++i2)
#pragma unroll
                for (int j2 = 0; j2 < 4; ++j2) acc[i2][j2] += av[i2] * bv[j2];
        }
        __syncthreads();
    }
#pragma unroll
    for (int i2 = 0; i2 < 4; ++i2)
#pragma unroll
        for (int j2 = 0; j2 < 4; ++j2) {
            int r = br + ty + 16 * i2, c = bc + tx + 16 * j2;
            if (c < N) C[(size_t)r * ldc + c] = acc[i2][j2];
        }
}

// ---------- flash attention (fp32), O written in-place over Q ----------
__global__ __launch_bounds__(256) void k_flash(float* __restrict__ Qg,
                                               const float* __restrict__ Kg,
                                               const float* __restrict__ Vg) {
    __shared__ float Qs[32][128];
    __shared__ float Ks[32][128];
    __shared__ float Vs[32][128];
    __shared__ float Ps[32][33];
    __shared__ float mrow[32], lrow[32], arow[32];
    int tid = threadIdx.x;
    int qb = blockIdx.x * 32;
    int hh = blockIdx.y;
    const float scale = 0.08838834764831845f;   // 1/sqrt(128)
#pragma unroll
    for (int i = 0; i < 4; ++i) {
        int e = tid + i * 256;                  // 32 rows x 32 float4
        int r0 = e >> 5, c4 = e & 31;
        ((float4*)&Qs[r0][0])[c4] = ((const float4*)&Qg[(size_t)(qb + r0) * 512 + hh * 128])[c4];
    }
    if (tid < 32) { mrow[tid] = -INFINITY; lrow[tid] = 0.f; }
    float acc[16];
#pragma unroll
    for (int i = 0; i < 16; ++i) acc[i] = 0.f;
    int r  = tid >> 3;          // owned Q row in tile
    int m4 = (tid & 7) * 4;     // score cols (4/thread)
    int cg = (tid & 7) * 16;    // owned O cols (16/thread)
    __syncthreads();
    for (int kt = 0; kt < 128; ++kt) {
#pragma unroll
        for (int i = 0; i < 4; ++i) {
            int e = tid + i * 256;
            int rr = e >> 5, c4 = e & 31;
            ((float4*)&Ks[rr][0])[c4] = ((const float4*)&Kg[(size_t)(kt * 32 + rr) * 512 + hh * 128])[c4];
            ((float4*)&Vs[rr][0])[c4] = ((const float4*)&Vg[(size_t)(kt * 32 + rr) * 512 + hh * 128])[c4];
        }
        __syncthreads();
        float s0 = 0.f, s1 = 0.f, s2 = 0.f, s3 = 0.f;
        const float4* qp = (const float4*)&Qs[r][0];
        const float4* k0 = (const float4*)&Ks[m4][0];
        const float4* k1 = (const float4*)&Ks[m4 + 1][0];
        const float4* k2 = (const float4*)&Ks[m4 + 2][0];
        const float4* k3 = (const float4*)&Ks[m4 + 3][0];
#pragma unroll
        for (int d = 0; d < 32; ++d) {
            float4 q = qp[d];
            float4 a0 = k0[d], a1 = k1[d], a2 = k2[d], a3 = k3[d];
            s0 += q.x * a0.x + q.y * a0.y + q.z * a0.z + q.w * a0.w;
            s1 += q.x * a1.x + q.y * a1.y + q.z * a1.z + q.w * a1.w;
            s2 += q.x * a2.x + q.y * a2.y + q.z * a2.z + q.w * a2.w;
            s3 += q.x * a3.x + q.y * a3.y + q.z * a3.z + q.w * a3.w;
        }
        Ps[r][m4 + 0] = s0 * scale; Ps[r][m4 + 1] = s1 * scale;
        Ps[r][m4 + 2] = s2 * scale; Ps[r][m4 + 3] = s3 * scale;
        __syncthreads();
        if (tid < 32) {
            float mo = mrow[tid];
            float tm = -INFINITY;
            for (int j = 0; j < 32; ++j) tm = fmaxf(tm, Ps[tid][j]);
            float mn = fmaxf(mo, tm);
            float al = expf(mo - mn);       // first tile: exp(-inf)=0
            float s = 0.f;
            for (int j = 0; j < 32; ++j) { float p = expf(Ps[tid][j] - mn); Ps[tid][j] = p; s += p; }
            mrow[tid] = mn; lrow[tid] = lrow[tid] * al + s; arow[tid] = al;
        }
        __syncthreads();
        float al = arow[r];
#pragma unroll
        for (int i = 0; i < 16; ++i) acc[i] *= al;
        for (int m = 0; m < 32; ++m) {
            float p = Ps[r][m];
            const float4* vp = (const float4*)&Vs[m][cg];
#pragma unroll
            for (int j4 = 0; j4 < 4; ++j4) {
                float4 v = vp[j4];
                acc[j4 * 4 + 0] += p * v.x; acc[j4 * 4 + 1] += p * v.y;
                acc[j4 * 4 + 2] += p * v.z; acc[j4 * 4 + 3] += p * v.w;
            }
        }
        __syncthreads();
    }
    float inv = 1.0f / lrow[r];
    float* op = &Qg[(size_t)(qb + r) * 512 + hh * 128 + cg];
#pragma unroll
    for (int i = 0; i < 16; ++i) op[i] = acc[i] * inv;
}

// ---------- residual add + layernorm (D=512), O may alias A ----------
__global__ __launch_bounds__(256) void k_add_ln(const float* __restrict__ A,
                                                const float* __restrict__ B,
                                                float* __restrict__ O,
                                                const float* __restrict__ g,
                                                const float* __restrict__ b) {
    __shared__ float xr[512];
    __shared__ float red[256];
    int row = blockIdx.x, t = threadIdx.x;
    const float* a = A + (size_t)row * 512;
    const float* bb = B + (size_t)row * 512;
    float ls = 0.f;
    for (int j = t; j < 512; j += 256) { float v = a[j] + bb[j]; xr[j] = v; ls += v; }
    red[t] = ls; __syncthreads();
    for (int o = 128; o; o >>= 1) { if (t < o) red[t] += red[t + o]; __syncthreads(); }
    float mean = red[0] / 512.0f; __syncthreads();
    float lv = 0.f;
    for (int j = t; j < 512; j += 256) { float d = xr[j] - mean; lv += d * d; }
    red[t] = lv; __syncthreads();
    for (int o = 128; o; o >>= 1) { if (t < o) red[t] += red[t + o]; __syncthreads(); }
    float inv = 1.0f / sqrtf(red[0] / 512.0f + 1e-5f);
    float* o_ = O + (size_t)row * 512;
    for (int j = t; j < 512; j += 256)
        o_[j] = (xr[j] - mean) * inv * g[j] + b[j];
}

// ---------- fusion head (fp32 out: cat[80] ++ seq[20]) ----------
__global__ __launch_bounds__(128) void k_fusion(const float* __restrict__ subv,
                                                const float* __restrict__ protv,
                                                const float* __restrict__ seqv,
                                                const float* __restrict__ Wtime,
                                                const float* __restrict__ btime,
                                                const float* __restrict__ Wout,
                                                const float* __restrict__ bout,
                                                const int* __restrict__ t_ptr,
                                                const int* __restrict__ lo_ptr,
                                                float* __restrict__ out) {
    __shared__ float cat[80];
    int t = threadIdx.x;
    int tval = guard_int(t_ptr[0], 0, 500);
    int L    = guard_int(lo_ptr[0], 0, 3);
    float tf = (float)((double)tval / 500.0);
    if (t < 20) {
        cat[t] = subv[t];
        cat[20 + t] = protv[t];
        cat[40 + t] = seqv[t];
        cat[60 + t] = tf * Wtime[t] + btime[t];
    }
    __syncthreads();
    for (int j = 0; j < L; ++j) {
        float acc = 0.f;
        if (t < 80) {
            for (int i2 = 0; i2 < 80; ++i2)
                acc += fmaxf(cat[i2], 0.f) * Wout[(size_t)j * 6400 + i2 * 80 + t];
            acc += bout[j * 80 + t];
        }
        __syncthreads();
        if (t < 80) cat[t] = acc;
        __syncthreads();
    }
    if (t < 80) out[t] = fmaxf(cat[t], 0.f);
    if (t < 20) out[80 + t] = seqv[t];
}

// ---------- launch ----------
extern "C" void kernel_launch(void* const* d_in, const int* in_sizes, int n_in,
                              void* d_out, int out_size, void* d_ws, size_t ws_size,
                              hipStream_t stream) {
    static const int EXP[39] = {
        81920, 65536, 200000, 2097152, 2560, 128, 8192, 64, 1280, 20,
        524288, 1024, 524288, 1024, 524288, 1024, 524288, 1024, 1024, 1024,
        2097152, 4096, 2097152, 1024, 1024, 1024, 10240, 20, 19200, 240,
        20, 20, 256, 4096, 4096, 131072, 1, 1, 1 };
    float code = 0.f;
    if (n_in != 39) code = 900.f;
    else {
        for (int i = 0; i < 39; ++i)
            if (in_sizes[i] != EXP[i]) { code = 500.f + 4.f * (float)i; break; }
    }
    const size_t REQ = (size_t)42 * 1024 * 1024;
    if (code == 0.f && ws_size < REQ) code = (float)(ws_size >> 20);
    float* out = (float*)d_out;
    if (code != 0.f) {
        k_sentinel<<<1, 128, 0, stream>>>(out, -code, out_size);
        return;
    }

    // ---- direct fp32 input pointers ----
    const float* x_in   = (const float*)d_in[0];
    const float* adjs_in= (const float*)d_in[1];
    const float* embfp  = (const float*)d_in[2];
    const float* embw   = (const float*)d_in[3];
    const float* gW1 = (const float*)d_in[4];  const float* gb1 = (const float*)d_in[5];
    const float* gW2 = (const float*)d_in[6];  const float* gb2 = (const float*)d_in[7];
    const float* gW3 = (const float*)d_in[8];  const float* gb3 = (const float*)d_in[9];
    const float* Wq  = (const float*)d_in[10]; const float* bq  = (const float*)d_in[11];
    const float* Wk  = (const float*)d_in[12]; const float* bk  = (const float*)d_in[13];
    const float* Wv  = (const float*)d_in[14]; const float* bv  = (const float*)d_in[15];
    const float* Wo  = (const float*)d_in[16]; const float* bo  = (const float*)d_in[17];
    const float* ln1g= (const float*)d_in[18]; const float* ln1b= (const float*)d_in[19];
    const float* Wff1= (const float*)d_in[20]; const float* bff1= (const float*)d_in[21];
    const float* Wff2= (const float*)d_in[22]; const float* bff2= (const float*)d_in[23];
    const float* ln2g= (const float*)d_in[24]; const float* ln2b= (const float*)d_in[25];
    const float* Wproj=(const float*)d_in[26]; const float* bproj=(const float*)d_in[27];
    const float* Woutw=(const float*)d_in[28]; const float* boutw=(const float*)d_in[29];
    const float* Wtime=(const float*)d_in[30]; const float* btime=(const float*)d_in[31];
    const int* fingerprints = (const int*)d_in[32];
    const int* words        = (const int*)d_in[33];
    const int* edge_index   = (const int*)d_in[35];
    const int* t_ptr        = (const int*)d_in[36];
    const int* lo_ptr       = (const int*)d_in[37];

    // ---- workspace layout (42 MiB) ----
    char* wsb = (char*)d_ws;
    float* misc = (float*)wsb;                         // [0, 2 MiB)
    float* H    = (float*)(wsb + ((size_t)2  << 20));  // [2,10) 4096x512
    float* Q    = (float*)(wsb + ((size_t)10 << 20));  // [10,18) (O in-place)
    float* K    = (float*)(wsb + ((size_t)18 << 20));  // [18,26)
    float* V    = (float*)(wsb + ((size_t)26 << 20));  // [26,34) (also MHA out)
    float* T    = (float*)(wsb + ((size_t)34 << 20));  // [34,42) FF accumulator
    float* FFHc = Q;                                   // FF hidden chunk (Q free then)
    unsigned* ADJB = (unsigned*)Q;                     // protein bitmap (2 MiB)
    float* pt0  = K;                                   // protein temps in K region (6.94 MiB)
    float* ph1  = pt0 + 81920;
    float* pt1  = ph1 + 524288;
    float* ph2  = pt1 + 524288;
    float* pt2  = ph2 + 262144;
    float* pgo  = pt2 + 262144;
    // misc sub-allocations
    float* Xoh  = misc;                // 81920
    float* fpv  = misc + 81920;
    float* st0  = misc + 87040;
    float* sh1  = misc + 92160;
    float* st1  = misc + 124928;
    float* sh2  = misc + 157696;
    float* st2  = misc + 174080;
    float* sgo  = misc + 190464;
    float* P    = misc + 195584;       // 81920
    float* subv = misc + 277504;
    float* protv= misc + 277536;
    float* seqv = misc + 277568;
    int*   flags= (int*)(misc + 400000);   // [1]=first NaN stage

    hipMemsetAsync(flags, 0, 2 * sizeof(int), stream);

    auto g2 = [](int M, int N) { return dim3((unsigned)((N + 63) / 64), (unsigned)((M + 63) / 64), 1); };

    // 1. diffusion sampling -> X one-hot
    k_sample<<<16, 256, 0, stream>>>(x_in, t_ptr, Xoh);
    k_scan_f32<<<64, 256, 0, stream>>>(Xoh, 81920, 2, flags);

    // 2. substrate GCN (all fp32)
    k_gather_fp<<<20, 256, 0, stream>>>(embfp, fingerprints, fpv);
    k_gemm_nn<false, false><<<g2(256, 20), 256, 0, stream>>>(256, 20, 256, adjs_in, 256, fpv, 20, st0, 20, nullptr);
    k_gemm_nn<true,  false><<<g2(256, 128), 256, 0, stream>>>(256, 128, 20, st0, 20, gW1, 128, sh1, 128, gb1);
    k_gemm_nn<false, false><<<g2(256, 128), 256, 0, stream>>>(256, 128, 256, adjs_in, 256, sh1, 128, st1, 128, nullptr);
    k_gemm_nn<true,  false><<<g2(256, 64), 256, 0, stream>>>(256, 64, 128, st1, 128, gW2, 64, sh2, 64, gb2);
    k_gemm_nn<false, false><<<g2(256, 64), 256, 0, stream>>>(256, 64, 256, adjs_in, 256, sh2, 64, st2, 64, nullptr);
    k_gemm_nn<false, false><<<g2(256, 20), 256, 0, stream>>>(256, 20, 64, st2, 64, gW3, 20, sgo, 20, gb3);
    k_colmean<<<20, 256, 0, stream>>>(sgo, 256, 20, subv);
    k_scan_f32<<<1, 256, 0, stream>>>(subv, 20, 3, flags);

    // 3. transformer (fp32 end-to-end)
    k_embed<<<8192, 256, 0, stream>>>(embw, words, H);
    k_scan_f32<<<256, 256, 0, stream>>>(H, 2097152, 4, flags);
    for (int l = 0; l < 2; ++l) {
        int sb = 5 + l * 5;
        const float* wq = Wq + (size_t)l * 262144;
        const float* wk = Wk + (size_t)l * 262144;
        const float* wv = Wv + (size_t)l * 262144;
        const float* wo = Wo + (size_t)l * 262144;
        k_gemm_nn<false, false><<<g2(4096, 512), 256, 0, stream>>>(4096, 512, 512, H, 512, wq, 512, Q, 512, bq + l * 512);
        k_gemm_nn<false, false><<<g2(4096, 512), 256, 0, stream>>>(4096, 512, 512, H, 512, wk, 512, K, 512, bk + l * 512);
        k_gemm_nn<false, false><<<g2(4096, 512), 256, 0, stream>>>(4096, 512, 512, H, 512, wv, 512, V, 512, bv + l * 512);
        k_flash<<<dim3(128, 4, 1), 256, 0, stream>>>(Q, K, V);     // O -> Q
        k_scan_f32<<<256, 256, 0, stream>>>(Q, 2097152, sb + 0, flags);
        k_gemm_nn<false, false><<<g2(4096, 512), 256, 0, stream>>>(4096, 512, 512, Q, 512, wo, 512, V, 512, bo + l * 512);
        k_add_ln<<<4096, 256, 0, stream>>>(H, V, H, ln1g + l * 512, ln1b + l * 512);
        k_scan_f32<<<256, 256, 0, stream>>>(H, 2097152, sb + 1, flags);
        // FF in 4 chunks of 512 hidden dims: FFHc = relu(H@W1[:,ch]+b1); T (+)= FFHc@W2[ch,:]
        for (int c = 0; c < 4; ++c) {
            k_gemm_nn<true, false><<<g2(4096, 512), 256, 0, stream>>>(
                4096, 512, 512, H, 512, Wff1 + (size_t)l * 1048576 + c * 512, 2048, FFHc, 512, bff1 + l * 2048 + c * 512);
            if (c == 0)
                k_gemm_nn<false, false><<<g2(4096, 512), 256, 0, stream>>>(
                    4096, 512, 512, FFHc, 512, Wff2 + (size_t)l * 1048576 + (size_t)c * 512 * 512, 512, T, 512, bff2 + l * 512);
            else
                k_gemm_nn<false, true><<<g2(4096, 512), 256, 0, stream>>>(
                    4096, 512, 512, FFHc, 512, Wff2 + (size_t)l * 1048576 + (size_t)c * 512 * 512, 512, T, 512, nullptr);
        }
        k_add_ln<<<4096, 256, 0, stream>>>(H, T, H, ln2g + l * 512, ln2b + l * 512);
        k_scan_f32<<<256, 256, 0, stream>>>(H, 2097152, sb + 2, flags);
    }

    // 4. projection + mean -> seq
    k_gemm_nn<false, false><<<g2(4096, 20), 256, 0, stream>>>(4096, 20, 512, H, 512, Wproj, 20, P, 20, bproj);
    k_colmean<<<20, 256, 0, stream>>>(P, 4096, 20, seqv);
    k_scan_f32<<<1, 256, 0, stream>>>(seqv, 20, 17, flags);

    // 5. protein GCN (bit-packed adjacency in Q region, temps in K region)
    hipMemsetAsync(ADJB, 0, (size_t)4096 * 128 * 4, stream);
    k_scatter_bits<<<256, 256, 0, stream>>>(edge_index, ADJB);
    k_gemm_bits<<<g2(4096, 20), 256, 0, stream>>>(20, ADJB, Xoh, 20, pt0, 20);
    k_gemm_nn<true,  false><<<g2(4096, 128), 256, 0, stream>>>(4096, 128, 20, pt0, 20, gW1, 128, ph1, 128, gb1);
    k_gemm_bits<<<g2(4096, 128), 256, 0, stream>>>(128, ADJB, ph1, 128, pt1, 128);
    k_gemm_nn<true,  false><<<g2(4096, 64), 256, 0, stream>>>(4096, 64, 128, pt1, 128, gW2, 64, ph2, 64, gb2);
    k_gemm_bits<<<g2(4096, 64), 256, 0, stream>>>(64, ADJB, ph2, 64, pt2, 64);
    k_gemm_nn<false, false><<<g2(4096, 20), 256, 0, stream>>>(4096, 20, 64, pt2, 64, gW3, 20, pgo, 20, gb3);
    k_colmean<<<20, 256, 0, stream>>>(pgo, 4096, 20, protv);
    k_scan_f32<<<1, 256, 0, stream>>>(protv, 20, 18, flags);

    // 6. fusion head -> d_out (100 fp32: cat[80] ++ seq[20])
    k_fusion<<<1, 128, 0, stream>>>(subv, protv, seqv, Wtime, btime, Woutw, boutw, t_ptr, lo_ptr, out);
    k_finalize<<<1, 128, 0, stream>>>(out, out_size, flags);
}

// Round 8
// 5316.047 us; speedup vs baseline: 1.7675x; 1.7675x over previous
//
#include <hip/hip_runtime.h>
#include <math.h>

// ---------- helpers ----------
__device__ inline int guard_int(int raw, int lo, int hi) {
    if (raw >= lo && raw <= hi) return raw;
    float f = __int_as_float(raw);
    int v = (int)f;
    return (v >= lo && v <= hi) ? v : lo;
}

// ---------- threefry2x32 (JAX-compatible) ----------
__device__ inline void tf2x32(unsigned k0, unsigned k1, unsigned x0, unsigned x1,
                              unsigned& o0, unsigned& o1) {
    unsigned ks2 = k0 ^ k1 ^ 0x1BD11BDAu;
    x0 += k0; x1 += k1;
#define TFR(r) { x0 += x1; x1 = (x1 << (r)) | (x1 >> (32 - (r))); x1 ^= x0; }
    TFR(13) TFR(15) TFR(26) TFR(6)  x0 += k1;  x1 += ks2 + 1u;
    TFR(17) TFR(29) TFR(16) TFR(24) x0 += ks2; x1 += k0 + 2u;
    TFR(13) TFR(15) TFR(26) TFR(6)  x0 += k0;  x1 += k1 + 3u;
    TFR(17) TFR(29) TFR(16) TFR(24) x0 += k1;  x1 += ks2 + 4u;
    TFR(13) TFR(15) TFR(26) TFR(6)  x0 += ks2; x1 += k0 + 5u;
#undef TFR
    o0 = x0; o1 = x1;
}

#define SAMPLE_SCHEME 1   // partitionable threefry (o0^o1) — verified PASS in R7

// ---------- sentinel ----------
__global__ void k_sentinel(float* __restrict__ out, float val, int n) {
    int i = blockIdx.x * 128 + threadIdx.x;
    if (i < n) out[i] = val;
}

// ---------- diffusion categorical sampling -> one-hot X ----------
__global__ __launch_bounds__(256) void k_sample(const float* __restrict__ x,
                                                const int* __restrict__ t_ptr,
                                                float* __restrict__ X) {
    int i = blockIdx.x * 256 + threadIdx.x;
    if (i >= 4096) return;
    int tval = guard_int(t_ptr[0], 0, 500);
    double tf = (double)tval / 500.0;
    const double sc = 0.008;
    const double PI_HALF = 1.5707963267948966;
    double num = cos((tf + sc) / (1.0 + sc) * PI_HALF);
    double den = cos(sc / (1.0 + sc) * PI_HALF);
    float ab = (float)((num * num) / (den * den));
    float phi = (1.0f - ab) / 20.0f;
    float xv[20]; float sx = 0.f;
    for (int j = 0; j < 20; ++j) { xv[j] = x[i * 20 + j]; sx += xv[j]; }
    float best = -1e30f; int bj = 0;
    for (int j = 0; j < 20; ++j) {
        float prob = fmaxf(ab * xv[j] + phi * sx, 0.0f);
        float lp = logf(prob + 1e-9f);
        unsigned m = (unsigned)(i * 20 + j);
        unsigned o0, o1, bits;
#if SAMPLE_SCHEME == 0
        if (m < 40960u) { tf2x32(0u, 42u, m, m + 40960u, o0, o1); bits = o0; }
        else            { tf2x32(0u, 42u, m - 40960u, m, o0, o1); bits = o1; }
#else
        tf2x32(0u, 42u, 0u, m, o0, o1); bits = o0 ^ o1;
#endif
        float u = __uint_as_float((bits >> 9) | 0x3f800000u) - 1.0f;
        if (u < 1.1754943508222875e-38f) u = 1.1754943508222875e-38f;
        float gmb = -logf(-logf(u));
        float z = lp + gmb;
        if (z > best) { best = z; bj = j; }
    }
    for (int j = 0; j < 20; ++j) X[i * 20 + j] = (j == bj) ? 1.0f : 0.0f;
}

// ---------- small utility kernels ----------
__global__ __launch_bounds__(256) void k_gather_fp(const float* __restrict__ emb,
                                                   const int* __restrict__ idx,
                                                   float* __restrict__ out) {
    int i = blockIdx.x * 256 + threadIdx.x;
    if (i >= 256 * 20) return;
    int a = i / 20, d = i % 20;
    out[i] = emb[(size_t)idx[a] * 20 + d];
}

__global__ __launch_bounds__(256) void k_scatter_bits(const int* __restrict__ ei,
                                                      unsigned* __restrict__ bits) {
    int e = blockIdx.x * 256 + threadIdx.x;
    if (e >= 65536) return;
    int r = ei[e], c = ei[65536 + e];
    atomicOr(&bits[(size_t)r * 128 + (c >> 5)], 1u << (c & 31));
}

__global__ __launch_bounds__(256) void k_embed(const float* __restrict__ embw,
                                               const int* __restrict__ words,
                                               float* __restrict__ H) {
    int idx = blockIdx.x * 256 + threadIdx.x;
    if (idx >= 4096 * 512) return;
    int pos = idx >> 9, d = idx & 511;
    float e = embw[(size_t)words[pos] * 512 + d];
    float expo = (float)(d >> 1) * (1.0f / 256.0f);
    float ang = (float)pos * exp2f(-expo * 13.287712379549449f);  // / 10000^expo
    float pe = (d & 1) ? cosf(ang) : sinf(ang);
    H[idx] = e + pe;
}

__global__ __launch_bounds__(256) void k_colmean(const float* __restrict__ M, int R, int C,
                                                 float* __restrict__ out) {
    __shared__ float red[256];
    int c = blockIdx.x, t = threadIdx.x;
    float s = 0.f;
    for (int r = t; r < R; r += 256) s += M[(size_t)r * C + c];
    red[t] = s; __syncthreads();
    for (int o = 128; o; o >>= 1) { if (t < o) red[t] += red[t + o]; __syncthreads(); }
    if (t == 0) out[c] = red[0] / (float)R;
}

// ---------- GEMM (fp32): C[M,N] = [C +] A@B + bias, optional relu ----------
template<bool RELU, bool ACC>
__global__ __launch_bounds__(256) void k_gemm_nn(int M, int N, int K,
        const float* __restrict__ A, int lda,
        const float* __restrict__ B, int ldb,
        float* __restrict__ C, int ldc,
        const float* __restrict__ bias) {
    __shared__ float As[16][65];
    __shared__ float Bs[16][65];
    int tid = threadIdx.x;
    int tx = tid & 15, ty = tid >> 4;
    int br = blockIdx.y * 64, bc = blockIdx.x * 64;
    float acc[4][4] = {};
    for (int k0 = 0; k0 < K; k0 += 16) {
#pragma unroll
        for (int c0 = 0; c0 < 4; ++c0) {
            int r = (tid >> 4) + c0 * 16, kk = tid & 15;
            int gr = br + r, gk = k0 + kk;
            As[kk][r] = (gr < M && gk < K) ? A[(size_t)gr * lda + gk] : 0.f;
        }
#pragma unroll
        for (int c0 = 0; c0 < 4; ++c0) {
            int col = tid & 63, kk = (tid >> 6) + c0 * 4;
            int gc = bc + col, gk = k0 + kk;
            Bs[kk][col] = (gc < N && gk < K) ? B[(size_t)gk * ldb + gc] : 0.f;
        }
        __syncthreads();
#pragma unroll
        for (int kk = 0; kk < 16; ++kk) {
            float av[4], bv[4];
#pragma unroll
            for (int i2 = 0; i2 < 4; ++i2) av[i2] = As[kk][ty + 16 * i2];
#pragma unroll
            for (int j2 = 0; j2 < 4; ++j2) bv[j2] = Bs[kk][tx + 16 * j2];
#pragma unroll
            for (int i2 = 0; i2 < 4; ++i2)
#pragma unroll
                for (int j2 = 0; j2 < 4; ++j2) acc[i2][j2] += av[i2] * bv[j2];
        }
        __syncthreads();
    }
#pragma unroll
    for (int i2 = 0; i2 < 4; ++i2)
#pragma unroll
        for (int j2 = 0; j2 < 4; ++j2) {
            int r = br + ty + 16 * i2, c = bc + tx + 16 * j2;
            if (r < M && c < N) {
                float v = acc[i2][j2];
                if (ACC) v += C[(size_t)r * ldc + c];
                if (bias) v += bias[c];
                if (RELU) v = fmaxf(v, 0.f);
                C[(size_t)r * ldc + c] = v;
            }
        }
}

// ---------- SpMM: C[4096,N] = BITS @ B, per-row bitmap scan (nnz ~16/row) ----------
template<int NC, int CHUNKS>
__global__ __launch_bounds__(256) void k_spmm_bits(
        const unsigned* __restrict__ BITS,
        const float* __restrict__ B, int ldb,
        float* __restrict__ C, int ldc) {
    int t = blockIdx.x * 256 + threadIdx.x;
    int r = t / CHUNKS;
    int cb = (t % CHUNKS) * NC;
    if (r >= 4096) return;
    float acc[NC];
#pragma unroll
    for (int j = 0; j < NC; ++j) acc[j] = 0.f;
    const unsigned* bw = &BITS[(size_t)r * 128];
    for (int w = 0; w < 128; ++w) {
        unsigned bits = bw[w];
        while (bits) {
            int b = __ffs(bits) - 1; bits &= bits - 1;
            const float* brow = &B[(size_t)(w * 32 + b) * ldb + cb];
#pragma unroll
            for (int j = 0; j < NC; ++j) acc[j] += brow[j];
        }
    }
#pragma unroll
    for (int j = 0; j < NC; ++j) C[(size_t)r * ldc + cb + j] = acc[j];
}

// ---------- flash attention (fp32), bank-conflict-free, O in-place over Q ----------
// Block: 16 Q-rows x 1 head. Score map: (col=tid&31, group=tid>>5 -> 2 rows).
// K/V staged TRANSPOSED [128][33]: bank=(d+c)%32 -> conflict-free lane reads.
__global__ __launch_bounds__(256) void k_flash(float* __restrict__ Qg,
                                               const float* __restrict__ Kg,
                                               const float* __restrict__ Vg) {
    __shared__ float Qs[16][128];
    __shared__ float Kt[128][33];
    __shared__ float Vt[128][33];
    __shared__ float Ps[16][33];
    const int tid = threadIdx.x;
    const int qb = blockIdx.x * 16;
    const int hh = blockIdx.y;
    const float scale = 0.08838834764831845f;   // 1/sqrt(128)
#pragma unroll
    for (int i = 0; i < 2; ++i) {               // stage Q: 512 float4
        int e = tid + i * 256; int r = e >> 5, c4 = e & 31;
        ((float4*)&Qs[r][0])[c4] = ((const float4*)&Qg[(size_t)(qb + r) * 512 + hh * 128])[c4];
    }
    const int sc = tid & 31;        // score col == output e-lane
    const int r0 = (tid >> 5) * 2, r1 = r0 + 1;
    const int stc = tid >> 3, stdq = tid & 7;   // staging map: row 0..31, d-oct 0..7
    float m0 = -INFINITY, m1 = -INFINITY, l0 = 0.f, l1 = 0.f;
    float o0[4] = {0.f, 0.f, 0.f, 0.f}, o1[4] = {0.f, 0.f, 0.f, 0.f};
    __syncthreads();
    for (int kt = 0; kt < 128; ++kt) {
        {   // stage K transposed (coalesced global float4 -> scattered LDS scalar)
            const float* kb = &Kg[(size_t)(kt * 32 + stc) * 512 + hh * 128 + stdq * 16];
#pragma unroll
            for (int j = 0; j < 4; ++j) {
                float4 w = ((const float4*)kb)[j];
                int d = stdq * 16 + j * 4;
                Kt[d + 0][stc] = w.x; Kt[d + 1][stc] = w.y;
                Kt[d + 2][stc] = w.z; Kt[d + 3][stc] = w.w;
            }
        }
        __syncthreads();    // Kt ready; also guarantees previous PV finished
        float s0 = 0.f, s1 = 0.f;
#pragma unroll 4
        for (int d = 0; d < 128; ++d) {
            float kv = Kt[d][sc];               // conflict-free
            s0 += Qs[r0][d] * kv;               // broadcast
            s1 += Qs[r1][d] * kv;
        }
        s0 *= scale; s1 *= scale;
        float t0 = s0, t1 = s1;                 // row max over 32 lanes
#pragma unroll
        for (int off = 16; off > 0; off >>= 1) {
            t0 = fmaxf(t0, __shfl_xor(t0, off, 32));
            t1 = fmaxf(t1, __shfl_xor(t1, off, 32));
        }
        float mn0 = fmaxf(m0, t0), mn1 = fmaxf(m1, t1);
        float al0 = expf(m0 - mn0), al1 = expf(m1 - mn1);   // first tile: exp(-inf)=0
        float p0 = expf(s0 - mn0), p1 = expf(s1 - mn1);
        float su0 = p0, su1 = p1;               // row sum over 32 lanes
#pragma unroll
        for (int off = 16; off > 0; off >>= 1) {
            su0 += __shfl_xor(su0, off, 32);
            su1 += __shfl_xor(su1, off, 32);
        }
        m0 = mn0; m1 = mn1;
        l0 = l0 * al0 + su0; l1 = l1 * al1 + su1;
        Ps[r0][sc] = p0; Ps[r1][sc] = p1;
        {   // stage V transposed
            const float* vb = &Vg[(size_t)(kt * 32 + stc) * 512 + hh * 128 + stdq * 16];
#pragma unroll
            for (int j = 0; j < 4; ++j) {
                float4 w = ((const float4*)vb)[j];
                int d = stdq * 16 + j * 4;
                Vt[d + 0][stc] = w.x; Vt[d + 1][stc] = w.y;
                Vt[d + 2][stc] = w.z; Vt[d + 3][stc] = w.w;
            }
        }
        __syncthreads();    // Ps + Vt ready
#pragma unroll
        for (int k = 0; k < 4; ++k) { o0[k] *= al0; o1[k] *= al1; }
        for (int m = 0; m < 32; ++m) {
            float p0v = Ps[r0][m], p1v = Ps[r1][m];     // broadcast
#pragma unroll
            for (int k = 0; k < 4; ++k) {
                float v = Vt[sc + 32 * k][m];           // conflict-free
                o0[k] += p0v * v;
                o1[k] += p1v * v;
            }
        }
        // no barrier here: next Kt staging is disjoint from Ps/Vt reads,
        // and next __syncthreads() orders Ps rewrites after all PV reads.
    }
    float inv0 = 1.0f / l0, inv1 = 1.0f / l1;   // l is row-uniform across lanes
#pragma unroll
    for (int k = 0; k < 4; ++k) {
        Qg[(size_t)(qb + r0) * 512 + hh * 128 + sc + 32 * k] = o0[k] * inv0;
        Qg[(size_t)(qb + r1) * 512 + hh * 128 + sc + 32 * k] = o1[k] * inv1;
    }
}

// ---------- residual add + layernorm (D=512), O may alias A ----------
__global__ __launch_bounds__(256) void k_add_ln(const float* __restrict__ A,
                                                const float* __restrict__ B,
                                                float* __restrict__ O,
                                                const float* __restrict__ g,
                                                const float* __restrict__ b) {
    __shared__ float xr[512];
    __shared__ float red[256];
    int row = blockIdx.x, t = threadIdx.x;
    const float* a = A + (size_t)row * 512;
    const float* bb = B + (size_t)row * 512;
    float ls = 0.f;
    for (int j = t; j < 512; j += 256) { float v = a[j] + bb[j]; xr[j] = v; ls += v; }
    red[t] = ls; __syncthreads();
    for (int o = 128; o; o >>= 1) { if (t < o) red[t] += red[t + o]; __syncthreads(); }
    float mean = red[0] / 512.0f; __syncthreads();
    float lv = 0.f;
    for (int j = t; j < 512; j += 256) { float d = xr[j] - mean; lv += d * d; }
    red[t] = lv; __syncthreads();
    for (int o = 128; o; o >>= 1) { if (t < o) red[t] += red[t + o]; __syncthreads(); }
    float inv = 1.0f / sqrtf(red[0] / 512.0f + 1e-5f);
    float* o_ = O + (size_t)row * 512;
    for (int j = t; j < 512; j += 256)
        o_[j] = (xr[j] - mean) * inv * g[j] + b[j];
}

// ---------- fusion head (fp32 out: cat[80] ++ seq[20]) ----------
__global__ __launch_bounds__(128) void k_fusion(const float* __restrict__ subv,
                                                const float* __restrict__ protv,
                                                const float* __restrict__ seqv,
                                                const float* __restrict__ Wtime,
                                                const float* __restrict__ btime,
                                                const float* __restrict__ Wout,
                                                const float* __restrict__ bout,
                                                const int* __restrict__ t_ptr,
                                                const int* __restrict__ lo_ptr,
                                                float* __restrict__ out) {
    __shared__ float cat[80];
    int t = threadIdx.x;
    int tval = guard_int(t_ptr[0], 0, 500);
    int L    = guard_int(lo_ptr[0], 0, 3);
    float tf = (float)((double)tval / 500.0);
    if (t < 20) {
        cat[t] = subv[t];
        cat[20 + t] = protv[t];
        cat[40 + t] = seqv[t];
        cat[60 + t] = tf * Wtime[t] + btime[t];
    }
    __syncthreads();
    for (int j = 0; j < L; ++j) {
        float acc = 0.f;
        if (t < 80) {
            for (int i2 = 0; i2 < 80; ++i2)
                acc += fmaxf(cat[i2], 0.f) * Wout[(size_t)j * 6400 + i2 * 80 + t];
            acc += bout[j * 80 + t];
        }
        __syncthreads();
        if (t < 80) cat[t] = acc;
        __syncthreads();
    }
    if (t < 80) out[t] = fmaxf(cat[t], 0.f);
    if (t < 20) out[80 + t] = seqv[t];
}

// ---------- launch ----------
extern "C" void kernel_launch(void* const* d_in, const int* in_sizes, int n_in,
                              void* d_out, int out_size, void* d_ws, size_t ws_size,
                              hipStream_t stream) {
    static const int EXP[39] = {
        81920, 65536, 200000, 2097152, 2560, 128, 8192, 64, 1280, 20,
        524288, 1024, 524288, 1024, 524288, 1024, 524288, 1024, 1024, 1024,
        2097152, 4096, 2097152, 1024, 1024, 1024, 10240, 20, 19200, 240,
        20, 20, 256, 4096, 4096, 131072, 1, 1, 1 };
    float code = 0.f;
    if (n_in != 39) code = 900.f;
    else {
        for (int i = 0; i < 39; ++i)
            if (in_sizes[i] != EXP[i]) { code = 500.f + 4.f * (float)i; break; }
    }
    const size_t REQ = (size_t)42 * 1024 * 1024;
    if (code == 0.f && ws_size < REQ) code = (float)(ws_size >> 20);
    float* out = (float*)d_out;
    if (code != 0.f) {
        k_sentinel<<<1, 128, 0, stream>>>(out, -code, out_size);
        return;
    }

    const float* x_in   = (const float*)d_in[0];
    const float* adjs_in= (const float*)d_in[1];
    const float* embfp  = (const float*)d_in[2];
    const float* embw   = (const float*)d_in[3];
    const float* gW1 = (const float*)d_in[4];  const float* gb1 = (const float*)d_in[5];
    const float* gW2 = (const float*)d_in[6];  const float* gb2 = (const float*)d_in[7];
    const float* gW3 = (const float*)d_in[8];  const float* gb3 = (const float*)d_in[9];
    const float* Wq  = (const float*)d_in[10]; const float* bq  = (const float*)d_in[11];
    const float* Wk  = (const float*)d_in[12]; const float* bk  = (const float*)d_in[13];
    const float* Wv  = (const float*)d_in[14]; const float* bv  = (const float*)d_in[15];
    const float* Wo  = (const float*)d_in[16]; const float* bo  = (const float*)d_in[17];
    const float* ln1g= (const float*)d_in[18]; const float* ln1b= (const float*)d_in[19];
    const float* Wff1= (const float*)d_in[20]; const float* bff1= (const float*)d_in[21];
    const float* Wff2= (const float*)d_in[22]; const float* bff2= (const float*)d_in[23];
    const float* ln2g= (const float*)d_in[24]; const float* ln2b= (const float*)d_in[25];
    const float* Wproj=(const float*)d_in[26]; const float* bproj=(const float*)d_in[27];
    const float* Woutw=(const float*)d_in[28]; const float* boutw=(const float*)d_in[29];
    const float* Wtime=(const float*)d_in[30]; const float* btime=(const float*)d_in[31];
    const int* fingerprints = (const int*)d_in[32];
    const int* words        = (const int*)d_in[33];
    const int* edge_index   = (const int*)d_in[35];
    const int* t_ptr        = (const int*)d_in[36];
    const int* lo_ptr       = (const int*)d_in[37];

    // ---- workspace (42 MiB) ----
    char* wsb = (char*)d_ws;
    float* misc = (float*)wsb;                         // [0, 2 MiB)
    float* H    = (float*)(wsb + ((size_t)2  << 20));  // [2,10) 4096x512
    float* Q    = (float*)(wsb + ((size_t)10 << 20));  // [10,18) (attn out in-place)
    float* K    = (float*)(wsb + ((size_t)18 << 20));  // [18,26)
    float* V    = (float*)(wsb + ((size_t)26 << 20));  // [26,34) (also MHA out)
    float* T    = (float*)(wsb + ((size_t)34 << 20));  // [34,42) FF accumulator
    float* FFHc = Q;                                   // FF hidden chunk 4096x1024 (Q+K, free then)
    unsigned* ADJB = (unsigned*)Q;                     // protein bitmap (2 MiB)
    float* pt0  = K;                                   // protein temps in K region
    float* ph1  = pt0 + 81920;
    float* pt1  = ph1 + 524288;
    float* ph2  = pt1 + 524288;
    float* pt2  = ph2 + 262144;
    float* pgo  = pt2 + 262144;
    float* Xoh  = misc;                // 81920
    float* fpv  = misc + 81920;
    float* st0  = misc + 87040;
    float* sh1  = misc + 92160;
    float* st1  = misc + 124928;
    float* sh2  = misc + 157696;
    float* st2  = misc + 174080;
    float* sgo  = misc + 190464;
    float* P    = misc + 195584;       // 81920
    float* subv = misc + 277504;
    float* protv= misc + 277536;
    float* seqv = misc + 277568;

    auto g2 = [](int M, int N) { return dim3((unsigned)((N + 63) / 64), (unsigned)((M + 63) / 64), 1); };

    // 1. diffusion sampling -> X one-hot
    k_sample<<<16, 256, 0, stream>>>(x_in, t_ptr, Xoh);

    // 2. substrate GCN
    k_gather_fp<<<20, 256, 0, stream>>>(embfp, fingerprints, fpv);
    k_gemm_nn<false, false><<<g2(256, 20), 256, 0, stream>>>(256, 20, 256, adjs_in, 256, fpv, 20, st0, 20, nullptr);
    k_gemm_nn<true,  false><<<g2(256, 128), 256, 0, stream>>>(256, 128, 20, st0, 20, gW1, 128, sh1, 128, gb1);
    k_gemm_nn<false, false><<<g2(256, 128), 256, 0, stream>>>(256, 128, 256, adjs_in, 256, sh1, 128, st1, 128, nullptr);
    k_gemm_nn<true,  false><<<g2(256, 64), 256, 0, stream>>>(256, 64, 128, st1, 128, gW2, 64, sh2, 64, gb2);
    k_gemm_nn<false, false><<<g2(256, 64), 256, 0, stream>>>(256, 64, 256, adjs_in, 256, sh2, 64, st2, 64, nullptr);
    k_gemm_nn<false, false><<<g2(256, 20), 256, 0, stream>>>(256, 20, 64, st2, 64, gW3, 20, sgo, 20, gb3);
    k_colmean<<<20, 256, 0, stream>>>(sgo, 256, 20, subv);

    // 3. transformer
    k_embed<<<8192, 256, 0, stream>>>(embw, words, H);
    for (int l = 0; l < 2; ++l) {
        const float* wq = Wq + (size_t)l * 262144;
        const float* wk = Wk + (size_t)l * 262144;
        const float* wv = Wv + (size_t)l * 262144;
        const float* wo = Wo + (size_t)l * 262144;
        k_gemm_nn<false, false><<<g2(4096, 512), 256, 0, stream>>>(4096, 512, 512, H, 512, wq, 512, Q, 512, bq + l * 512);
        k_gemm_nn<false, false><<<g2(4096, 512), 256, 0, stream>>>(4096, 512, 512, H, 512, wk, 512, K, 512, bk + l * 512);
        k_gemm_nn<false, false><<<g2(4096, 512), 256, 0, stream>>>(4096, 512, 512, H, 512, wv, 512, V, 512, bv + l * 512);
        k_flash<<<dim3(256, 4, 1), 256, 0, stream>>>(Q, K, V);     // O -> Q
        k_gemm_nn<false, false><<<g2(4096, 512), 256, 0, stream>>>(4096, 512, 512, Q, 512, wo, 512, V, 512, bo + l * 512);
        k_add_ln<<<4096, 256, 0, stream>>>(H, V, H, ln1g + l * 512, ln1b + l * 512);
        // FF in 2 chunks of 1024 hidden dims
        for (int c = 0; c < 2; ++c) {
            k_gemm_nn<true, false><<<g2(4096, 1024), 256, 0, stream>>>(
                4096, 1024, 512, H, 512, Wff1 + (size_t)l * 1048576 + c * 1024, 2048, FFHc, 1024, bff1 + l * 2048 + c * 1024);
            if (c == 0)
                k_gemm_nn<false, false><<<g2(4096, 512), 256, 0, stream>>>(
                    4096, 512, 1024, FFHc, 1024, Wff2 + (size_t)l * 1048576 + (size_t)c * 1024 * 512, 512, T, 512, bff2 + l * 512);
            else
                k_gemm_nn<false, true><<<g2(4096, 512), 256, 0, stream>>>(
                    4096, 512, 1024, FFHc, 1024, Wff2 + (size_t)l * 1048576 + (size_t)c * 1024 * 512, 512, T, 512, nullptr);
        }
        k_add_ln<<<4096, 256, 0, stream>>>(H, T, H, ln2g + l * 512, ln2b + l * 512);
    }

    // 4. projection + mean -> seq
    k_gemm_nn<false, false><<<g2(4096, 20), 256, 0, stream>>>(4096, 20, 512, H, 512, Wproj, 20, P, 20, bproj);
    k_colmean<<<20, 256, 0, stream>>>(P, 4096, 20, seqv);

    // 5. protein GCN (bitmap SpMM: per-row bit scan, nnz~16)
    hipMemsetAsync(ADJB, 0, (size_t)4096 * 128 * 4, stream);
    k_scatter_bits<<<256, 256, 0, stream>>>(edge_index, ADJB);
    k_spmm_bits<20, 1><<<16, 256, 0, stream>>>(ADJB, Xoh, 20, pt0, 20);
    k_gemm_nn<true,  false><<<g2(4096, 128), 256, 0, stream>>>(4096, 128, 20, pt0, 20, gW1, 128, ph1, 128, gb1);
    k_spmm_bits<32, 4><<<64, 256, 0, stream>>>(ADJB, ph1, 128, pt1, 128);
    k_gemm_nn<true,  false><<<g2(4096, 64), 256, 0, stream>>>(4096, 64, 128, pt1, 128, gW2, 64, ph2, 64, gb2);
    k_spmm_bits<32, 2><<<32, 256, 0, stream>>>(ADJB, ph2, 64, pt2, 64);
    k_gemm_nn<false, false><<<g2(4096, 20), 256, 0, stream>>>(4096, 20, 64, pt2, 64, gW3, 20, pgo, 20, gb3);
    k_colmean<<<20, 256, 0, stream>>>(pgo, 4096, 20, protv);

    // 6. fusion head -> d_out (100 fp32: cat[80] ++ seq[20])
    k_fusion<<<1, 128, 0, stream>>>(subv, protv, seqv, Wtime, btime, Woutw, boutw, t_ptr, lo_ptr, out);
}

// Round 9
// 3880.667 us; speedup vs baseline: 2.4213x; 1.3699x over previous
//
#include <hip/hip_runtime.h>
#include <math.h>

typedef unsigned short ushort_t;
typedef __attribute__((ext_vector_type(8))) short bf16x8;
typedef __attribute__((ext_vector_type(4))) float f32x4;

// ---------- helpers ----------
__device__ inline float bf2f(unsigned u) { return __uint_as_float((u & 0xffffu) << 16); }
__device__ inline ushort_t f2bf(float f) {
    unsigned u = __float_as_uint(f);
    return (ushort_t)((u + 0x7fffu + ((u >> 16) & 1u)) >> 16);   // RNE
}
__device__ inline void stv(float* p, float v) { *p = v; }
__device__ inline void stv(ushort_t* p, float v) { *p = f2bf(v); }
__device__ inline int guard_int(int raw, int lo, int hi) {
    if (raw >= lo && raw <= hi) return raw;
    float f = __int_as_float(raw);
    int v = (int)f;
    return (v >= lo && v <= hi) ? v : lo;
}
__device__ inline void unpack8(uint4 w, float* d) {
    d[0] = bf2f(w.x); d[1] = bf2f(w.x >> 16);
    d[2] = bf2f(w.y); d[3] = bf2f(w.y >> 16);
    d[4] = bf2f(w.z); d[5] = bf2f(w.z >> 16);
    d[6] = bf2f(w.w); d[7] = bf2f(w.w >> 16);
}

// ---------- threefry2x32 (JAX partitionable, verified R7) ----------
__device__ inline void tf2x32(unsigned k0, unsigned k1, unsigned x0, unsigned x1,
                              unsigned& o0, unsigned& o1) {
    unsigned ks2 = k0 ^ k1 ^ 0x1BD11BDAu;
    x0 += k0; x1 += k1;
#define TFR(r) { x0 += x1; x1 = (x1 << (r)) | (x1 >> (32 - (r))); x1 ^= x0; }
    TFR(13) TFR(15) TFR(26) TFR(6)  x0 += k1;  x1 += ks2 + 1u;
    TFR(17) TFR(29) TFR(16) TFR(24) x0 += ks2; x1 += k0 + 2u;
    TFR(13) TFR(15) TFR(26) TFR(6)  x0 += k0;  x1 += k1 + 3u;
    TFR(17) TFR(29) TFR(16) TFR(24) x0 += k1;  x1 += ks2 + 4u;
    TFR(13) TFR(15) TFR(26) TFR(6)  x0 += ks2; x1 += k0 + 5u;
#undef TFR
    o0 = x0; o1 = x1;
}

__global__ void k_sentinel(float* __restrict__ out, float val, int n) {
    int i = blockIdx.x * 128 + threadIdx.x;
    if (i < n) out[i] = val;
}

// ---------- diffusion categorical sampling -> one-hot X ----------
__global__ __launch_bounds__(256) void k_sample(const float* __restrict__ x,
                                                const int* __restrict__ t_ptr,
                                                float* __restrict__ X) {
    int i = blockIdx.x * 256 + threadIdx.x;
    if (i >= 4096) return;
    int tval = guard_int(t_ptr[0], 0, 500);
    double tf = (double)tval / 500.0;
    const double sc = 0.008;
    const double PI_HALF = 1.5707963267948966;
    double num = cos((tf + sc) / (1.0 + sc) * PI_HALF);
    double den = cos(sc / (1.0 + sc) * PI_HALF);
    float ab = (float)((num * num) / (den * den));
    float phi = (1.0f - ab) / 20.0f;
    float xv[20]; float sx = 0.f;
    for (int j = 0; j < 20; ++j) { xv[j] = x[i * 20 + j]; sx += xv[j]; }
    float best = -1e30f; int bj = 0;
    for (int j = 0; j < 20; ++j) {
        float prob = fmaxf(ab * xv[j] + phi * sx, 0.0f);
        float lp = logf(prob + 1e-9f);
        unsigned m = (unsigned)(i * 20 + j);
        unsigned o0, o1;
        tf2x32(0u, 42u, 0u, m, o0, o1);
        unsigned bits = o0 ^ o1;
        float u = __uint_as_float((bits >> 9) | 0x3f800000u) - 1.0f;
        if (u < 1.1754943508222875e-38f) u = 1.1754943508222875e-38f;
        float gmb = -logf(-logf(u));
        float z = lp + gmb;
        if (z > best) { best = z; bj = j; }
    }
    for (int j = 0; j < 20; ++j) X[i * 20 + j] = (j == bj) ? 1.0f : 0.0f;
}

// ---------- small utility kernels ----------
__global__ __launch_bounds__(256) void k_gather_fp(const float* __restrict__ emb,
                                                   const int* __restrict__ idx,
                                                   float* __restrict__ out) {
    int i = blockIdx.x * 256 + threadIdx.x;
    if (i >= 256 * 20) return;
    int a = i / 20, d = i % 20;
    out[i] = emb[(size_t)idx[a] * 20 + d];
}

__global__ __launch_bounds__(256) void k_scatter_bits(const int* __restrict__ ei,
                                                      unsigned* __restrict__ bits) {
    int e = blockIdx.x * 256 + threadIdx.x;
    if (e >= 65536) return;
    int r = ei[e], c = ei[65536 + e];
    atomicOr(&bits[(size_t)r * 128 + (c >> 5)], 1u << (c & 31));
}

// embed writes fp32 H and bf16 Hb
__global__ __launch_bounds__(256) void k_embed(const float* __restrict__ embw,
                                               const int* __restrict__ words,
                                               float* __restrict__ H,
                                               ushort_t* __restrict__ Hb) {
    int idx = blockIdx.x * 256 + threadIdx.x;
    if (idx >= 4096 * 512) return;
    int pos = idx >> 9, d = idx & 511;
    float e = embw[(size_t)words[pos] * 512 + d];
    float expo = (float)(d >> 1) * (1.0f / 256.0f);
    float ang = (float)pos * exp2f(-expo * 13.287712379549449f);
    float pe = (d & 1) ? cosf(ang) : sinf(ang);
    float v = e + pe;
    H[idx] = v; Hb[idx] = f2bf(v);
}

__global__ __launch_bounds__(256) void k_colmean(const float* __restrict__ M, int R, int C,
                                                 float* __restrict__ out) {
    __shared__ float red[256];
    int c = blockIdx.x, t = threadIdx.x;
    float s = 0.f;
    for (int r = t; r < R; r += 256) s += M[(size_t)r * C + c];
    red[t] = s; __syncthreads();
    for (int o = 128; o; o >>= 1) { if (t < o) red[t] += red[t + o]; __syncthreads(); }
    if (t == 0) out[c] = red[0] / (float)R;
}

// ---------- weight cast+transpose: in fp32 [K,N] -> out bf16 [N,K] ----------
__global__ __launch_bounds__(256) void k_castT(const float* __restrict__ in,
                                               ushort_t* __restrict__ out,
                                               int Kd, int Nd) {
    __shared__ float t[32][33];
    int bx = blockIdx.x * 32, by = blockIdx.y * 32;   // bx: n-base, by: k-base
    int tx = threadIdx.x & 31, ty = threadIdx.x >> 5; // ty 0..7
#pragma unroll
    for (int i = 0; i < 4; ++i)
        t[ty + i * 8][tx] = in[(size_t)(by + ty + i * 8) * Nd + bx + tx];
    __syncthreads();
#pragma unroll
    for (int i = 0; i < 4; ++i)
        out[(size_t)(bx + ty + i * 8) * Kd + by + tx] = f2bf(t[tx][ty + i * 8]);
}

// ---------- MFMA bf16 GEMM: C[M,N] = A[M,K](bf16) @ Bt[N,K](bf16) + bias ----------
// 64x64 tile, 4 waves in 2x2, each wave 32x32 via 4x mfma_f32_16x16x32_bf16.
template<bool RELU, typename TC>
__global__ __launch_bounds__(256) void k_gemm_mfma(int M, int N, int K,
        const ushort_t* __restrict__ A,
        const ushort_t* __restrict__ Bt,
        TC* __restrict__ C, int ldc,
        const float* __restrict__ bias) {
    __shared__ ushort_t As[64][40];
    __shared__ ushort_t Bs[64][40];
    int tid = threadIdx.x;
    int lane = tid & 63, wave = tid >> 6;
    int wr = wave >> 1, wc = wave & 1;
    int lrow = lane & 15, lq = lane >> 4;
    int br = blockIdx.y * 64, bc = blockIdx.x * 64;
    f32x4 acc[2][2];
#pragma unroll
    for (int i = 0; i < 2; ++i)
#pragma unroll
        for (int j = 0; j < 2; ++j) { acc[i][j][0] = 0.f; acc[i][j][1] = 0.f; acc[i][j][2] = 0.f; acc[i][j][3] = 0.f; }
    int sr = tid >> 2, sseg = tid & 3;      // staging: 64 rows x 4 segs of 8 bf16
    for (int k0 = 0; k0 < K; k0 += 32) {
        *(uint4*)&As[sr][sseg * 8] = *(const uint4*)&A[(size_t)(br + sr) * K + k0 + sseg * 8];
        *(uint4*)&Bs[sr][sseg * 8] = *(const uint4*)&Bt[(size_t)(bc + sr) * K + k0 + sseg * 8];
        __syncthreads();
        bf16x8 af[2], bfr[2];
#pragma unroll
        for (int i = 0; i < 2; ++i) {
            af[i]  = *(const bf16x8*)&As[wr * 32 + i * 16 + lrow][lq * 8];
            bfr[i] = *(const bf16x8*)&Bs[wc * 32 + i * 16 + lrow][lq * 8];
        }
#pragma unroll
        for (int i = 0; i < 2; ++i)
#pragma unroll
            for (int j = 0; j < 2; ++j)
                acc[i][j] = __builtin_amdgcn_mfma_f32_16x16x32_bf16(af[i], bfr[j], acc[i][j], 0, 0, 0);
        __syncthreads();
    }
#pragma unroll
    for (int i = 0; i < 2; ++i)
#pragma unroll
        for (int j = 0; j < 2; ++j) {
            int col = bc + wc * 32 + j * 16 + lrow;
            float bv = bias ? bias[col] : 0.f;
#pragma unroll
            for (int r = 0; r < 4; ++r) {
                int row = br + wr * 32 + i * 16 + lq * 4 + r;
                float v = acc[i][j][r] + bv;
                if (RELU) v = fmaxf(v, 0.f);
                stv(&C[(size_t)row * ldc + col], v);
            }
        }
}

// ---------- fp32 GEMM (small/odd shapes): C = A@B + bias, optional relu ----------
template<bool RELU>
__global__ __launch_bounds__(256) void k_gemm_nn(int M, int N, int K,
        const float* __restrict__ A, int lda,
        const float* __restrict__ B, int ldb,
        float* __restrict__ C, int ldc,
        const float* __restrict__ bias) {
    __shared__ float As[16][65];
    __shared__ float Bs[16][65];
    int tid = threadIdx.x;
    int tx = tid & 15, ty = tid >> 4;
    int br = blockIdx.y * 64, bc = blockIdx.x * 64;
    float acc[4][4] = {};
    for (int k0 = 0; k0 < K; k0 += 16) {
#pragma unroll
        for (int c0 = 0; c0 < 4; ++c0) {
            int r = (tid >> 4) + c0 * 16, kk = tid & 15;
            int gr = br + r, gk = k0 + kk;
            As[kk][r] = (gr < M && gk < K) ? A[(size_t)gr * lda + gk] : 0.f;
        }
#pragma unroll
        for (int c0 = 0; c0 < 4; ++c0) {
            int col = tid & 63, kk = (tid >> 6) + c0 * 4;
            int gc = bc + col, gk = k0 + kk;
            Bs[kk][col] = (gc < N && gk < K) ? B[(size_t)gk * ldb + gc] : 0.f;
        }
        __syncthreads();
#pragma unroll
        for (int kk = 0; kk < 16; ++kk) {
            float av[4], bv[4];
#pragma unroll
            for (int i2 = 0; i2 < 4; ++i2) av[i2] = As[kk][ty + 16 * i2];
#pragma unroll
            for (int j2 = 0; j2 < 4; ++j2) bv[j2] = Bs[kk][tx + 16 * j2];
#pragma unroll
            for (int i2 = 0; i2 < 4; ++i2)
#pragma unroll
                for (int j2 = 0; j2 < 4; ++j2) acc[i2][j2] += av[i2] * bv[j2];
        }
        __syncthreads();
    }
#pragma unroll
    for (int i2 = 0; i2 < 4; ++i2)
#pragma unroll
        for (int j2 = 0; j2 < 4; ++j2) {
            int r = br + ty + 16 * i2, c = bc + tx + 16 * j2;
            if (r < M && c < N) {
                float v = acc[i2][j2];
                if (bias) v += bias[c];
                if (RELU) v = fmaxf(v, 0.f);
                C[(size_t)r * ldc + c] = v;
            }
        }
}

// ---------- SpMM: C[4096,N] = BITS @ B ----------
template<int NC, int CHUNKS>
__global__ __launch_bounds__(256) void k_spmm_bits(
        const unsigned* __restrict__ BITS,
        const float* __restrict__ B, int ldb,
        float* __restrict__ C, int ldc) {
    int t = blockIdx.x * 256 + threadIdx.x;
    int r = t / CHUNKS;
    int cb = (t % CHUNKS) * NC;
    if (r >= 4096) return;
    float acc[NC];
#pragma unroll
    for (int j = 0; j < NC; ++j) acc[j] = 0.f;
    const unsigned* bw = &BITS[(size_t)r * 128];
    for (int w = 0; w < 128; ++w) {
        unsigned bits = bw[w];
        while (bits) {
            int b = __ffs(bits) - 1; bits &= bits - 1;
            const float* brow = &B[(size_t)(w * 32 + b) * ldb + cb];
#pragma unroll
            for (int j = 0; j < NC; ++j) acc[j] += brow[j];
        }
    }
#pragma unroll
    for (int j = 0; j < NC; ++j) C[(size_t)r * ldc + cb + j] = acc[j];
}

// ---------- flash attention: bf16 in/out, fp32 compute, O in-place over Q ----------
// 16 Q-rows x 1 head per block. K row-major [32][132] (float4 reads, quad-spread),
// V transposed [128][33] (conflict-free scalar).
__global__ __launch_bounds__(256) void k_flash(ushort_t* __restrict__ Qg,
                                               const ushort_t* __restrict__ Kg,
                                               const ushort_t* __restrict__ Vg) {
    __shared__ float Qs[16][128];
    __shared__ float Ks[32][132];
    __shared__ float Vt[128][33];
    __shared__ float Ps[16][33];
    const int tid = threadIdx.x;
    const int qb = blockIdx.x * 16;
    const int hh = blockIdx.y;
    const float scale = 0.08838834764831845f;   // 1/sqrt(128)
    {   // stage Q: 16 rows x 16 segs of 8 bf16
        int r = tid >> 4, seg = tid & 15;
        uint4 w = *(const uint4*)&Qg[(size_t)(qb + r) * 512 + hh * 128 + seg * 8];
        unpack8(w, &Qs[r][seg * 8]);
    }
    const int sc = tid & 31;
    const int r0 = (tid >> 5) * 2, r1 = r0 + 1;
    float m0 = -INFINITY, m1 = -INFINITY, l0 = 0.f, l1 = 0.f;
    float o0[4] = {0.f, 0.f, 0.f, 0.f}, o1[4] = {0.f, 0.f, 0.f, 0.f};
    __syncthreads();
    for (int kt = 0; kt < 128; ++kt) {
        {   // stage K: 32 rows x 16 segs
            int seg = tid & 15;
#pragma unroll
            for (int i = 0; i < 2; ++i) {
                int rr = (tid >> 4) + i * 16;
                uint4 w = *(const uint4*)&Kg[(size_t)(kt * 32 + rr) * 512 + hh * 128 + seg * 8];
                float f[8]; unpack8(w, f);
                *(float4*)&Ks[rr][seg * 8]     = *(float4*)&f[0];
                *(float4*)&Ks[rr][seg * 8 + 4] = *(float4*)&f[4];
            }
        }
        __syncthreads();    // Ks ready; also orders prev-iter Ps reads before rewrite
        float s0 = 0.f, s1 = 0.f;
#pragma unroll
        for (int d = 0; d < 128; d += 4) {
            float4 kv = *(const float4*)&Ks[sc][d];
            float4 q0 = *(const float4*)&Qs[r0][d];
            float4 q1 = *(const float4*)&Qs[r1][d];
            s0 += q0.x * kv.x + q0.y * kv.y + q0.z * kv.z + q0.w * kv.w;
            s1 += q1.x * kv.x + q1.y * kv.y + q1.z * kv.z + q1.w * kv.w;
        }
        s0 *= scale; s1 *= scale;
        float t0 = s0, t1 = s1;
#pragma unroll
        for (int off = 16; off > 0; off >>= 1) {
            t0 = fmaxf(t0, __shfl_xor(t0, off, 32));
            t1 = fmaxf(t1, __shfl_xor(t1, off, 32));
        }
        float mn0 = fmaxf(m0, t0), mn1 = fmaxf(m1, t1);
        float al0 = expf(m0 - mn0), al1 = expf(m1 - mn1);
        float p0 = expf(s0 - mn0), p1 = expf(s1 - mn1);
        float su0 = p0, su1 = p1;
#pragma unroll
        for (int off = 16; off > 0; off >>= 1) {
            su0 += __shfl_xor(su0, off, 32);
            su1 += __shfl_xor(su1, off, 32);
        }
        m0 = mn0; m1 = mn1;
        l0 = l0 * al0 + su0; l1 = l1 * al1 + su1;
        Ps[r0][sc] = p0; Ps[r1][sc] = p1;
        {   // stage V transposed
            int seg = tid & 15;
#pragma unroll
            for (int i = 0; i < 2; ++i) {
                int rr = (tid >> 4) + i * 16;
                uint4 w = *(const uint4*)&Vg[(size_t)(kt * 32 + rr) * 512 + hh * 128 + seg * 8];
                float f[8]; unpack8(w, f);
#pragma unroll
                for (int j = 0; j < 8; ++j) Vt[seg * 8 + j][rr] = f[j];
            }
        }
        __syncthreads();    // Ps + Vt ready
#pragma unroll
        for (int k = 0; k < 4; ++k) { o0[k] *= al0; o1[k] *= al1; }
        for (int m = 0; m < 32; ++m) {
            float p0v = Ps[r0][m], p1v = Ps[r1][m];
#pragma unroll
            for (int k = 0; k < 4; ++k) {
                float v = Vt[sc + 32 * k][m];
                o0[k] += p0v * v;
                o1[k] += p1v * v;
            }
        }
        // no barrier: next K staging (Ks) is disjoint from Ps/Vt reads; next
        // __syncthreads() orders Ps/Vt rewrites after all PV reads.
    }
    float inv0 = 1.0f / l0, inv1 = 1.0f / l1;
#pragma unroll
    for (int k = 0; k < 4; ++k) {
        Qg[(size_t)(qb + r0) * 512 + hh * 128 + sc + 32 * k] = f2bf(o0[k] * inv0);
        Qg[(size_t)(qb + r1) * 512 + hh * 128 + sc + 32 * k] = f2bf(o1[k] * inv1);
    }
}

// ---------- residual add + layernorm: writes fp32 H and bf16 Hb ----------
__global__ __launch_bounds__(256) void k_add_ln(const float* __restrict__ A,
                                                const float* __restrict__ B,
                                                float* __restrict__ O,
                                                ushort_t* __restrict__ Ob,
                                                const float* __restrict__ g,
                                                const float* __restrict__ b) {
    __shared__ float xr[512];
    __shared__ float red[256];
    int row = blockIdx.x, t = threadIdx.x;
    const float* a = A + (size_t)row * 512;
    const float* bb = B + (size_t)row * 512;
    float ls = 0.f;
    for (int j = t; j < 512; j += 256) { float v = a[j] + bb[j]; xr[j] = v; ls += v; }
    red[t] = ls; __syncthreads();
    for (int o = 128; o; o >>= 1) { if (t < o) red[t] += red[t + o]; __syncthreads(); }
    float mean = red[0] / 512.0f; __syncthreads();
    float lv = 0.f;
    for (int j = t; j < 512; j += 256) { float d = xr[j] - mean; lv += d * d; }
    red[t] = lv; __syncthreads();
    for (int o = 128; o; o >>= 1) { if (t < o) red[t] += red[t + o]; __syncthreads(); }
    float inv = 1.0f / sqrtf(red[0] / 512.0f + 1e-5f);
    float* o_ = O + (size_t)row * 512;
    ushort_t* ob = Ob + (size_t)row * 512;
    for (int j = t; j < 512; j += 256) {
        float v = (xr[j] - mean) * inv * g[j] + b[j];
        o_[j] = v; ob[j] = f2bf(v);
    }
}

// ---------- fusion head ----------
__global__ __launch_bounds__(128) void k_fusion(const float* __restrict__ subv,
                                                const float* __restrict__ protv,
                                                const float* __restrict__ seqv,
                                                const float* __restrict__ Wtime,
                                                const float* __restrict__ btime,
                                                const float* __restrict__ Wout,
                                                const float* __restrict__ bout,
                                                const int* __restrict__ t_ptr,
                                                const int* __restrict__ lo_ptr,
                                                float* __restrict__ out) {
    __shared__ float cat[80];
    int t = threadIdx.x;
    int tval = guard_int(t_ptr[0], 0, 500);
    int L    = guard_int(lo_ptr[0], 0, 3);
    float tf = (float)((double)tval / 500.0);
    if (t < 20) {
        cat[t] = subv[t];
        cat[20 + t] = protv[t];
        cat[40 + t] = seqv[t];
        cat[60 + t] = tf * Wtime[t] + btime[t];
    }
    __syncthreads();
    for (int j = 0; j < L; ++j) {
        float acc = 0.f;
        if (t < 80) {
            for (int i2 = 0; i2 < 80; ++i2)
                acc += fmaxf(cat[i2], 0.f) * Wout[(size_t)j * 6400 + i2 * 80 + t];
            acc += bout[j * 80 + t];
        }
        __syncthreads();
        if (t < 80) cat[t] = acc;
        __syncthreads();
    }
    if (t < 80) out[t] = fmaxf(cat[t], 0.f);
    if (t < 20) out[80 + t] = seqv[t];
}

// ---------- launch ----------
extern "C" void kernel_launch(void* const* d_in, const int* in_sizes, int n_in,
                              void* d_out, int out_size, void* d_ws, size_t ws_size,
                              hipStream_t stream) {
    static const int EXP[39] = {
        81920, 65536, 200000, 2097152, 2560, 128, 8192, 64, 1280, 20,
        524288, 1024, 524288, 1024, 524288, 1024, 524288, 1024, 1024, 1024,
        2097152, 4096, 2097152, 1024, 1024, 1024, 10240, 20, 19200, 240,
        20, 20, 256, 4096, 4096, 131072, 1, 1, 1 };
    float code = 0.f;
    if (n_in != 39) code = 900.f;
    else {
        for (int i = 0; i < 39; ++i)
            if (in_sizes[i] != EXP[i]) { code = 500.f + 4.f * (float)i; break; }
    }
    const size_t REQ = (size_t)42 * 1024 * 1024;
    if (code == 0.f && ws_size < REQ) code = (float)(ws_size >> 20);
    float* out = (float*)d_out;
    if (code != 0.f) {
        k_sentinel<<<1, 128, 0, stream>>>(out, -code, out_size);
        return;
    }

    const float* x_in   = (const float*)d_in[0];
    const float* adjs_in= (const float*)d_in[1];
    const float* embfp  = (const float*)d_in[2];
    const float* embw   = (const float*)d_in[3];
    const float* gW1 = (const float*)d_in[4];  const float* gb1 = (const float*)d_in[5];
    const float* gW2 = (const float*)d_in[6];  const float* gb2 = (const float*)d_in[7];
    const float* gW3 = (const float*)d_in[8];  const float* gb3 = (const float*)d_in[9];
    const float* Wq  = (const float*)d_in[10]; const float* bq  = (const float*)d_in[11];
    const float* Wk  = (const float*)d_in[12]; const float* bk  = (const float*)d_in[13];
    const float* Wv  = (const float*)d_in[14]; const float* bv  = (const float*)d_in[15];
    const float* Wo  = (const float*)d_in[16]; const float* bo  = (const float*)d_in[17];
    const float* ln1g= (const float*)d_in[18]; const float* ln1b= (const float*)d_in[19];
    const float* Wff1= (const float*)d_in[20]; const float* bff1= (const float*)d_in[21];
    const float* Wff2= (const float*)d_in[22]; const float* bff2= (const float*)d_in[23];
    const float* ln2g= (const float*)d_in[24]; const float* ln2b= (const float*)d_in[25];
    const float* Wproj=(const float*)d_in[26]; const float* bproj=(const float*)d_in[27];
    const float* Woutw=(const float*)d_in[28]; const float* boutw=(const float*)d_in[29];
    const float* Wtime=(const float*)d_in[30]; const float* btime=(const float*)d_in[31];
    const int* fingerprints = (const int*)d_in[32];
    const int* words        = (const int*)d_in[33];
    const int* edge_index   = (const int*)d_in[35];
    const int* t_ptr        = (const int*)d_in[36];
    const int* lo_ptr       = (const int*)d_in[37];

    // ---- workspace (42 MiB) ----
    // [0,2) misc | [2,10) H fp32 | [10,14) Hb bf16 | [14,18) Qb | [18,22) Kb | [22,26) Vb
    // [14,30) FFHb bf16 4096x2048 (aliases QKV, dead then) | [30,38) T fp32 | [38,42) Wscr bf16
    char* wsb = (char*)d_ws;
    float*    misc = (float*)wsb;
    float*    H    = (float*)(wsb + ((size_t)2  << 20));
    ushort_t* Hb   = (ushort_t*)(wsb + ((size_t)10 << 20));
    ushort_t* Qb   = (ushort_t*)(wsb + ((size_t)14 << 20));
    ushort_t* Kb   = (ushort_t*)(wsb + ((size_t)18 << 20));
    ushort_t* Vb   = (ushort_t*)(wsb + ((size_t)22 << 20));
    ushort_t* FFHb = (ushort_t*)(wsb + ((size_t)14 << 20));
    float*    T    = (float*)(wsb + ((size_t)30 << 20));
    ushort_t* Wscr = (ushort_t*)(wsb + ((size_t)38 << 20));
    unsigned* ADJB = (unsigned*)Qb;                 // protein bitmap (2 MiB)
    float* pt0  = (float*)Kb;                       // protein temps in [18,30)
    float* ph1  = pt0 + 81920;
    float* pt1  = ph1 + 524288;
    float* ph2  = pt1 + 524288;
    float* pt2  = ph2 + 262144;
    float* pgo  = pt2 + 262144;
    float* Xoh  = misc;
    float* fpv  = misc + 81920;
    float* st0  = misc + 87040;
    float* sh1  = misc + 92160;
    float* st1  = misc + 124928;
    float* sh2  = misc + 157696;
    float* st2  = misc + 174080;
    float* sgo  = misc + 190464;
    float* P    = misc + 195584;
    float* subv = misc + 277504;
    float* protv= misc + 277536;
    float* seqv = misc + 277568;

    auto g2 = [](int M, int N) { return dim3((unsigned)((N + 63) / 64), (unsigned)((M + 63) / 64), 1); };
    auto gm = [](int M, int N) { return dim3((unsigned)(N / 64), (unsigned)(M / 64), 1); };
    auto gt = [](int Kd, int Nd) { return dim3((unsigned)(Nd / 32), (unsigned)(Kd / 32), 1); };

    // 1. diffusion sampling
    k_sample<<<16, 256, 0, stream>>>(x_in, t_ptr, Xoh);

    // 2. substrate GCN (fp32)
    k_gather_fp<<<20, 256, 0, stream>>>(embfp, fingerprints, fpv);
    k_gemm_nn<false><<<g2(256, 20), 256, 0, stream>>>(256, 20, 256, adjs_in, 256, fpv, 20, st0, 20, nullptr);
    k_gemm_nn<true ><<<g2(256, 128), 256, 0, stream>>>(256, 128, 20, st0, 20, gW1, 128, sh1, 128, gb1);
    k_gemm_nn<false><<<g2(256, 128), 256, 0, stream>>>(256, 128, 256, adjs_in, 256, sh1, 128, st1, 128, nullptr);
    k_gemm_nn<true ><<<g2(256, 64), 256, 0, stream>>>(256, 64, 128, st1, 128, gW2, 64, sh2, 64, gb2);
    k_gemm_nn<false><<<g2(256, 64), 256, 0, stream>>>(256, 64, 256, adjs_in, 256, sh2, 64, st2, 64, nullptr);
    k_gemm_nn<false><<<g2(256, 20), 256, 0, stream>>>(256, 20, 64, st2, 64, gW3, 20, sgo, 20, gb3);
    k_colmean<<<20, 256, 0, stream>>>(sgo, 256, 20, subv);

    // 3. transformer (bf16 MFMA GEMMs + fp32 flash/LN)
    k_embed<<<8192, 256, 0, stream>>>(embw, words, H, Hb);
    for (int l = 0; l < 2; ++l) {
        const float* wq = Wq + (size_t)l * 262144;
        const float* wk = Wk + (size_t)l * 262144;
        const float* wv = Wv + (size_t)l * 262144;
        const float* wo = Wo + (size_t)l * 262144;
        ushort_t* wqb = Wscr;            // 512x512 each
        ushort_t* wkb = Wscr + 262144;
        ushort_t* wvb = Wscr + 524288;
        ushort_t* wob = Wscr + 786432;
        k_castT<<<gt(512, 512), 256, 0, stream>>>(wq, wqb, 512, 512);
        k_castT<<<gt(512, 512), 256, 0, stream>>>(wk, wkb, 512, 512);
        k_castT<<<gt(512, 512), 256, 0, stream>>>(wv, wvb, 512, 512);
        k_castT<<<gt(512, 512), 256, 0, stream>>>(wo, wob, 512, 512);
        k_gemm_mfma<false, ushort_t><<<gm(4096, 512), 256, 0, stream>>>(4096, 512, 512, Hb, wqb, Qb, 512, bq + l * 512);
        k_gemm_mfma<false, ushort_t><<<gm(4096, 512), 256, 0, stream>>>(4096, 512, 512, Hb, wkb, Kb, 512, bk + l * 512);
        k_gemm_mfma<false, ushort_t><<<gm(4096, 512), 256, 0, stream>>>(4096, 512, 512, Hb, wvb, Vb, 512, bv + l * 512);
        k_flash<<<dim3(256, 4, 1), 256, 0, stream>>>(Qb, Kb, Vb);   // O -> Qb (bf16)
        k_gemm_mfma<false, float><<<gm(4096, 512), 256, 0, stream>>>(4096, 512, 512, Qb, wob, T, 512, bo + l * 512);
        k_add_ln<<<4096, 256, 0, stream>>>(H, T, H, Hb, ln1g + l * 512, ln1b + l * 512);
        // FF: FFHb = relu(Hb@W1+b1) bf16 [4096,2048]; T = FFHb@W2+b2 fp32
        k_castT<<<gt(512, 2048), 256, 0, stream>>>(Wff1 + (size_t)l * 1048576, Wscr, 512, 2048);
        k_gemm_mfma<true, ushort_t><<<gm(4096, 2048), 256, 0, stream>>>(4096, 2048, 512, Hb, Wscr, FFHb, 2048, bff1 + l * 2048);
        k_castT<<<gt(2048, 512), 256, 0, stream>>>(Wff2 + (size_t)l * 1048576, Wscr, 2048, 512);
        k_gemm_mfma<false, float><<<gm(4096, 512), 256, 0, stream>>>(4096, 512, 2048, FFHb, Wscr, T, 512, bff2 + l * 512);
        k_add_ln<<<4096, 256, 0, stream>>>(H, T, H, Hb, ln2g + l * 512, ln2b + l * 512);
    }

    // 4. projection + mean -> seq (fp32)
    k_gemm_nn<false><<<g2(4096, 20), 256, 0, stream>>>(4096, 20, 512, H, 512, Wproj, 20, P, 20, bproj);
    k_colmean<<<20, 256, 0, stream>>>(P, 4096, 20, seqv);

    // 5. protein GCN
    hipMemsetAsync(ADJB, 0, (size_t)4096 * 128 * 4, stream);
    k_scatter_bits<<<256, 256, 0, stream>>>(edge_index, ADJB);
    k_spmm_bits<20, 1><<<16, 256, 0, stream>>>(ADJB, Xoh, 20, pt0, 20);
    k_gemm_nn<true ><<<g2(4096, 128), 256, 0, stream>>>(4096, 128, 20, pt0, 20, gW1, 128, ph1, 128, gb1);
    k_spmm_bits<32, 4><<<64, 256, 0, stream>>>(ADJB, ph1, 128, pt1, 128);
    k_gemm_nn<true ><<<g2(4096, 64), 256, 0, stream>>>(4096, 64, 128, pt1, 128, gW2, 64, ph2, 64, gb2);
    k_spmm_bits<32, 2><<<32, 256, 0, stream>>>(ADJB, ph2, 64, pt2, 64);
    k_gemm_nn<false><<<g2(4096, 20), 256, 0, stream>>>(4096, 20, 64, pt2, 64, gW3, 20, pgo, 20, gb3);
    k_colmean<<<20, 256, 0, stream>>>(pgo, 4096, 20, protv);

    // 6. fusion head
    k_fusion<<<1, 128, 0, stream>>>(subv, protv, seqv, Wtime, btime, Woutw, boutw, t_ptr, lo_ptr, out);
}

// Round 10
// 1627.867 us; speedup vs baseline: 5.7720x; 2.3839x over previous
//
#include <hip/hip_runtime.h>
#include <math.h>

typedef unsigned short ushort_t;
typedef __attribute__((ext_vector_type(8))) short bf16x8;
typedef __attribute__((ext_vector_type(4))) float f32x4;

// ---------- helpers ----------
__device__ inline float bf2f(unsigned u) { return __uint_as_float((u & 0xffffu) << 16); }
__device__ inline ushort_t f2bf(float f) {
    unsigned u = __float_as_uint(f);
    return (ushort_t)((u + 0x7fffu + ((u >> 16) & 1u)) >> 16);   // RNE
}
__device__ inline void stv(float* p, float v) { *p = v; }
__device__ inline void stv(ushort_t* p, float v) { *p = f2bf(v); }
__device__ inline int guard_int(int raw, int lo, int hi) {
    if (raw >= lo && raw <= hi) return raw;
    float f = __int_as_float(raw);
    int v = (int)f;
    return (v >= lo && v <= hi) ? v : lo;
}

// ---------- threefry2x32 (JAX partitionable, verified R7) ----------
__device__ inline void tf2x32(unsigned k0, unsigned k1, unsigned x0, unsigned x1,
                              unsigned& o0, unsigned& o1) {
    unsigned ks2 = k0 ^ k1 ^ 0x1BD11BDAu;
    x0 += k0; x1 += k1;
#define TFR(r) { x0 += x1; x1 = (x1 << (r)) | (x1 >> (32 - (r))); x1 ^= x0; }
    TFR(13) TFR(15) TFR(26) TFR(6)  x0 += k1;  x1 += ks2 + 1u;
    TFR(17) TFR(29) TFR(16) TFR(24) x0 += ks2; x1 += k0 + 2u;
    TFR(13) TFR(15) TFR(26) TFR(6)  x0 += k0;  x1 += k1 + 3u;
    TFR(17) TFR(29) TFR(16) TFR(24) x0 += k1;  x1 += ks2 + 4u;
    TFR(13) TFR(15) TFR(26) TFR(6)  x0 += ks2; x1 += k0 + 5u;
#undef TFR
    o0 = x0; o1 = x1;
}

__global__ void k_sentinel(float* __restrict__ out, float val, int n) {
    int i = blockIdx.x * 128 + threadIdx.x;
    if (i < n) out[i] = val;
}

// ---------- diffusion categorical sampling -> one-hot X ----------
__global__ __launch_bounds__(256) void k_sample(const float* __restrict__ x,
                                                const int* __restrict__ t_ptr,
                                                float* __restrict__ X) {
    int i = blockIdx.x * 256 + threadIdx.x;
    if (i >= 4096) return;
    int tval = guard_int(t_ptr[0], 0, 500);
    double tf = (double)tval / 500.0;
    const double sc = 0.008;
    const double PI_HALF = 1.5707963267948966;
    double num = cos((tf + sc) / (1.0 + sc) * PI_HALF);
    double den = cos(sc / (1.0 + sc) * PI_HALF);
    float ab = (float)((num * num) / (den * den));
    float phi = (1.0f - ab) / 20.0f;
    float xv[20]; float sx = 0.f;
    for (int j = 0; j < 20; ++j) { xv[j] = x[i * 20 + j]; sx += xv[j]; }
    float best = -1e30f; int bj = 0;
    for (int j = 0; j < 20; ++j) {
        float prob = fmaxf(ab * xv[j] + phi * sx, 0.0f);
        float lp = logf(prob + 1e-9f);
        unsigned m = (unsigned)(i * 20 + j);
        unsigned o0, o1;
        tf2x32(0u, 42u, 0u, m, o0, o1);
        unsigned bits = o0 ^ o1;
        float u = __uint_as_float((bits >> 9) | 0x3f800000u) - 1.0f;
        if (u < 1.1754943508222875e-38f) u = 1.1754943508222875e-38f;
        float gmb = -logf(-logf(u));
        float z = lp + gmb;
        if (z > best) { best = z; bj = j; }
    }
    for (int j = 0; j < 20; ++j) X[i * 20 + j] = (j == bj) ? 1.0f : 0.0f;
}

// ---------- small utility kernels ----------
__global__ __launch_bounds__(256) void k_gather_fp(const float* __restrict__ emb,
                                                   const int* __restrict__ idx,
                                                   float* __restrict__ out) {
    int i = blockIdx.x * 256 + threadIdx.x;
    if (i >= 256 * 20) return;
    int a = i / 20, d = i % 20;
    out[i] = emb[(size_t)idx[a] * 20 + d];
}

__global__ __launch_bounds__(256) void k_scatter_bits(const int* __restrict__ ei,
                                                      unsigned* __restrict__ bits) {
    int e = blockIdx.x * 256 + threadIdx.x;
    if (e >= 65536) return;
    int r = ei[e], c = ei[65536 + e];
    atomicOr(&bits[(size_t)r * 128 + (c >> 5)], 1u << (c & 31));
}

__global__ __launch_bounds__(256) void k_embed(const float* __restrict__ embw,
                                               const int* __restrict__ words,
                                               float* __restrict__ H,
                                               ushort_t* __restrict__ Hb) {
    int idx = blockIdx.x * 256 + threadIdx.x;
    if (idx >= 4096 * 512) return;
    int pos = idx >> 9, d = idx & 511;
    float e = embw[(size_t)words[pos] * 512 + d];
    float expo = (float)(d >> 1) * (1.0f / 256.0f);
    float ang = (float)pos * exp2f(-expo * 13.287712379549449f);
    float pe = (d & 1) ? cosf(ang) : sinf(ang);
    float v = e + pe;
    H[idx] = v; Hb[idx] = f2bf(v);
}

__global__ __launch_bounds__(256) void k_colmean(const float* __restrict__ M, int R, int C,
                                                 float* __restrict__ out) {
    __shared__ float red[256];
    int c = blockIdx.x, t = threadIdx.x;
    float s = 0.f;
    for (int r = t; r < R; r += 256) s += M[(size_t)r * C + c];
    red[t] = s; __syncthreads();
    for (int o = 128; o; o >>= 1) { if (t < o) red[t] += red[t + o]; __syncthreads(); }
    if (t == 0) out[c] = red[0] / (float)R;
}

// ---------- weight cast+transpose: fp32 [K,N] -> bf16 [N,K] ----------
__global__ __launch_bounds__(256) void k_castT(const float* __restrict__ in,
                                               ushort_t* __restrict__ out,
                                               int Kd, int Nd) {
    __shared__ float t[32][33];
    int bx = blockIdx.x * 32, by = blockIdx.y * 32;
    int tx = threadIdx.x & 31, ty = threadIdx.x >> 5;
#pragma unroll
    for (int i = 0; i < 4; ++i)
        t[ty + i * 8][tx] = in[(size_t)(by + ty + i * 8) * Nd + bx + tx];
    __syncthreads();
#pragma unroll
    for (int i = 0; i < 4; ++i)
        out[(size_t)(bx + ty + i * 8) * Kd + by + tx] = f2bf(t[tx][ty + i * 8]);
}

// ---------- MFMA bf16 GEMM: C[M,N] = A[M,K](bf16) @ Bt[N,K](bf16) + bias ----------
template<bool RELU, typename TC>
__global__ __launch_bounds__(256) void k_gemm_mfma(int M, int N, int K,
        const ushort_t* __restrict__ A,
        const ushort_t* __restrict__ Bt,
        TC* __restrict__ C, int ldc,
        const float* __restrict__ bias) {
    __shared__ ushort_t As[64][40];
    __shared__ ushort_t Bs[64][40];
    int tid = threadIdx.x;
    int lane = tid & 63, wave = tid >> 6;
    int wr = wave >> 1, wc = wave & 1;
    int lrow = lane & 15, lq = lane >> 4;
    int br = blockIdx.y * 64, bc = blockIdx.x * 64;
    f32x4 acc[2][2];
#pragma unroll
    for (int i = 0; i < 2; ++i)
#pragma unroll
        for (int j = 0; j < 2; ++j) { acc[i][j][0] = 0.f; acc[i][j][1] = 0.f; acc[i][j][2] = 0.f; acc[i][j][3] = 0.f; }
    int sr = tid >> 2, sseg = tid & 3;
    for (int k0 = 0; k0 < K; k0 += 32) {
        *(uint4*)&As[sr][sseg * 8] = *(const uint4*)&A[(size_t)(br + sr) * K + k0 + sseg * 8];
        *(uint4*)&Bs[sr][sseg * 8] = *(const uint4*)&Bt[(size_t)(bc + sr) * K + k0 + sseg * 8];
        __syncthreads();
        bf16x8 af[2], bfr[2];
#pragma unroll
        for (int i = 0; i < 2; ++i) {
            af[i]  = *(const bf16x8*)&As[wr * 32 + i * 16 + lrow][lq * 8];
            bfr[i] = *(const bf16x8*)&Bs[wc * 32 + i * 16 + lrow][lq * 8];
        }
#pragma unroll
        for (int i = 0; i < 2; ++i)
#pragma unroll
            for (int j = 0; j < 2; ++j)
                acc[i][j] = __builtin_amdgcn_mfma_f32_16x16x32_bf16(af[i], bfr[j], acc[i][j], 0, 0, 0);
        __syncthreads();
    }
#pragma unroll
    for (int i = 0; i < 2; ++i)
#pragma unroll
        for (int j = 0; j < 2; ++j) {
            int col = bc + wc * 32 + j * 16 + lrow;
            float bv = bias ? bias[col] : 0.f;
#pragma unroll
            for (int r = 0; r < 4; ++r) {
                int row = br + wr * 32 + i * 16 + lq * 4 + r;
                float v = acc[i][j][r] + bv;
                if (RELU) v = fmaxf(v, 0.f);
                stv(&C[(size_t)row * ldc + col], v);
            }
        }
}

// ---------- fp32 GEMM (small/odd shapes) ----------
template<bool RELU>
__global__ __launch_bounds__(256) void k_gemm_nn(int M, int N, int K,
        const float* __restrict__ A, int lda,
        const float* __restrict__ B, int ldb,
        float* __restrict__ C, int ldc,
        const float* __restrict__ bias) {
    __shared__ float As[16][65];
    __shared__ float Bs[16][65];
    int tid = threadIdx.x;
    int tx = tid & 15, ty = tid >> 4;
    int br = blockIdx.y * 64, bc = blockIdx.x * 64;
    float acc[4][4] = {};
    for (int k0 = 0; k0 < K; k0 += 16) {
#pragma unroll
        for (int c0 = 0; c0 < 4; ++c0) {
            int r = (tid >> 4) + c0 * 16, kk = tid & 15;
            int gr = br + r, gk = k0 + kk;
            As[kk][r] = (gr < M && gk < K) ? A[(size_t)gr * lda + gk] : 0.f;
        }
#pragma unroll
        for (int c0 = 0; c0 < 4; ++c0) {
            int col = tid & 63, kk = (tid >> 6) + c0 * 4;
            int gc = bc + col, gk = k0 + kk;
            Bs[kk][col] = (gc < N && gk < K) ? B[(size_t)gk * ldb + gc] : 0.f;
        }
        __syncthreads();
#pragma unroll
        for (int kk = 0; kk < 16; ++kk) {
            float av[4], bv[4];
#pragma unroll
            for (int i2 = 0; i2 < 4; ++i2) av[i2] = As[kk][ty + 16 * i2];
#pragma unroll
            for (int j2 = 0; j2 < 4; ++j2) bv[j2] = Bs[kk][tx + 16 * j2];
#pragma unroll
            for (int i2 = 0; i2 < 4; ++i2)
#pragma unroll
                for (int j2 = 0; j2 < 4; ++j2) acc[i2][j2] += av[i2] * bv[j2];
        }
        __syncthreads();
    }
#pragma unroll
    for (int i2 = 0; i2 < 4; ++i2)
#pragma unroll
        for (int j2 = 0; j2 < 4; ++j2) {
            int r = br + ty + 16 * i2, c = bc + tx + 16 * j2;
            if (r < M && c < N) {
                float v = acc[i2][j2];
                if (bias) v += bias[c];
                if (RELU) v = fmaxf(v, 0.f);
                C[(size_t)r * ldc + c] = v;
            }
        }
}

// ---------- SpMM: C[4096,N] = BITS @ B ----------
template<int NC, int CHUNKS>
__global__ __launch_bounds__(256) void k_spmm_bits(
        const unsigned* __restrict__ BITS,
        const float* __restrict__ B, int ldb,
        float* __restrict__ C, int ldc) {
    int t = blockIdx.x * 256 + threadIdx.x;
    int r = t / CHUNKS;
    int cb = (t % CHUNKS) * NC;
    if (r >= 4096) return;
    float acc[NC];
#pragma unroll
    for (int j = 0; j < NC; ++j) acc[j] = 0.f;
    const unsigned* bw = &BITS[(size_t)r * 128];
    for (int w = 0; w < 128; ++w) {
        unsigned bits = bw[w];
        while (bits) {
            int b = __ffs(bits) - 1; bits &= bits - 1;
            const float* brow = &B[(size_t)(w * 32 + b) * ldb + cb];
#pragma unroll
            for (int j = 0; j < NC; ++j) acc[j] += brow[j];
        }
    }
#pragma unroll
    for (int j = 0; j < NC; ++j) C[(size_t)r * ldc + cb + j] = acc[j];
}

// ---------- MFMA flash attention: bf16 in/out, fp32 softmax, O in-place over Q ----------
// Block: 4 waves x 16 Q-rows = 64 rows; grid (64, 4 heads). Per 32-row K-tile:
// QK = 8 MFMAs (frag map proven in k_gemm_mfma), reg-resident online softmax
// (16-lane shfl_xor per quad), P -> LDS bf16 (C-layout -> A-layout), PV = 8 MFMAs.
__global__ __launch_bounds__(256) void k_flash(ushort_t* __restrict__ Qg,
                                               const ushort_t* __restrict__ Kg,
                                               const ushort_t* __restrict__ Vg) {
    __shared__ ushort_t Ks[32][136];    // K-tile row-major (stride 68 words: even 8-lane spread)
    __shared__ ushort_t Vt[128][40];    // V-tile transposed [vcol][krow]
    __shared__ ushort_t Ps[4][16][40];  // per-wave P [qrow][krow]
    const int tid = threadIdx.x;
    const int lane = tid & 63, wid = tid >> 6;
    const int lrow = lane & 15, lq = lane >> 4;
    const int qb = blockIdx.x * 64, hh = blockIdx.y;
    const float scale = 0.08838834764831845f;   // 1/sqrt(128)
    // Q fragments: A[m=lrow][k=lq*8+j + 32*step]
    bf16x8 qf[4];
    {
        const ushort_t* qrow = &Qg[(size_t)(qb + wid * 16 + lrow) * 512 + hh * 128 + lq * 8];
#pragma unroll
        for (int s = 0; s < 4; ++s) qf[s] = *(const bf16x8*)&qrow[s * 32];
    }
    f32x4 o[8];
#pragma unroll
    for (int ct = 0; ct < 8; ++ct) { o[ct][0] = 0.f; o[ct][1] = 0.f; o[ct][2] = 0.f; o[ct][3] = 0.f; }
    float m[4] = {-INFINITY, -INFINITY, -INFINITY, -INFINITY};
    float l[4] = {0.f, 0.f, 0.f, 0.f};
    for (int kt = 0; kt < 128; ++kt) {
        // stage K row-major + V transposed (cooperative, coalesced global reads)
#pragma unroll
        for (int i = 0; i < 2; ++i) {
            int sid = tid + i * 256; int r = sid >> 4, sg = sid & 15;
            *(uint4*)&Ks[r][sg * 8] = *(const uint4*)&Kg[(size_t)(kt * 32 + r) * 512 + hh * 128 + sg * 8];
            uint4 w = *(const uint4*)&Vg[(size_t)(kt * 32 + r) * 512 + hh * 128 + sg * 8];
            ushort_t tmp[8]; *(uint4*)tmp = w;
#pragma unroll
            for (int j = 0; j < 8; ++j) Vt[sg * 8 + j][r] = tmp[j];
        }
        __syncthreads();
        // QK: S[q=lq*4+reg][krow=c*16+lrow]
        f32x4 sa[2];
#pragma unroll
        for (int c = 0; c < 2; ++c) { sa[c][0] = 0.f; sa[c][1] = 0.f; sa[c][2] = 0.f; sa[c][3] = 0.f; }
#pragma unroll
        for (int c = 0; c < 2; ++c)
#pragma unroll
            for (int st = 0; st < 4; ++st) {
                bf16x8 kf = *(const bf16x8*)&Ks[c * 16 + lrow][st * 32 + lq * 8];
                sa[c] = __builtin_amdgcn_mfma_f32_16x16x32_bf16(qf[st], kf, sa[c], 0, 0, 0);
            }
        // online softmax per owned row (reg r); row data spread over 16 lanes of this quad
        float al[4];
#pragma unroll
        for (int r = 0; r < 4; ++r) {
            float s0 = sa[0][r] * scale, s1 = sa[1][r] * scale;
            float tm = fmaxf(s0, s1);
#pragma unroll
            for (int off = 1; off < 16; off <<= 1) tm = fmaxf(tm, __shfl_xor(tm, off, 64));
            float mn = fmaxf(m[r], tm);
            float a = expf(m[r] - mn);          // first tile: exp(-inf)=0
            float p0 = expf(s0 - mn), p1 = expf(s1 - mn);
            float su = p0 + p1;
#pragma unroll
            for (int off = 1; off < 16; off <<= 1) su += __shfl_xor(su, off, 64);
            m[r] = mn; l[r] = l[r] * a + su; al[r] = a;
            Ps[wid][lq * 4 + r][lrow] = f2bf(p0);
            Ps[wid][lq * 4 + r][16 + lrow] = f2bf(p1);
        }
#pragma unroll
        for (int ct = 0; ct < 8; ++ct)
#pragma unroll
            for (int r = 0; r < 4; ++r) o[ct][r] *= al[r];
        __builtin_amdgcn_s_waitcnt(0);      // P writes visible to same-wave cross-lane reads
        bf16x8 pf = *(const bf16x8*)&Ps[wid][lrow][lq * 8];   // A[m=lrow][k=lq*8+j]
#pragma unroll
        for (int ct = 0; ct < 8; ++ct) {
            bf16x8 vf = *(const bf16x8*)&Vt[ct * 16 + lrow][lq * 8];
            o[ct] = __builtin_amdgcn_mfma_f32_16x16x32_bf16(pf, vf, o[ct], 0, 0, 0);
        }
        __syncthreads();    // protect Ks/Vt before next staging
    }
#pragma unroll
    for (int ct = 0; ct < 8; ++ct)
#pragma unroll
        for (int r = 0; r < 4; ++r)
            Qg[(size_t)(qb + wid * 16 + lq * 4 + r) * 512 + hh * 128 + ct * 16 + lrow] = f2bf(o[ct][r] / l[r]);
}

// ---------- residual add + layernorm: writes fp32 H and bf16 Hb ----------
__global__ __launch_bounds__(256) void k_add_ln(const float* __restrict__ A,
                                                const float* __restrict__ B,
                                                float* __restrict__ O,
                                                ushort_t* __restrict__ Ob,
                                                const float* __restrict__ g,
                                                const float* __restrict__ b) {
    __shared__ float xr[512];
    __shared__ float red[256];
    int row = blockIdx.x, t = threadIdx.x;
    const float* a = A + (size_t)row * 512;
    const float* bb = B + (size_t)row * 512;
    float ls = 0.f;
    for (int j = t; j < 512; j += 256) { float v = a[j] + bb[j]; xr[j] = v; ls += v; }
    red[t] = ls; __syncthreads();
    for (int o = 128; o; o >>= 1) { if (t < o) red[t] += red[t + o]; __syncthreads(); }
    float mean = red[0] / 512.0f; __syncthreads();
    float lv = 0.f;
    for (int j = t; j < 512; j += 256) { float d = xr[j] - mean; lv += d * d; }
    red[t] = lv; __syncthreads();
    for (int o = 128; o; o >>= 1) { if (t < o) red[t] += red[t + o]; __syncthreads(); }
    float inv = 1.0f / sqrtf(red[0] / 512.0f + 1e-5f);
    float* o_ = O + (size_t)row * 512;
    ushort_t* ob = Ob + (size_t)row * 512;
    for (int j = t; j < 512; j += 256) {
        float v = (xr[j] - mean) * inv * g[j] + b[j];
        o_[j] = v; ob[j] = f2bf(v);
    }
}

// ---------- fusion head ----------
__global__ __launch_bounds__(128) void k_fusion(const float* __restrict__ subv,
                                                const float* __restrict__ protv,
                                                const float* __restrict__ seqv,
                                                const float* __restrict__ Wtime,
                                                const float* __restrict__ btime,
                                                const float* __restrict__ Wout,
                                                const float* __restrict__ bout,
                                                const int* __restrict__ t_ptr,
                                                const int* __restrict__ lo_ptr,
                                                float* __restrict__ out) {
    __shared__ float cat[80];
    int t = threadIdx.x;
    int tval = guard_int(t_ptr[0], 0, 500);
    int L    = guard_int(lo_ptr[0], 0, 3);
    float tf = (float)((double)tval / 500.0);
    if (t < 20) {
        cat[t] = subv[t];
        cat[20 + t] = protv[t];
        cat[40 + t] = seqv[t];
        cat[60 + t] = tf * Wtime[t] + btime[t];
    }
    __syncthreads();
    for (int j = 0; j < L; ++j) {
        float acc = 0.f;
        if (t < 80) {
            for (int i2 = 0; i2 < 80; ++i2)
                acc += fmaxf(cat[i2], 0.f) * Wout[(size_t)j * 6400 + i2 * 80 + t];
            acc += bout[j * 80 + t];
        }
        __syncthreads();
        if (t < 80) cat[t] = acc;
        __syncthreads();
    }
    if (t < 80) out[t] = fmaxf(cat[t], 0.f);
    if (t < 20) out[80 + t] = seqv[t];
}

// ---------- launch ----------
extern "C" void kernel_launch(void* const* d_in, const int* in_sizes, int n_in,
                              void* d_out, int out_size, void* d_ws, size_t ws_size,
                              hipStream_t stream) {
    static const int EXP[39] = {
        81920, 65536, 200000, 2097152, 2560, 128, 8192, 64, 1280, 20,
        524288, 1024, 524288, 1024, 524288, 1024, 524288, 1024, 1024, 1024,
        2097152, 4096, 2097152, 1024, 1024, 1024, 10240, 20, 19200, 240,
        20, 20, 256, 4096, 4096, 131072, 1, 1, 1 };
    float code = 0.f;
    if (n_in != 39) code = 900.f;
    else {
        for (int i = 0; i < 39; ++i)
            if (in_sizes[i] != EXP[i]) { code = 500.f + 4.f * (float)i; break; }
    }
    const size_t REQ = (size_t)42 * 1024 * 1024;
    if (code == 0.f && ws_size < REQ) code = (float)(ws_size >> 20);
    float* out = (float*)d_out;
    if (code != 0.f) {
        k_sentinel<<<1, 128, 0, stream>>>(out, -code, out_size);
        return;
    }

    const float* x_in   = (const float*)d_in[0];
    const float* adjs_in= (const float*)d_in[1];
    const float* embfp  = (const float*)d_in[2];
    const float* embw   = (const float*)d_in[3];
    const float* gW1 = (const float*)d_in[4];  const float* gb1 = (const float*)d_in[5];
    const float* gW2 = (const float*)d_in[6];  const float* gb2 = (const float*)d_in[7];
    const float* gW3 = (const float*)d_in[8];  const float* gb3 = (const float*)d_in[9];
    const float* Wq  = (const float*)d_in[10]; const float* bq  = (const float*)d_in[11];
    const float* Wk  = (const float*)d_in[12]; const float* bk  = (const float*)d_in[13];
    const float* Wv  = (const float*)d_in[14]; const float* bv  = (const float*)d_in[15];
    const float* Wo  = (const float*)d_in[16]; const float* bo  = (const float*)d_in[17];
    const float* ln1g= (const float*)d_in[18]; const float* ln1b= (const float*)d_in[19];
    const float* Wff1= (const float*)d_in[20]; const float* bff1= (const float*)d_in[21];
    const float* Wff2= (const float*)d_in[22]; const float* bff2= (const float*)d_in[23];
    const float* ln2g= (const float*)d_in[24]; const float* ln2b= (const float*)d_in[25];
    const float* Wproj=(const float*)d_in[26]; const float* bproj=(const float*)d_in[27];
    const float* Woutw=(const float*)d_in[28]; const float* boutw=(const float*)d_in[29];
    const float* Wtime=(const float*)d_in[30]; const float* btime=(const float*)d_in[31];
    const int* fingerprints = (const int*)d_in[32];
    const int* words        = (const int*)d_in[33];
    const int* edge_index   = (const int*)d_in[35];
    const int* t_ptr        = (const int*)d_in[36];
    const int* lo_ptr       = (const int*)d_in[37];

    // ---- workspace (42 MiB) ----
    char* wsb = (char*)d_ws;
    float*    misc = (float*)wsb;
    float*    H    = (float*)(wsb + ((size_t)2  << 20));
    ushort_t* Hb   = (ushort_t*)(wsb + ((size_t)10 << 20));
    ushort_t* Qb   = (ushort_t*)(wsb + ((size_t)14 << 20));
    ushort_t* Kb   = (ushort_t*)(wsb + ((size_t)18 << 20));
    ushort_t* Vb   = (ushort_t*)(wsb + ((size_t)22 << 20));
    ushort_t* FFHb = (ushort_t*)(wsb + ((size_t)14 << 20));
    float*    T    = (float*)(wsb + ((size_t)30 << 20));
    ushort_t* Wscr = (ushort_t*)(wsb + ((size_t)38 << 20));
    unsigned* ADJB = (unsigned*)Qb;
    float* pt0  = (float*)Kb;
    float* ph1  = pt0 + 81920;
    float* pt1  = ph1 + 524288;
    float* ph2  = pt1 + 524288;
    float* pt2  = ph2 + 262144;
    float* pgo  = pt2 + 262144;
    float* Xoh  = misc;
    float* fpv  = misc + 81920;
    float* st0  = misc + 87040;
    float* sh1  = misc + 92160;
    float* st1  = misc + 124928;
    float* sh2  = misc + 157696;
    float* st2  = misc + 174080;
    float* sgo  = misc + 190464;
    float* P    = misc + 195584;
    float* subv = misc + 277504;
    float* protv= misc + 277536;
    float* seqv = misc + 277568;

    auto g2 = [](int M, int N) { return dim3((unsigned)((N + 63) / 64), (unsigned)((M + 63) / 64), 1); };
    auto gm = [](int M, int N) { return dim3((unsigned)(N / 64), (unsigned)(M / 64), 1); };
    auto gt = [](int Kd, int Nd) { return dim3((unsigned)(Nd / 32), (unsigned)(Kd / 32), 1); };

    // 1. diffusion sampling
    k_sample<<<16, 256, 0, stream>>>(x_in, t_ptr, Xoh);

    // 2. substrate GCN (fp32)
    k_gather_fp<<<20, 256, 0, stream>>>(embfp, fingerprints, fpv);
    k_gemm_nn<false><<<g2(256, 20), 256, 0, stream>>>(256, 20, 256, adjs_in, 256, fpv, 20, st0, 20, nullptr);
    k_gemm_nn<true ><<<g2(256, 128), 256, 0, stream>>>(256, 128, 20, st0, 20, gW1, 128, sh1, 128, gb1);
    k_gemm_nn<false><<<g2(256, 128), 256, 0, stream>>>(256, 128, 256, adjs_in, 256, sh1, 128, st1, 128, nullptr);
    k_gemm_nn<true ><<<g2(256, 64), 256, 0, stream>>>(256, 64, 128, st1, 128, gW2, 64, sh2, 64, gb2);
    k_gemm_nn<false><<<g2(256, 64), 256, 0, stream>>>(256, 64, 256, adjs_in, 256, sh2, 64, st2, 64, nullptr);
    k_gemm_nn<false><<<g2(256, 20), 256, 0, stream>>>(256, 20, 64, st2, 64, gW3, 20, sgo, 20, gb3);
    k_colmean<<<20, 256, 0, stream>>>(sgo, 256, 20, subv);

    // 3. transformer (bf16 MFMA GEMMs + MFMA flash)
    k_embed<<<8192, 256, 0, stream>>>(embw, words, H, Hb);
    for (int l = 0; l < 2; ++l) {
        const float* wq = Wq + (size_t)l * 262144;
        const float* wk = Wk + (size_t)l * 262144;
        const float* wv = Wv + (size_t)l * 262144;
        const float* wo = Wo + (size_t)l * 262144;
        ushort_t* wqb = Wscr;
        ushort_t* wkb = Wscr + 262144;
        ushort_t* wvb = Wscr + 524288;
        ushort_t* wob = Wscr + 786432;
        k_castT<<<gt(512, 512), 256, 0, stream>>>(wq, wqb, 512, 512);
        k_castT<<<gt(512, 512), 256, 0, stream>>>(wk, wkb, 512, 512);
        k_castT<<<gt(512, 512), 256, 0, stream>>>(wv, wvb, 512, 512);
        k_castT<<<gt(512, 512), 256, 0, stream>>>(wo, wob, 512, 512);
        k_gemm_mfma<false, ushort_t><<<gm(4096, 512), 256, 0, stream>>>(4096, 512, 512, Hb, wqb, Qb, 512, bq + l * 512);
        k_gemm_mfma<false, ushort_t><<<gm(4096, 512), 256, 0, stream>>>(4096, 512, 512, Hb, wkb, Kb, 512, bk + l * 512);
        k_gemm_mfma<false, ushort_t><<<gm(4096, 512), 256, 0, stream>>>(4096, 512, 512, Hb, wvb, Vb, 512, bv + l * 512);
        k_flash<<<dim3(64, 4, 1), 256, 0, stream>>>(Qb, Kb, Vb);    // O -> Qb (bf16)
        k_gemm_mfma<false, float><<<gm(4096, 512), 256, 0, stream>>>(4096, 512, 512, Qb, wob, T, 512, bo + l * 512);
        k_add_ln<<<4096, 256, 0, stream>>>(H, T, H, Hb, ln1g + l * 512, ln1b + l * 512);
        k_castT<<<gt(512, 2048), 256, 0, stream>>>(Wff1 + (size_t)l * 1048576, Wscr, 512, 2048);
        k_gemm_mfma<true, ushort_t><<<gm(4096, 2048), 256, 0, stream>>>(4096, 2048, 512, Hb, Wscr, FFHb, 2048, bff1 + l * 2048);
        k_castT<<<gt(2048, 512), 256, 0, stream>>>(Wff2 + (size_t)l * 1048576, Wscr, 2048, 512);
        k_gemm_mfma<false, float><<<gm(4096, 512), 256, 0, stream>>>(4096, 512, 2048, FFHb, Wscr, T, 512, bff2 + l * 512);
        k_add_ln<<<4096, 256, 0, stream>>>(H, T, H, Hb, ln2g + l * 512, ln2b + l * 512);
    }

    // 4. projection + mean -> seq (fp32)
    k_gemm_nn<false><<<g2(4096, 20), 256, 0, stream>>>(4096, 20, 512, H, 512, Wproj, 20, P, 20, bproj);
    k_colmean<<<20, 256, 0, stream>>>(P, 4096, 20, seqv);

    // 5. protein GCN
    hipMemsetAsync(ADJB, 0, (size_t)4096 * 128 * 4, stream);
    k_scatter_bits<<<256, 256, 0, stream>>>(edge_index, ADJB);
    k_spmm_bits<20, 1><<<16, 256, 0, stream>>>(ADJB, Xoh, 20, pt0, 20);
    k_gemm_nn<true ><<<g2(4096, 128), 256, 0, stream>>>(4096, 128, 20, pt0, 20, gW1, 128, ph1, 128, gb1);
    k_spmm_bits<32, 4><<<64, 256, 0, stream>>>(ADJB, ph1, 128, pt1, 128);
    k_gemm_nn<true ><<<g2(4096, 64), 256, 0, stream>>>(4096, 64, 128, pt1, 128, gW2, 64, ph2, 64, gb2);
    k_spmm_bits<32, 2><<<32, 256, 0, stream>>>(ADJB, ph2, 64, pt2, 64);
    k_gemm_nn<false><<<g2(4096, 20), 256, 0, stream>>>(4096, 20, 64, pt2, 64, gW3, 20, pgo, 20, gb3);
    k_colmean<<<20, 256, 0, stream>>>(pgo, 4096, 20, protv);

    // 6. fusion head
    k_fusion<<<1, 128, 0, stream>>>(subv, protv, seqv, Wtime, btime, Woutw, boutw, t_ptr, lo_ptr, out);
}

// Round 11
// 1352.174 us; speedup vs baseline: 6.9489x; 1.2039x over previous
//
#include <hip/hip_runtime.h>
#include <math.h>

typedef unsigned short ushort_t;
typedef __attribute__((ext_vector_type(8))) short bf16x8;
typedef __attribute__((ext_vector_type(4))) float f32x4;

// ---------- helpers ----------
__device__ inline float bf2f(unsigned u) { return __uint_as_float((u & 0xffffu) << 16); }
__device__ inline ushort_t f2bf(float f) {
    unsigned u = __float_as_uint(f);
    return (ushort_t)((u + 0x7fffu + ((u >> 16) & 1u)) >> 16);   // RNE
}
__device__ inline void stv(float* p, float v) { *p = v; }
__device__ inline void stv(ushort_t* p, float v) { *p = f2bf(v); }
__device__ inline int guard_int(int raw, int lo, int hi) {
    if (raw >= lo && raw <= hi) return raw;
    float f = __int_as_float(raw);
    int v = (int)f;
    return (v >= lo && v <= hi) ? v : lo;
}

// ---------- threefry2x32 (JAX partitionable, verified R7) ----------
__device__ inline void tf2x32(unsigned k0, unsigned k1, unsigned x0, unsigned x1,
                              unsigned& o0, unsigned& o1) {
    unsigned ks2 = k0 ^ k1 ^ 0x1BD11BDAu;
    x0 += k0; x1 += k1;
#define TFR(r) { x0 += x1; x1 = (x1 << (r)) | (x1 >> (32 - (r))); x1 ^= x0; }
    TFR(13) TFR(15) TFR(26) TFR(6)  x0 += k1;  x1 += ks2 + 1u;
    TFR(17) TFR(29) TFR(16) TFR(24) x0 += ks2; x1 += k0 + 2u;
    TFR(13) TFR(15) TFR(26) TFR(6)  x0 += k0;  x1 += k1 + 3u;
    TFR(17) TFR(29) TFR(16) TFR(24) x0 += k1;  x1 += ks2 + 4u;
    TFR(13) TFR(15) TFR(26) TFR(6)  x0 += ks2; x1 += k0 + 5u;
#undef TFR
    o0 = x0; o1 = x1;
}

__global__ void k_sentinel(float* __restrict__ out, float val, int n) {
    int i = blockIdx.x * 128 + threadIdx.x;
    if (i < n) out[i] = val;
}

// ---------- diffusion categorical sampling -> one-hot X ----------
__global__ __launch_bounds__(256) void k_sample(const float* __restrict__ x,
                                                const int* __restrict__ t_ptr,
                                                float* __restrict__ X) {
    int i = blockIdx.x * 256 + threadIdx.x;
    if (i >= 4096) return;
    int tval = guard_int(t_ptr[0], 0, 500);
    double tf = (double)tval / 500.0;
    const double sc = 0.008;
    const double PI_HALF = 1.5707963267948966;
    double num = cos((tf + sc) / (1.0 + sc) * PI_HALF);
    double den = cos(sc / (1.0 + sc) * PI_HALF);
    float ab = (float)((num * num) / (den * den));
    float phi = (1.0f - ab) / 20.0f;
    float xv[20]; float sx = 0.f;
    for (int j = 0; j < 20; ++j) { xv[j] = x[i * 20 + j]; sx += xv[j]; }
    float best = -1e30f; int bj = 0;
    for (int j = 0; j < 20; ++j) {
        float prob = fmaxf(ab * xv[j] + phi * sx, 0.0f);
        float lp = logf(prob + 1e-9f);
        unsigned m = (unsigned)(i * 20 + j);
        unsigned o0, o1;
        tf2x32(0u, 42u, 0u, m, o0, o1);
        unsigned bits = o0 ^ o1;
        float u = __uint_as_float((bits >> 9) | 0x3f800000u) - 1.0f;
        if (u < 1.1754943508222875e-38f) u = 1.1754943508222875e-38f;
        float gmb = -logf(-logf(u));
        float z = lp + gmb;
        if (z > best) { best = z; bj = j; }
    }
    for (int j = 0; j < 20; ++j) X[i * 20 + j] = (j == bj) ? 1.0f : 0.0f;
}

// ---------- small utility kernels ----------
__global__ __launch_bounds__(256) void k_gather_fp(const float* __restrict__ emb,
                                                   const int* __restrict__ idx,
                                                   float* __restrict__ out) {
    int i = blockIdx.x * 256 + threadIdx.x;
    if (i >= 256 * 20) return;
    int a = i / 20, d = i % 20;
    out[i] = emb[(size_t)idx[a] * 20 + d];
}

__global__ __launch_bounds__(256) void k_scatter_bits(const int* __restrict__ ei,
                                                      unsigned* __restrict__ bits) {
    int e = blockIdx.x * 256 + threadIdx.x;
    if (e >= 65536) return;
    int r = ei[e], c = ei[65536 + e];
    atomicOr(&bits[(size_t)r * 128 + (c >> 5)], 1u << (c & 31));
}

__global__ __launch_bounds__(256) void k_embed(const float* __restrict__ embw,
                                               const int* __restrict__ words,
                                               float* __restrict__ H,
                                               ushort_t* __restrict__ Hb) {
    int idx = blockIdx.x * 256 + threadIdx.x;
    if (idx >= 4096 * 512) return;
    int pos = idx >> 9, d = idx & 511;
    float e = embw[(size_t)words[pos] * 512 + d];
    float expo = (float)(d >> 1) * (1.0f / 256.0f);
    float ang = (float)pos * exp2f(-expo * 13.287712379549449f);
    float pe = (d & 1) ? cosf(ang) : sinf(ang);
    float v = e + pe;
    H[idx] = v; Hb[idx] = f2bf(v);
}

__global__ __launch_bounds__(256) void k_colmean(const float* __restrict__ M, int R, int C,
                                                 float* __restrict__ out) {
    __shared__ float red[256];
    int c = blockIdx.x, t = threadIdx.x;
    float s = 0.f;
    for (int r = t; r < R; r += 256) s += M[(size_t)r * C + c];
    red[t] = s; __syncthreads();
    for (int o = 128; o; o >>= 1) { if (t < o) red[t] += red[t + o]; __syncthreads(); }
    if (t == 0) out[c] = red[0] / (float)R;
}

// ---------- weight cast+transpose: fp32 [K,N] -> bf16 [N,K] ----------
__global__ __launch_bounds__(256) void k_castT(const float* __restrict__ in,
                                               ushort_t* __restrict__ out,
                                               int Kd, int Nd) {
    __shared__ float t[32][33];
    int bx = blockIdx.x * 32, by = blockIdx.y * 32;
    int tx = threadIdx.x & 31, ty = threadIdx.x >> 5;
#pragma unroll
    for (int i = 0; i < 4; ++i)
        t[ty + i * 8][tx] = in[(size_t)(by + ty + i * 8) * Nd + bx + tx];
    __syncthreads();
#pragma unroll
    for (int i = 0; i < 4; ++i)
        out[(size_t)(bx + ty + i * 8) * Kd + by + tx] = f2bf(t[tx][ty + i * 8]);
}

// ---------- bf16 transpose: in [4096][512] -> out [512][4096] ----------
__global__ __launch_bounds__(256) void k_transposeV(const ushort_t* __restrict__ in,
                                                    ushort_t* __restrict__ out) {
    __shared__ ushort_t t[32][33];
    int bx = blockIdx.x * 32;   // col of in / row of out (d)
    int by = blockIdx.y * 32;   // row of in (S)
    int tx = threadIdx.x & 31, ty = threadIdx.x >> 5;
#pragma unroll
    for (int i = 0; i < 4; ++i)
        t[ty + i * 8][tx] = in[(size_t)(by + ty + i * 8) * 512 + bx + tx];
    __syncthreads();
#pragma unroll
    for (int i = 0; i < 4; ++i)
        out[(size_t)(bx + ty + i * 8) * 4096 + by + tx] = t[tx][ty + i * 8];
}

// ---------- MFMA bf16 GEMM: C[M,N] = A[M,K](bf16) @ Bt[N,K](bf16) + bias ----------
template<bool RELU, typename TC>
__global__ __launch_bounds__(256) void k_gemm_mfma(int M, int N, int K,
        const ushort_t* __restrict__ A,
        const ushort_t* __restrict__ Bt,
        TC* __restrict__ C, int ldc,
        const float* __restrict__ bias) {
    __shared__ ushort_t As[64][40];
    __shared__ ushort_t Bs[64][40];
    int tid = threadIdx.x;
    int lane = tid & 63, wave = tid >> 6;
    int wr = wave >> 1, wc = wave & 1;
    int lrow = lane & 15, lq = lane >> 4;
    int br = blockIdx.y * 64, bc = blockIdx.x * 64;
    f32x4 acc[2][2];
#pragma unroll
    for (int i = 0; i < 2; ++i)
#pragma unroll
        for (int j = 0; j < 2; ++j) { acc[i][j][0] = 0.f; acc[i][j][1] = 0.f; acc[i][j][2] = 0.f; acc[i][j][3] = 0.f; }
    int sr = tid >> 2, sseg = tid & 3;
    for (int k0 = 0; k0 < K; k0 += 32) {
        *(uint4*)&As[sr][sseg * 8] = *(const uint4*)&A[(size_t)(br + sr) * K + k0 + sseg * 8];
        *(uint4*)&Bs[sr][sseg * 8] = *(const uint4*)&Bt[(size_t)(bc + sr) * K + k0 + sseg * 8];
        __syncthreads();
        bf16x8 af[2], bfr[2];
#pragma unroll
        for (int i = 0; i < 2; ++i) {
            af[i]  = *(const bf16x8*)&As[wr * 32 + i * 16 + lrow][lq * 8];
            bfr[i] = *(const bf16x8*)&Bs[wc * 32 + i * 16 + lrow][lq * 8];
        }
#pragma unroll
        for (int i = 0; i < 2; ++i)
#pragma unroll
            for (int j = 0; j < 2; ++j)
                acc[i][j] = __builtin_amdgcn_mfma_f32_16x16x32_bf16(af[i], bfr[j], acc[i][j], 0, 0, 0);
        __syncthreads();
    }
#pragma unroll
    for (int i = 0; i < 2; ++i)
#pragma unroll
        for (int j = 0; j < 2; ++j) {
            int col = bc + wc * 32 + j * 16 + lrow;
            float bv = bias ? bias[col] : 0.f;
#pragma unroll
            for (int r = 0; r < 4; ++r) {
                int row = br + wr * 32 + i * 16 + lq * 4 + r;
                float v = acc[i][j][r] + bv;
                if (RELU) v = fmaxf(v, 0.f);
                stv(&C[(size_t)row * ldc + col], v);
            }
        }
}

// ---------- fp32 GEMM (small/odd shapes) ----------
template<bool RELU>
__global__ __launch_bounds__(256) void k_gemm_nn(int M, int N, int K,
        const float* __restrict__ A, int lda,
        const float* __restrict__ B, int ldb,
        float* __restrict__ C, int ldc,
        const float* __restrict__ bias) {
    __shared__ float As[16][65];
    __shared__ float Bs[16][65];
    int tid = threadIdx.x;
    int tx = tid & 15, ty = tid >> 4;
    int br = blockIdx.y * 64, bc = blockIdx.x * 64;
    float acc[4][4] = {};
    for (int k0 = 0; k0 < K; k0 += 16) {
#pragma unroll
        for (int c0 = 0; c0 < 4; ++c0) {
            int r = (tid >> 4) + c0 * 16, kk = tid & 15;
            int gr = br + r, gk = k0 + kk;
            As[kk][r] = (gr < M && gk < K) ? A[(size_t)gr * lda + gk] : 0.f;
        }
#pragma unroll
        for (int c0 = 0; c0 < 4; ++c0) {
            int col = tid & 63, kk = (tid >> 6) + c0 * 4;
            int gc = bc + col, gk = k0 + kk;
            Bs[kk][col] = (gc < N && gk < K) ? B[(size_t)gk * ldb + gc] : 0.f;
        }
        __syncthreads();
#pragma unroll
        for (int kk = 0; kk < 16; ++kk) {
            float av[4], bv[4];
#pragma unroll
            for (int i2 = 0; i2 < 4; ++i2) av[i2] = As[kk][ty + 16 * i2];
#pragma unroll
            for (int j2 = 0; j2 < 4; ++j2) bv[j2] = Bs[kk][tx + 16 * j2];
#pragma unroll
            for (int i2 = 0; i2 < 4; ++i2)
#pragma unroll
                for (int j2 = 0; j2 < 4; ++j2) acc[i2][j2] += av[i2] * bv[j2];
        }
        __syncthreads();
    }
#pragma unroll
    for (int i2 = 0; i2 < 4; ++i2)
#pragma unroll
        for (int j2 = 0; j2 < 4; ++j2) {
            int r = br + ty + 16 * i2, c = bc + tx + 16 * j2;
            if (r < M && c < N) {
                float v = acc[i2][j2];
                if (bias) v += bias[c];
                if (RELU) v = fmaxf(v, 0.f);
                C[(size_t)r * ldc + c] = v;
            }
        }
}

// ---------- SpMM: C[4096,N] = BITS @ B ----------
template<int NC, int CHUNKS>
__global__ __launch_bounds__(256) void k_spmm_bits(
        const unsigned* __restrict__ BITS,
        const float* __restrict__ B, int ldb,
        float* __restrict__ C, int ldc) {
    int t = blockIdx.x * 256 + threadIdx.x;
    int r = t / CHUNKS;
    int cb = (t % CHUNKS) * NC;
    if (r >= 4096) return;
    float acc[NC];
#pragma unroll
    for (int j = 0; j < NC; ++j) acc[j] = 0.f;
    const unsigned* bw = &BITS[(size_t)r * 128];
    for (int w = 0; w < 128; ++w) {
        unsigned bits = bw[w];
        while (bits) {
            int b = __ffs(bits) - 1; bits &= bits - 1;
            const float* brow = &B[(size_t)(w * 32 + b) * ldb + cb];
#pragma unroll
            for (int j = 0; j < NC; ++j) acc[j] += brow[j];
        }
    }
#pragma unroll
    for (int j = 0; j < NC; ++j) C[(size_t)r * ldc + cb + j] = acc[j];
}

// ---------- MFMA flash v3: S computed TRANSPOSED (k-values land in registers),
// softmax = in-lane reduce + 2 shfl; V pre-transposed in global (VTg [512][4096]),
// staged conflict-free. bf16 in/out, fp32 softmax, O in-place over Q. ----------
__global__ __launch_bounds__(256) void k_flash(ushort_t* __restrict__ Qg,
                                               const ushort_t* __restrict__ Kg,
                                               const ushort_t* __restrict__ VTg) {
    __shared__ ushort_t Ks[32][136];    // K-tile row-major
    __shared__ ushort_t Vt[128][40];    // V^T tile: [vcol][krow], coalesced writes
    __shared__ ushort_t Ps[4][16][40];  // per-wave P [q][krow] (A-layout)
    __shared__ float    as_[4][16];     // per-wave alpha per q
    __shared__ float    ls_[4][16];     // per-wave l per q
    const int tid = threadIdx.x;
    const int lane = tid & 63, wid = tid >> 6;
    const int lrow = lane & 15, lq = lane >> 4;
    const int qb = blockIdx.x * 64, hh = blockIdx.y;
    const float scale = 0.08838834764831845f;   // 1/sqrt(128)
    // Q fragments (B-operand): B[n=lrow][k=lq*8+j + 32*st]
    bf16x8 qf[4];
    {
        const ushort_t* qrow = &Qg[(size_t)(qb + wid * 16 + lrow) * 512 + hh * 128 + lq * 8];
#pragma unroll
        for (int s = 0; s < 4; ++s) qf[s] = *(const bf16x8*)&qrow[s * 32];
    }
    f32x4 o[8];
#pragma unroll
    for (int ct = 0; ct < 8; ++ct) { o[ct][0] = 0.f; o[ct][1] = 0.f; o[ct][2] = 0.f; o[ct][3] = 0.f; }
    float m = -INFINITY, l = 0.f;       // per-lane: q = lrow
    for (int kt = 0; kt < 128; ++kt) {
        // stage K (row-major) + V^T (coalesced uint4, no scatter)
#pragma unroll
        for (int i = 0; i < 2; ++i) {
            int sid = tid + i * 256;
            int r = sid >> 4, sg = sid & 15;
            *(uint4*)&Ks[r][sg * 8] = *(const uint4*)&Kg[(size_t)(kt * 32 + r) * 512 + hh * 128 + sg * 8];
            int d = sid >> 2, c8 = sid & 3;
            *(uint4*)&Vt[d][c8 * 8] = *(const uint4*)&VTg[(size_t)(hh * 128 + d) * 4096 + kt * 32 + c8 * 8];
        }
        __syncthreads();
        // S^T: D[m=krow][n=q]  via mfma(A=K, B=Q)
        f32x4 sa[2];
#pragma unroll
        for (int c = 0; c < 2; ++c) { sa[c][0] = 0.f; sa[c][1] = 0.f; sa[c][2] = 0.f; sa[c][3] = 0.f; }
#pragma unroll
        for (int c = 0; c < 2; ++c)
#pragma unroll
            for (int st = 0; st < 4; ++st) {
                bf16x8 kf = *(const bf16x8*)&Ks[c * 16 + lrow][st * 32 + lq * 8];
                sa[c] = __builtin_amdgcn_mfma_f32_16x16x32_bf16(kf, qf[st], sa[c], 0, 0, 0);
            }
        // online softmax: lane owns q=lrow, 8 k-values in regs (krow = c*16 + lq*4 + r)
        float s[8];
        float tm = -INFINITY;
#pragma unroll
        for (int c = 0; c < 2; ++c)
#pragma unroll
            for (int r = 0; r < 4; ++r) { float v = sa[c][r] * scale; s[c * 4 + r] = v; tm = fmaxf(tm, v); }
        tm = fmaxf(tm, __shfl_xor(tm, 16));
        tm = fmaxf(tm, __shfl_xor(tm, 32));
        float mn = fmaxf(m, tm);
        float a = expf(m - mn);             // first tile: exp(-inf)=0
        float su = 0.f;
        float p[8];
#pragma unroll
        for (int i = 0; i < 8; ++i) { p[i] = expf(s[i] - mn); su += p[i]; }
        su += __shfl_xor(su, 16);
        su += __shfl_xor(su, 32);
        m = mn; l = l * a + su;
#pragma unroll
        for (int c = 0; c < 2; ++c)
#pragma unroll
            for (int r = 0; r < 4; ++r)
                Ps[wid][lrow][c * 16 + lq * 4 + r] = f2bf(p[c * 4 + r]);
        if (lq == 0) as_[wid][lrow] = a;
        __builtin_amdgcn_s_waitcnt(0);      // same-wave LDS visibility
        float av[4];
#pragma unroll
        for (int r = 0; r < 4; ++r) av[r] = as_[wid][lq * 4 + r];
#pragma unroll
        for (int ct = 0; ct < 8; ++ct)
#pragma unroll
            for (int r = 0; r < 4; ++r) o[ct][r] *= av[r];
        bf16x8 pf = *(const bf16x8*)&Ps[wid][lrow][lq * 8];   // A[m=q][k=lq*8+j]
#pragma unroll
        for (int ct = 0; ct < 8; ++ct) {
            bf16x8 vf = *(const bf16x8*)&Vt[ct * 16 + lrow][lq * 8];
            o[ct] = __builtin_amdgcn_mfma_f32_16x16x32_bf16(pf, vf, o[ct], 0, 0, 0);
        }
        __syncthreads();    // protect Ks/Vt before next staging
    }
    if (lq == 0) ls_[wid][lrow] = l;
    __builtin_amdgcn_s_waitcnt(0);
    float lv[4];
#pragma unroll
    for (int r = 0; r < 4; ++r) lv[r] = 1.0f / ls_[wid][lq * 4 + r];
#pragma unroll
    for (int ct = 0; ct < 8; ++ct)
#pragma unroll
        for (int r = 0; r < 4; ++r)
            Qg[(size_t)(qb + wid * 16 + lq * 4 + r) * 512 + hh * 128 + ct * 16 + lrow] = f2bf(o[ct][r] * lv[r]);
}

// ---------- residual add + layernorm: writes fp32 H and bf16 Hb ----------
__global__ __launch_bounds__(256) void k_add_ln(const float* __restrict__ A,
                                                const float* __restrict__ B,
                                                float* __restrict__ O,
                                                ushort_t* __restrict__ Ob,
                                                const float* __restrict__ g,
                                                const float* __restrict__ b) {
    __shared__ float xr[512];
    __shared__ float red[256];
    int row = blockIdx.x, t = threadIdx.x;
    const float* a = A + (size_t)row * 512;
    const float* bb = B + (size_t)row * 512;
    float ls = 0.f;
    for (int j = t; j < 512; j += 256) { float v = a[j] + bb[j]; xr[j] = v; ls += v; }
    red[t] = ls; __syncthreads();
    for (int o = 128; o; o >>= 1) { if (t < o) red[t] += red[t + o]; __syncthreads(); }
    float mean = red[0] / 512.0f; __syncthreads();
    float lv = 0.f;
    for (int j = t; j < 512; j += 256) { float d = xr[j] - mean; lv += d * d; }
    red[t] = lv; __syncthreads();
    for (int o = 128; o; o >>= 1) { if (t < o) red[t] += red[t + o]; __syncthreads(); }
    float inv = 1.0f / sqrtf(red[0] / 512.0f + 1e-5f);
    float* o_ = O + (size_t)row * 512;
    ushort_t* ob = Ob + (size_t)row * 512;
    for (int j = t; j < 512; j += 256) {
        float v = (xr[j] - mean) * inv * g[j] + b[j];
        o_[j] = v; ob[j] = f2bf(v);
    }
}

// ---------- fusion head ----------
__global__ __launch_bounds__(128) void k_fusion(const float* __restrict__ subv,
                                                const float* __restrict__ protv,
                                                const float* __restrict__ seqv,
                                                const float* __restrict__ Wtime,
                                                const float* __restrict__ btime,
                                                const float* __restrict__ Wout,
                                                const float* __restrict__ bout,
                                                const int* __restrict__ t_ptr,
                                                const int* __restrict__ lo_ptr,
                                                float* __restrict__ out) {
    __shared__ float cat[80];
    int t = threadIdx.x;
    int tval = guard_int(t_ptr[0], 0, 500);
    int L    = guard_int(lo_ptr[0], 0, 3);
    float tf = (float)((double)tval / 500.0);
    if (t < 20) {
        cat[t] = subv[t];
        cat[20 + t] = protv[t];
        cat[40 + t] = seqv[t];
        cat[60 + t] = tf * Wtime[t] + btime[t];
    }
    __syncthreads();
    for (int j = 0; j < L; ++j) {
        float acc = 0.f;
        if (t < 80) {
            for (int i2 = 0; i2 < 80; ++i2)
                acc += fmaxf(cat[i2], 0.f) * Wout[(size_t)j * 6400 + i2 * 80 + t];
            acc += bout[j * 80 + t];
        }
        __syncthreads();
        if (t < 80) cat[t] = acc;
        __syncthreads();
    }
    if (t < 80) out[t] = fmaxf(cat[t], 0.f);
    if (t < 20) out[80 + t] = seqv[t];
}

// ---------- launch ----------
extern "C" void kernel_launch(void* const* d_in, const int* in_sizes, int n_in,
                              void* d_out, int out_size, void* d_ws, size_t ws_size,
                              hipStream_t stream) {
    static const int EXP[39] = {
        81920, 65536, 200000, 2097152, 2560, 128, 8192, 64, 1280, 20,
        524288, 1024, 524288, 1024, 524288, 1024, 524288, 1024, 1024, 1024,
        2097152, 4096, 2097152, 1024, 1024, 1024, 10240, 20, 19200, 240,
        20, 20, 256, 4096, 4096, 131072, 1, 1, 1 };
    float code = 0.f;
    if (n_in != 39) code = 900.f;
    else {
        for (int i = 0; i < 39; ++i)
            if (in_sizes[i] != EXP[i]) { code = 500.f + 4.f * (float)i; break; }
    }
    const size_t REQ = (size_t)46 * 1024 * 1024;
    if (code == 0.f && ws_size < REQ) code = (float)(ws_size >> 20);
    float* out = (float*)d_out;
    if (code != 0.f) {
        k_sentinel<<<1, 128, 0, stream>>>(out, -code, out_size);
        return;
    }

    const float* x_in   = (const float*)d_in[0];
    const float* adjs_in= (const float*)d_in[1];
    const float* embfp  = (const float*)d_in[2];
    const float* embw   = (const float*)d_in[3];
    const float* gW1 = (const float*)d_in[4];  const float* gb1 = (const float*)d_in[5];
    const float* gW2 = (const float*)d_in[6];  const float* gb2 = (const float*)d_in[7];
    const float* gW3 = (const float*)d_in[8];  const float* gb3 = (const float*)d_in[9];
    const float* Wq  = (const float*)d_in[10]; const float* bq  = (const float*)d_in[11];
    const float* Wk  = (const float*)d_in[12]; const float* bk  = (const float*)d_in[13];
    const float* Wv  = (const float*)d_in[14]; const float* bv  = (const float*)d_in[15];
    const float* Wo  = (const float*)d_in[16]; const float* bo  = (const float*)d_in[17];
    const float* ln1g= (const float*)d_in[18]; const float* ln1b= (const float*)d_in[19];
    const float* Wff1= (const float*)d_in[20]; const float* bff1= (const float*)d_in[21];
    const float* Wff2= (const float*)d_in[22]; const float* bff2= (const float*)d_in[23];
    const float* ln2g= (const float*)d_in[24]; const float* ln2b= (const float*)d_in[25];
    const float* Wproj=(const float*)d_in[26]; const float* bproj=(const float*)d_in[27];
    const float* Woutw=(const float*)d_in[28]; const float* boutw=(const float*)d_in[29];
    const float* Wtime=(const float*)d_in[30]; const float* btime=(const float*)d_in[31];
    const int* fingerprints = (const int*)d_in[32];
    const int* words        = (const int*)d_in[33];
    const int* edge_index   = (const int*)d_in[35];
    const int* t_ptr        = (const int*)d_in[36];
    const int* lo_ptr       = (const int*)d_in[37];

    // ---- workspace (46 MiB) ----
    char* wsb = (char*)d_ws;
    float*    misc = (float*)wsb;
    float*    H    = (float*)(wsb + ((size_t)2  << 20));
    ushort_t* Hb   = (ushort_t*)(wsb + ((size_t)10 << 20));
    ushort_t* Qb   = (ushort_t*)(wsb + ((size_t)14 << 20));
    ushort_t* Kb   = (ushort_t*)(wsb + ((size_t)18 << 20));
    ushort_t* Vb   = (ushort_t*)(wsb + ((size_t)22 << 20));
    ushort_t* FFHb = (ushort_t*)(wsb + ((size_t)14 << 20));
    float*    T    = (float*)(wsb + ((size_t)30 << 20));
    ushort_t* Wscr = (ushort_t*)(wsb + ((size_t)38 << 20));
    ushort_t* VTg  = (ushort_t*)(wsb + ((size_t)42 << 20));   // V^T [512][4096] bf16
    unsigned* ADJB = (unsigned*)Qb;
    float* pt0  = (float*)Kb;
    float* ph1  = pt0 + 81920;
    float* pt1  = ph1 + 524288;
    float* ph2  = pt1 + 524288;
    float* pt2  = ph2 + 262144;
    float* pgo  = pt2 + 262144;
    float* Xoh  = misc;
    float* fpv  = misc + 81920;
    float* st0  = misc + 87040;
    float* sh1  = misc + 92160;
    float* st1  = misc + 124928;
    float* sh2  = misc + 157696;
    float* st2  = misc + 174080;
    float* sgo  = misc + 190464;
    float* P    = misc + 195584;
    float* subv = misc + 277504;
    float* protv= misc + 277536;
    float* seqv = misc + 277568;

    auto g2 = [](int M, int N) { return dim3((unsigned)((N + 63) / 64), (unsigned)((M + 63) / 64), 1); };
    auto gm = [](int M, int N) { return dim3((unsigned)(N / 64), (unsigned)(M / 64), 1); };
    auto gt = [](int Kd, int Nd) { return dim3((unsigned)(Nd / 32), (unsigned)(Kd / 32), 1); };

    // 1. diffusion sampling
    k_sample<<<16, 256, 0, stream>>>(x_in, t_ptr, Xoh);

    // 2. substrate GCN (fp32)
    k_gather_fp<<<20, 256, 0, stream>>>(embfp, fingerprints, fpv);
    k_gemm_nn<false><<<g2(256, 20), 256, 0, stream>>>(256, 20, 256, adjs_in, 256, fpv, 20, st0, 20, nullptr);
    k_gemm_nn<true ><<<g2(256, 128), 256, 0, stream>>>(256, 128, 20, st0, 20, gW1, 128, sh1, 128, gb1);
    k_gemm_nn<false><<<g2(256, 128), 256, 0, stream>>>(256, 128, 256, adjs_in, 256, sh1, 128, st1, 128, nullptr);
    k_gemm_nn<true ><<<g2(256, 64), 256, 0, stream>>>(256, 64, 128, st1, 128, gW2, 64, sh2, 64, gb2);
    k_gemm_nn<false><<<g2(256, 64), 256, 0, stream>>>(256, 64, 256, adjs_in, 256, sh2, 64, st2, 64, nullptr);
    k_gemm_nn<false><<<g2(256, 20), 256, 0, stream>>>(256, 20, 64, st2, 64, gW3, 20, sgo, 20, gb3);
    k_colmean<<<20, 256, 0, stream>>>(sgo, 256, 20, subv);

    // 3. transformer (bf16 MFMA GEMMs + MFMA flash v3)
    k_embed<<<8192, 256, 0, stream>>>(embw, words, H, Hb);
    for (int l = 0; l < 2; ++l) {
        const float* wq = Wq + (size_t)l * 262144;
        const float* wk = Wk + (size_t)l * 262144;
        const float* wv = Wv + (size_t)l * 262144;
        const float* wo = Wo + (size_t)l * 262144;
        ushort_t* wqb = Wscr;
        ushort_t* wkb = Wscr + 262144;
        ushort_t* wvb = Wscr + 524288;
        ushort_t* wob = Wscr + 786432;
        k_castT<<<gt(512, 512), 256, 0, stream>>>(wq, wqb, 512, 512);
        k_castT<<<gt(512, 512), 256, 0, stream>>>(wk, wkb, 512, 512);
        k_castT<<<gt(512, 512), 256, 0, stream>>>(wv, wvb, 512, 512);
        k_castT<<<gt(512, 512), 256, 0, stream>>>(wo, wob, 512, 512);
        k_gemm_mfma<false, ushort_t><<<gm(4096, 512), 256, 0, stream>>>(4096, 512, 512, Hb, wqb, Qb, 512, bq + l * 512);
        k_gemm_mfma<false, ushort_t><<<gm(4096, 512), 256, 0, stream>>>(4096, 512, 512, Hb, wkb, Kb, 512, bk + l * 512);
        k_gemm_mfma<false, ushort_t><<<gm(4096, 512), 256, 0, stream>>>(4096, 512, 512, Hb, wvb, Vb, 512, bv + l * 512);
        k_transposeV<<<dim3(16, 128, 1), 256, 0, stream>>>(Vb, VTg);
        k_flash<<<dim3(64, 4, 1), 256, 0, stream>>>(Qb, Kb, VTg);   // O -> Qb (bf16)
        k_gemm_mfma<false, float><<<gm(4096, 512), 256, 0, stream>>>(4096, 512, 512, Qb, wob, T, 512, bo + l * 512);
        k_add_ln<<<4096, 256, 0, stream>>>(H, T, H, Hb, ln1g + l * 512, ln1b + l * 512);
        k_castT<<<gt(512, 2048), 256, 0, stream>>>(Wff1 + (size_t)l * 1048576, Wscr, 512, 2048);
        k_gemm_mfma<true, ushort_t><<<gm(4096, 2048), 256, 0, stream>>>(4096, 2048, 512, Hb, Wscr, FFHb, 2048, bff1 + l * 2048);
        k_castT<<<gt(2048, 512), 256, 0, stream>>>(Wff2 + (size_t)l * 1048576, Wscr, 2048, 512);
        k_gemm_mfma<false, float><<<gm(4096, 512), 256, 0, stream>>>(4096, 512, 2048, FFHb, Wscr, T, 512, bff2 + l * 512);
        k_add_ln<<<4096, 256, 0, stream>>>(H, T, H, Hb, ln2g + l * 512, ln2b + l * 512);
    }

    // 4. projection + mean -> seq (fp32)
    k_gemm_nn<false><<<g2(4096, 20), 256, 0, stream>>>(4096, 20, 512, H, 512, Wproj, 20, P, 20, bproj);
    k_colmean<<<20, 256, 0, stream>>>(P, 4096, 20, seqv);

    // 5. protein GCN
    hipMemsetAsync(ADJB, 0, (size_t)4096 * 128 * 4, stream);
    k_scatter_bits<<<256, 256, 0, stream>>>(edge_index, ADJB);
    k_spmm_bits<20, 1><<<16, 256, 0, stream>>>(ADJB, Xoh, 20, pt0, 20);
    k_gemm_nn<true ><<<g2(4096, 128), 256, 0, stream>>>(4096, 128, 20, pt0, 20, gW1, 128, ph1, 128, gb1);
    k_spmm_bits<32, 4><<<64, 256, 0, stream>>>(ADJB, ph1, 128, pt1, 128);
    k_gemm_nn<true ><<<g2(4096, 64), 256, 0, stream>>>(4096, 64, 128, pt1, 128, gW2, 64, ph2, 64, gb2);
    k_spmm_bits<32, 2><<<32, 256, 0, stream>>>(ADJB, ph2, 64, pt2, 64);
    k_gemm_nn<false><<<g2(4096, 20), 256, 0, stream>>>(4096, 20, 64, pt2, 64, gW3, 20, pgo, 20, gb3);
    k_colmean<<<20, 256, 0, stream>>>(pgo, 4096, 20, protv);

    // 6. fusion head
    k_fusion<<<1, 128, 0, stream>>>(subv, protv, seqv, Wtime, btime, Woutw, boutw, t_ptr, lo_ptr, out);
}

// Round 12
// 1258.772 us; speedup vs baseline: 7.4645x; 1.0742x over previous
//
#include <hip/hip_runtime.h>
#include <math.h>

typedef unsigned short ushort_t;
typedef __attribute__((ext_vector_type(8))) short bf16x8;
typedef __attribute__((ext_vector_type(4))) float f32x4;

// ---------- helpers ----------
__device__ inline float bf2f(unsigned u) { return __uint_as_float((u & 0xffffu) << 16); }
__device__ inline ushort_t f2bf(float f) {
    unsigned u = __float_as_uint(f);
    return (ushort_t)((u + 0x7fffu + ((u >> 16) & 1u)) >> 16);   // RNE
}
__device__ inline void stv(float* p, float v) { *p = v; }
__device__ inline void stv(ushort_t* p, float v) { *p = f2bf(v); }
__device__ inline int guard_int(int raw, int lo, int hi) {
    if (raw >= lo && raw <= hi) return raw;
    float f = __int_as_float(raw);
    int v = (int)f;
    return (v >= lo && v <= hi) ? v : lo;
}

// ---------- threefry2x32 (JAX partitionable, verified R7) ----------
__device__ inline void tf2x32(unsigned k0, unsigned k1, unsigned x0, unsigned x1,
                              unsigned& o0, unsigned& o1) {
    unsigned ks2 = k0 ^ k1 ^ 0x1BD11BDAu;
    x0 += k0; x1 += k1;
#define TFR(r) { x0 += x1; x1 = (x1 << (r)) | (x1 >> (32 - (r))); x1 ^= x0; }
    TFR(13) TFR(15) TFR(26) TFR(6)  x0 += k1;  x1 += ks2 + 1u;
    TFR(17) TFR(29) TFR(16) TFR(24) x0 += ks2; x1 += k0 + 2u;
    TFR(13) TFR(15) TFR(26) TFR(6)  x0 += k0;  x1 += k1 + 3u;
    TFR(17) TFR(29) TFR(16) TFR(24) x0 += k1;  x1 += ks2 + 4u;
    TFR(13) TFR(15) TFR(26) TFR(6)  x0 += ks2; x1 += k0 + 5u;
#undef TFR
    o0 = x0; o1 = x1;
}

__global__ void k_sentinel(float* __restrict__ out, float val, int n) {
    int i = blockIdx.x * 128 + threadIdx.x;
    if (i < n) out[i] = val;
}

// ---------- diffusion categorical sampling -> one-hot X ----------
__global__ __launch_bounds__(256) void k_sample(const float* __restrict__ x,
                                                const int* __restrict__ t_ptr,
                                                float* __restrict__ X) {
    int i = blockIdx.x * 256 + threadIdx.x;
    if (i >= 4096) return;
    int tval = guard_int(t_ptr[0], 0, 500);
    double tf = (double)tval / 500.0;
    const double sc = 0.008;
    const double PI_HALF = 1.5707963267948966;
    double num = cos((tf + sc) / (1.0 + sc) * PI_HALF);
    double den = cos(sc / (1.0 + sc) * PI_HALF);
    float ab = (float)((num * num) / (den * den));
    float phi = (1.0f - ab) / 20.0f;
    float xv[20]; float sx = 0.f;
    for (int j = 0; j < 20; ++j) { xv[j] = x[i * 20 + j]; sx += xv[j]; }
    float best = -1e30f; int bj = 0;
    for (int j = 0; j < 20; ++j) {
        float prob = fmaxf(ab * xv[j] + phi * sx, 0.0f);
        float lp = logf(prob + 1e-9f);
        unsigned m = (unsigned)(i * 20 + j);
        unsigned o0, o1;
        tf2x32(0u, 42u, 0u, m, o0, o1);
        unsigned bits = o0 ^ o1;
        float u = __uint_as_float((bits >> 9) | 0x3f800000u) - 1.0f;
        if (u < 1.1754943508222875e-38f) u = 1.1754943508222875e-38f;
        float gmb = -logf(-logf(u));
        float z = lp + gmb;
        if (z > best) { best = z; bj = j; }
    }
    for (int j = 0; j < 20; ++j) X[i * 20 + j] = (j == bj) ? 1.0f : 0.0f;
}

// ---------- small utility kernels ----------
__global__ __launch_bounds__(256) void k_gather_fp(const float* __restrict__ emb,
                                                   const int* __restrict__ idx,
                                                   float* __restrict__ out) {
    int i = blockIdx.x * 256 + threadIdx.x;
    if (i >= 256 * 20) return;
    int a = i / 20, d = i % 20;
    out[i] = emb[(size_t)idx[a] * 20 + d];
}

__global__ __launch_bounds__(256) void k_scatter_bits(const int* __restrict__ ei,
                                                      unsigned* __restrict__ bits) {
    int e = blockIdx.x * 256 + threadIdx.x;
    if (e >= 65536) return;
    int r = ei[e], c = ei[65536 + e];
    atomicOr(&bits[(size_t)r * 128 + (c >> 5)], 1u << (c & 31));
}

__global__ __launch_bounds__(256) void k_embed(const float* __restrict__ embw,
                                               const int* __restrict__ words,
                                               float* __restrict__ H,
                                               ushort_t* __restrict__ Hb) {
    int idx = blockIdx.x * 256 + threadIdx.x;
    if (idx >= 4096 * 512) return;
    int pos = idx >> 9, d = idx & 511;
    float e = embw[(size_t)words[pos] * 512 + d];
    float expo = (float)(d >> 1) * (1.0f / 256.0f);
    float ang = (float)pos * exp2f(-expo * 13.287712379549449f);
    float pe = (d & 1) ? cosf(ang) : sinf(ang);
    float v = e + pe;
    H[idx] = v; Hb[idx] = f2bf(v);
}

__global__ __launch_bounds__(256) void k_colmean(const float* __restrict__ M, int R, int C,
                                                 float* __restrict__ out) {
    __shared__ float red[256];
    int c = blockIdx.x, t = threadIdx.x;
    float s = 0.f;
    for (int r = t; r < R; r += 256) s += M[(size_t)r * C + c];
    red[t] = s; __syncthreads();
    for (int o = 128; o; o >>= 1) { if (t < o) red[t] += red[t + o]; __syncthreads(); }
    if (t == 0) out[c] = red[0] / (float)R;
}

// ---------- weight cast+transpose: fp32 [K,N] -> bf16 [N,K] ----------
__global__ __launch_bounds__(256) void k_castT(const float* __restrict__ in,
                                               ushort_t* __restrict__ out,
                                               int Kd, int Nd) {
    __shared__ float t[32][33];
    int bx = blockIdx.x * 32, by = blockIdx.y * 32;
    int tx = threadIdx.x & 31, ty = threadIdx.x >> 5;
#pragma unroll
    for (int i = 0; i < 4; ++i)
        t[ty + i * 8][tx] = in[(size_t)(by + ty + i * 8) * Nd + bx + tx];
    __syncthreads();
#pragma unroll
    for (int i = 0; i < 4; ++i)
        out[(size_t)(bx + ty + i * 8) * Kd + by + tx] = f2bf(t[tx][ty + i * 8]);
}

// ---------- bf16 transpose: in [4096][512] -> out [512][4096] ----------
__global__ __launch_bounds__(256) void k_transposeV(const ushort_t* __restrict__ in,
                                                    ushort_t* __restrict__ out) {
    __shared__ ushort_t t[32][33];
    int bx = blockIdx.x * 32;
    int by = blockIdx.y * 32;
    int tx = threadIdx.x & 31, ty = threadIdx.x >> 5;
#pragma unroll
    for (int i = 0; i < 4; ++i)
        t[ty + i * 8][tx] = in[(size_t)(by + ty + i * 8) * 512 + bx + tx];
    __syncthreads();
#pragma unroll
    for (int i = 0; i < 4; ++i)
        out[(size_t)(bx + ty + i * 8) * 4096 + by + tx] = t[tx][ty + i * 8];
}

// ---------- MFMA bf16 GEMM v2: BM=128 x BN tile, 4 waves (2x2 quadrants) ----------
// C[M,N] = A[M,K](bf16) @ Bt[N,K](bf16) + bias. Wave computes 64 x BN/2.
template<int BN, bool RELU, typename TC>
__global__ __launch_bounds__(256) void k_gemm_mfma2(int M, int N, int K,
        const ushort_t* __restrict__ A,
        const ushort_t* __restrict__ Bt,
        TC* __restrict__ C, int ldc,
        const float* __restrict__ bias) {
    constexpr int NJ = BN / 32;          // 16-col frags per wave
    __shared__ ushort_t As[128][40];
    __shared__ ushort_t Bs[BN][40];
    int tid = threadIdx.x;
    int lane = tid & 63, wave = tid >> 6;
    int wr = wave >> 1, wc = wave & 1;
    int lrow = lane & 15, lq = lane >> 4;
    int br = blockIdx.y * 128, bc = blockIdx.x * BN;
    f32x4 acc[4][NJ];
#pragma unroll
    for (int i = 0; i < 4; ++i)
#pragma unroll
        for (int j = 0; j < NJ; ++j) { acc[i][j][0] = 0.f; acc[i][j][1] = 0.f; acc[i][j][2] = 0.f; acc[i][j][3] = 0.f; }
    int sr = tid >> 2, sseg = tid & 3;   // 64 rows x 4 segs per 256-thread pass
    for (int k0 = 0; k0 < K; k0 += 32) {
#pragma unroll
        for (int it = 0; it < 2; ++it)
            *(uint4*)&As[sr + it * 64][sseg * 8] = *(const uint4*)&A[(size_t)(br + sr + it * 64) * K + k0 + sseg * 8];
#pragma unroll
        for (int it = 0; it < BN / 64; ++it)
            *(uint4*)&Bs[sr + it * 64][sseg * 8] = *(const uint4*)&Bt[(size_t)(bc + sr + it * 64) * K + k0 + sseg * 8];
        __syncthreads();
        bf16x8 af[4], bfr[NJ];
#pragma unroll
        for (int i = 0; i < 4; ++i) af[i] = *(const bf16x8*)&As[wr * 64 + i * 16 + lrow][lq * 8];
#pragma unroll
        for (int j = 0; j < NJ; ++j) bfr[j] = *(const bf16x8*)&Bs[wc * (BN / 2) + j * 16 + lrow][lq * 8];
#pragma unroll
        for (int i = 0; i < 4; ++i)
#pragma unroll
            for (int j = 0; j < NJ; ++j)
                acc[i][j] = __builtin_amdgcn_mfma_f32_16x16x32_bf16(af[i], bfr[j], acc[i][j], 0, 0, 0);
        __syncthreads();
    }
#pragma unroll
    for (int i = 0; i < 4; ++i)
#pragma unroll
        for (int j = 0; j < NJ; ++j) {
            int col = bc + wc * (BN / 2) + j * 16 + lrow;
            float bv = bias ? bias[col] : 0.f;
#pragma unroll
            for (int r = 0; r < 4; ++r) {
                int row = br + wr * 64 + i * 16 + lq * 4 + r;
                float v = acc[i][j][r] + bv;
                if (RELU) v = fmaxf(v, 0.f);
                stv(&C[(size_t)row * ldc + col], v);
            }
        }
}

// ---------- fp32 GEMM (small/odd shapes) ----------
template<bool RELU>
__global__ __launch_bounds__(256) void k_gemm_nn(int M, int N, int K,
        const float* __restrict__ A, int lda,
        const float* __restrict__ B, int ldb,
        float* __restrict__ C, int ldc,
        const float* __restrict__ bias) {
    __shared__ float As[16][65];
    __shared__ float Bs[16][65];
    int tid = threadIdx.x;
    int tx = tid & 15, ty = tid >> 4;
    int br = blockIdx.y * 64, bc = blockIdx.x * 64;
    float acc[4][4] = {};
    for (int k0 = 0; k0 < K; k0 += 16) {
#pragma unroll
        for (int c0 = 0; c0 < 4; ++c0) {
            int r = (tid >> 4) + c0 * 16, kk = tid & 15;
            int gr = br + r, gk = k0 + kk;
            As[kk][r] = (gr < M && gk < K) ? A[(size_t)gr * lda + gk] : 0.f;
        }
#pragma unroll
        for (int c0 = 0; c0 < 4; ++c0) {
            int col = tid & 63, kk = (tid >> 6) + c0 * 4;
            int gc = bc + col, gk = k0 + kk;
            Bs[kk][col] = (gc < N && gk < K) ? B[(size_t)gk * ldb + gc] : 0.f;
        }
        __syncthreads();
#pragma unroll
        for (int kk = 0; kk < 16; ++kk) {
            float av[4], bv[4];
#pragma unroll
            for (int i2 = 0; i2 < 4; ++i2) av[i2] = As[kk][ty + 16 * i2];
#pragma unroll
            for (int j2 = 0; j2 < 4; ++j2) bv[j2] = Bs[kk][tx + 16 * j2];
#pragma unroll
            for (int i2 = 0; i2 < 4; ++i2)
#pragma unroll
                for (int j2 = 0; j2 < 4; ++j2) acc[i2][j2] += av[i2] * bv[j2];
        }
        __syncthreads();
    }
#pragma unroll
    for (int i2 = 0; i2 < 4; ++i2)
#pragma unroll
        for (int j2 = 0; j2 < 4; ++j2) {
            int r = br + ty + 16 * i2, c = bc + tx + 16 * j2;
            if (r < M && c < N) {
                float v = acc[i2][j2];
                if (bias) v += bias[c];
                if (RELU) v = fmaxf(v, 0.f);
                C[(size_t)r * ldc + c] = v;
            }
        }
}

// ---------- SpMM: C[4096,N] = BITS @ B ----------
template<int NC, int CHUNKS>
__global__ __launch_bounds__(256) void k_spmm_bits(
        const unsigned* __restrict__ BITS,
        const float* __restrict__ B, int ldb,
        float* __restrict__ C, int ldc) {
    int t = blockIdx.x * 256 + threadIdx.x;
    int r = t / CHUNKS;
    int cb = (t % CHUNKS) * NC;
    if (r >= 4096) return;
    float acc[NC];
#pragma unroll
    for (int j = 0; j < NC; ++j) acc[j] = 0.f;
    const unsigned* bw = &BITS[(size_t)r * 128];
    for (int w = 0; w < 128; ++w) {
        unsigned bits = bw[w];
        while (bits) {
            int b = __ffs(bits) - 1; bits &= bits - 1;
            const float* brow = &B[(size_t)(w * 32 + b) * ldb + cb];
#pragma unroll
            for (int j = 0; j < NC; ++j) acc[j] += brow[j];
        }
    }
#pragma unroll
    for (int j = 0; j < NC; ++j) C[(size_t)r * ldc + cb + j] = acc[j];
}

// ---------- MFMA flash v4: split-K over 2 halves (grid.z), partial O/m/l out ----------
__global__ __launch_bounds__(256) void k_flash(const ushort_t* __restrict__ Qg,
                                               const ushort_t* __restrict__ Kg,
                                               const ushort_t* __restrict__ VTg,
                                               ushort_t* __restrict__ OP,
                                               float* __restrict__ Mp,
                                               float* __restrict__ Lp) {
    __shared__ ushort_t Ks[32][136];
    __shared__ ushort_t Vt[128][40];
    __shared__ ushort_t Ps[4][16][40];
    __shared__ float    as_[4][16];
    __shared__ float    ls_[4][16];
    const int tid = threadIdx.x;
    const int lane = tid & 63, wid = tid >> 6;
    const int lrow = lane & 15, lq = lane >> 4;
    const int qb = blockIdx.x * 64, hh = blockIdx.y, z = blockIdx.z;
    const float scale = 0.08838834764831845f;   // 1/sqrt(128)
    bf16x8 qf[4];
    {
        const ushort_t* qrow = &Qg[(size_t)(qb + wid * 16 + lrow) * 512 + hh * 128 + lq * 8];
#pragma unroll
        for (int s = 0; s < 4; ++s) qf[s] = *(const bf16x8*)&qrow[s * 32];
    }
    f32x4 o[8];
#pragma unroll
    for (int ct = 0; ct < 8; ++ct) { o[ct][0] = 0.f; o[ct][1] = 0.f; o[ct][2] = 0.f; o[ct][3] = 0.f; }
    float m = -INFINITY, l = 0.f;
    for (int kt = z * 64; kt < z * 64 + 64; ++kt) {
#pragma unroll
        for (int i = 0; i < 2; ++i) {
            int sid = tid + i * 256;
            int r = sid >> 4, sg = sid & 15;
            *(uint4*)&Ks[r][sg * 8] = *(const uint4*)&Kg[(size_t)(kt * 32 + r) * 512 + hh * 128 + sg * 8];
            int d = sid >> 2, c8 = sid & 3;
            *(uint4*)&Vt[d][c8 * 8] = *(const uint4*)&VTg[(size_t)(hh * 128 + d) * 4096 + kt * 32 + c8 * 8];
        }
        __syncthreads();
        f32x4 sa[2];
#pragma unroll
        for (int c = 0; c < 2; ++c) { sa[c][0] = 0.f; sa[c][1] = 0.f; sa[c][2] = 0.f; sa[c][3] = 0.f; }
#pragma unroll
        for (int c = 0; c < 2; ++c)
#pragma unroll
            for (int st = 0; st < 4; ++st) {
                bf16x8 kf = *(const bf16x8*)&Ks[c * 16 + lrow][st * 32 + lq * 8];
                sa[c] = __builtin_amdgcn_mfma_f32_16x16x32_bf16(kf, qf[st], sa[c], 0, 0, 0);
            }
        float s[8];
        float tm = -INFINITY;
#pragma unroll
        for (int c = 0; c < 2; ++c)
#pragma unroll
            for (int r = 0; r < 4; ++r) { float v = sa[c][r] * scale; s[c * 4 + r] = v; tm = fmaxf(tm, v); }
        tm = fmaxf(tm, __shfl_xor(tm, 16));
        tm = fmaxf(tm, __shfl_xor(tm, 32));
        float mn = fmaxf(m, tm);
        float a = expf(m - mn);
        float su = 0.f;
        float p[8];
#pragma unroll
        for (int i = 0; i < 8; ++i) { p[i] = expf(s[i] - mn); su += p[i]; }
        su += __shfl_xor(su, 16);
        su += __shfl_xor(su, 32);
        m = mn; l = l * a + su;
#pragma unroll
        for (int c = 0; c < 2; ++c)
#pragma unroll
            for (int r = 0; r < 4; ++r)
                Ps[wid][lrow][c * 16 + lq * 4 + r] = f2bf(p[c * 4 + r]);
        if (lq == 0) as_[wid][lrow] = a;
        __builtin_amdgcn_s_waitcnt(0);
        float av[4];
#pragma unroll
        for (int r = 0; r < 4; ++r) av[r] = as_[wid][lq * 4 + r];
#pragma unroll
        for (int ct = 0; ct < 8; ++ct)
#pragma unroll
            for (int r = 0; r < 4; ++r) o[ct][r] *= av[r];
        bf16x8 pf = *(const bf16x8*)&Ps[wid][lrow][lq * 8];
#pragma unroll
        for (int ct = 0; ct < 8; ++ct) {
            bf16x8 vf = *(const bf16x8*)&Vt[ct * 16 + lrow][lq * 8];
            o[ct] = __builtin_amdgcn_mfma_f32_16x16x32_bf16(pf, vf, o[ct], 0, 0, 0);
        }
        __syncthreads();
    }
    // write UNNORMALIZED partial O (bf16) + m/l per q-row
    if (lq == 0) {
        Mp[(size_t)(z * 4 + hh) * 4096 + qb + wid * 16 + lrow] = m;
        Lp[(size_t)(z * 4 + hh) * 4096 + qb + wid * 16 + lrow] = l;
    }
    ushort_t* ob = OP + (size_t)z * 2097152;
#pragma unroll
    for (int ct = 0; ct < 8; ++ct)
#pragma unroll
        for (int r = 0; r < 4; ++r)
            ob[(size_t)(qb + wid * 16 + lq * 4 + r) * 512 + hh * 128 + ct * 16 + lrow] = f2bf(o[ct][r]);
}

// ---------- flash split-K combine: Qb = (O0*w0 + O1*w1) / (l0*w0 + l1*w1) ----------
__global__ __launch_bounds__(256) void k_fcomb(const ushort_t* __restrict__ OP,
                                               const float* __restrict__ Mp,
                                               const float* __restrict__ Lp,
                                               ushort_t* __restrict__ Qb) {
    int idx = blockIdx.x * 256 + threadIdx.x;
    if (idx >= 4096 * 512) return;
    int row = idx >> 9, col = idx & 511;
    int hh = col >> 7;
    float m0 = Mp[hh * 4096 + row], m1 = Mp[(4 + hh) * 4096 + row];
    float l0 = Lp[hh * 4096 + row], l1 = Lp[(4 + hh) * 4096 + row];
    float mm = fmaxf(m0, m1);
    float w0 = expf(m0 - mm), w1 = expf(m1 - mm);
    float denom = l0 * w0 + l1 * w1;
    float o0 = bf2f(OP[idx]), o1 = bf2f(OP[2097152 + idx]);
    Qb[idx] = f2bf((o0 * w0 + o1 * w1) / denom);
}

// ---------- residual add + layernorm: writes fp32 H and bf16 Hb ----------
__global__ __launch_bounds__(256) void k_add_ln(const float* __restrict__ A,
                                                const float* __restrict__ B,
                                                float* __restrict__ O,
                                                ushort_t* __restrict__ Ob,
                                                const float* __restrict__ g,
                                                const float* __restrict__ b) {
    __shared__ float xr[512];
    __shared__ float red[256];
    int row = blockIdx.x, t = threadIdx.x;
    const float* a = A + (size_t)row * 512;
    const float* bb = B + (size_t)row * 512;
    float ls = 0.f;
    for (int j = t; j < 512; j += 256) { float v = a[j] + bb[j]; xr[j] = v; ls += v; }
    red[t] = ls; __syncthreads();
    for (int o = 128; o; o >>= 1) { if (t < o) red[t] += red[t + o]; __syncthreads(); }
    float mean = red[0] / 512.0f; __syncthreads();
    float lv = 0.f;
    for (int j = t; j < 512; j += 256) { float d = xr[j] - mean; lv += d * d; }
    red[t] = lv; __syncthreads();
    for (int o = 128; o; o >>= 1) { if (t < o) red[t] += red[t + o]; __syncthreads(); }
    float inv = 1.0f / sqrtf(red[0] / 512.0f + 1e-5f);
    float* o_ = O + (size_t)row * 512;
    ushort_t* ob = Ob + (size_t)row * 512;
    for (int j = t; j < 512; j += 256) {
        float v = (xr[j] - mean) * inv * g[j] + b[j];
        o_[j] = v; ob[j] = f2bf(v);
    }
}

// ---------- fusion head ----------
__global__ __launch_bounds__(128) void k_fusion(const float* __restrict__ subv,
                                                const float* __restrict__ protv,
                                                const float* __restrict__ seqv,
                                                const float* __restrict__ Wtime,
                                                const float* __restrict__ btime,
                                                const float* __restrict__ Wout,
                                                const float* __restrict__ bout,
                                                const int* __restrict__ t_ptr,
                                                const int* __restrict__ lo_ptr,
                                                float* __restrict__ out) {
    __shared__ float cat[80];
    int t = threadIdx.x;
    int tval = guard_int(t_ptr[0], 0, 500);
    int L    = guard_int(lo_ptr[0], 0, 3);
    float tf = (float)((double)tval / 500.0);
    if (t < 20) {
        cat[t] = subv[t];
        cat[20 + t] = protv[t];
        cat[40 + t] = seqv[t];
        cat[60 + t] = tf * Wtime[t] + btime[t];
    }
    __syncthreads();
    for (int j = 0; j < L; ++j) {
        float acc = 0.f;
        if (t < 80) {
            for (int i2 = 0; i2 < 80; ++i2)
                acc += fmaxf(cat[i2], 0.f) * Wout[(size_t)j * 6400 + i2 * 80 + t];
            acc += bout[j * 80 + t];
        }
        __syncthreads();
        if (t < 80) cat[t] = acc;
        __syncthreads();
    }
    if (t < 80) out[t] = fmaxf(cat[t], 0.f);
    if (t < 20) out[80 + t] = seqv[t];
}

// ---------- launch ----------
extern "C" void kernel_launch(void* const* d_in, const int* in_sizes, int n_in,
                              void* d_out, int out_size, void* d_ws, size_t ws_size,
                              hipStream_t stream) {
    static const int EXP[39] = {
        81920, 65536, 200000, 2097152, 2560, 128, 8192, 64, 1280, 20,
        524288, 1024, 524288, 1024, 524288, 1024, 524288, 1024, 1024, 1024,
        2097152, 4096, 2097152, 1024, 1024, 1024, 10240, 20, 19200, 240,
        20, 20, 256, 4096, 4096, 131072, 1, 1, 1 };
    float code = 0.f;
    if (n_in != 39) code = 900.f;
    else {
        for (int i = 0; i < 39; ++i)
            if (in_sizes[i] != EXP[i]) { code = 500.f + 4.f * (float)i; break; }
    }
    const size_t REQ = (size_t)46 * 1024 * 1024;
    if (code == 0.f && ws_size < REQ) code = (float)(ws_size >> 20);
    float* out = (float*)d_out;
    if (code != 0.f) {
        k_sentinel<<<1, 128, 0, stream>>>(out, -code, out_size);
        return;
    }

    const float* x_in   = (const float*)d_in[0];
    const float* adjs_in= (const float*)d_in[1];
    const float* embfp  = (const float*)d_in[2];
    const float* embw   = (const float*)d_in[3];
    const float* gW1 = (const float*)d_in[4];  const float* gb1 = (const float*)d_in[5];
    const float* gW2 = (const float*)d_in[6];  const float* gb2 = (const float*)d_in[7];
    const float* gW3 = (const float*)d_in[8];  const float* gb3 = (const float*)d_in[9];
    const float* Wq  = (const float*)d_in[10]; const float* bq  = (const float*)d_in[11];
    const float* Wk  = (const float*)d_in[12]; const float* bk  = (const float*)d_in[13];
    const float* Wv  = (const float*)d_in[14]; const float* bv  = (const float*)d_in[15];
    const float* Wo  = (const float*)d_in[16]; const float* bo  = (const float*)d_in[17];
    const float* ln1g= (const float*)d_in[18]; const float* ln1b= (const float*)d_in[19];
    const float* Wff1= (const float*)d_in[20]; const float* bff1= (const float*)d_in[21];
    const float* Wff2= (const float*)d_in[22]; const float* bff2= (const float*)d_in[23];
    const float* ln2g= (const float*)d_in[24]; const float* ln2b= (const float*)d_in[25];
    const float* Wproj=(const float*)d_in[26]; const float* bproj=(const float*)d_in[27];
    const float* Woutw=(const float*)d_in[28]; const float* boutw=(const float*)d_in[29];
    const float* Wtime=(const float*)d_in[30]; const float* btime=(const float*)d_in[31];
    const int* fingerprints = (const int*)d_in[32];
    const int* words        = (const int*)d_in[33];
    const int* edge_index   = (const int*)d_in[35];
    const int* t_ptr        = (const int*)d_in[36];
    const int* lo_ptr       = (const int*)d_in[37];

    // ---- workspace (46 MiB) ----
    char* wsb = (char*)d_ws;
    float*    misc = (float*)wsb;
    float*    H    = (float*)(wsb + ((size_t)2  << 20));
    ushort_t* Hb   = (ushort_t*)(wsb + ((size_t)10 << 20));
    ushort_t* Qb   = (ushort_t*)(wsb + ((size_t)14 << 20));
    ushort_t* Kb   = (ushort_t*)(wsb + ((size_t)18 << 20));
    ushort_t* Vb   = (ushort_t*)(wsb + ((size_t)22 << 20));
    ushort_t* FFHb = (ushort_t*)(wsb + ((size_t)14 << 20));
    float*    T    = (float*)(wsb + ((size_t)30 << 20));
    ushort_t* OP   = (ushort_t*)(wsb + ((size_t)30 << 20));   // flash partials (2x4 MiB, alias T)
    ushort_t* Wscr = (ushort_t*)(wsb + ((size_t)38 << 20));
    ushort_t* VTg  = (ushort_t*)(wsb + ((size_t)42 << 20));   // V^T [512][4096] bf16
    unsigned* ADJB = (unsigned*)Qb;
    float* pt0  = (float*)Kb;
    float* ph1  = pt0 + 81920;
    float* pt1  = ph1 + 524288;
    float* ph2  = pt1 + 524288;
    float* pt2  = ph2 + 262144;
    float* pgo  = pt2 + 262144;
    float* Xoh  = misc;
    float* fpv  = misc + 81920;
    float* st0  = misc + 87040;
    float* sh1  = misc + 92160;
    float* st1  = misc + 124928;
    float* sh2  = misc + 157696;
    float* st2  = misc + 174080;
    float* sgo  = misc + 190464;
    float* P    = misc + 195584;
    float* subv = misc + 277504;
    float* protv= misc + 277536;
    float* seqv = misc + 277568;
    float* Mp   = misc + 300000;     // 32768 floats
    float* Lp   = misc + 360000;     // 32768 floats

    auto g2 = [](int M, int N) { return dim3((unsigned)((N + 63) / 64), (unsigned)((M + 63) / 64), 1); };
    auto gm64  = [](int M, int N) { return dim3((unsigned)(N / 64), (unsigned)(M / 128), 1); };
    auto gm128 = [](int M, int N) { return dim3((unsigned)(N / 128), (unsigned)(M / 128), 1); };
    auto gt = [](int Kd, int Nd) { return dim3((unsigned)(Nd / 32), (unsigned)(Kd / 32), 1); };

    // 1. diffusion sampling
    k_sample<<<16, 256, 0, stream>>>(x_in, t_ptr, Xoh);

    // 2. substrate GCN (fp32)
    k_gather_fp<<<20, 256, 0, stream>>>(embfp, fingerprints, fpv);
    k_gemm_nn<false><<<g2(256, 20), 256, 0, stream>>>(256, 20, 256, adjs_in, 256, fpv, 20, st0, 20, nullptr);
    k_gemm_nn<true ><<<g2(256, 128), 256, 0, stream>>>(256, 128, 20, st0, 20, gW1, 128, sh1, 128, gb1);
    k_gemm_nn<false><<<g2(256, 128), 256, 0, stream>>>(256, 128, 256, adjs_in, 256, sh1, 128, st1, 128, nullptr);
    k_gemm_nn<true ><<<g2(256, 64), 256, 0, stream>>>(256, 64, 128, st1, 128, gW2, 64, sh2, 64, gb2);
    k_gemm_nn<false><<<g2(256, 64), 256, 0, stream>>>(256, 64, 256, adjs_in, 256, sh2, 64, st2, 64, nullptr);
    k_gemm_nn<false><<<g2(256, 20), 256, 0, stream>>>(256, 20, 64, st2, 64, gW3, 20, sgo, 20, gb3);
    k_colmean<<<20, 256, 0, stream>>>(sgo, 256, 20, subv);

    // 3. transformer (BM=128 MFMA GEMMs + split-K MFMA flash)
    k_embed<<<8192, 256, 0, stream>>>(embw, words, H, Hb);
    for (int l = 0; l < 2; ++l) {
        const float* wq = Wq + (size_t)l * 262144;
        const float* wk = Wk + (size_t)l * 262144;
        const float* wv = Wv + (size_t)l * 262144;
        const float* wo = Wo + (size_t)l * 262144;
        ushort_t* wqb = Wscr;
        ushort_t* wkb = Wscr + 262144;
        ushort_t* wvb = Wscr + 524288;
        ushort_t* wob = Wscr + 786432;
        k_castT<<<gt(512, 512), 256, 0, stream>>>(wq, wqb, 512, 512);
        k_castT<<<gt(512, 512), 256, 0, stream>>>(wk, wkb, 512, 512);
        k_castT<<<gt(512, 512), 256, 0, stream>>>(wv, wvb, 512, 512);
        k_castT<<<gt(512, 512), 256, 0, stream>>>(wo, wob, 512, 512);
        k_gemm_mfma2<64, false, ushort_t><<<gm64(4096, 512), 256, 0, stream>>>(4096, 512, 512, Hb, wqb, Qb, 512, bq + l * 512);
        k_gemm_mfma2<64, false, ushort_t><<<gm64(4096, 512), 256, 0, stream>>>(4096, 512, 512, Hb, wkb, Kb, 512, bk + l * 512);
        k_gemm_mfma2<64, false, ushort_t><<<gm64(4096, 512), 256, 0, stream>>>(4096, 512, 512, Hb, wvb, Vb, 512, bv + l * 512);
        k_transposeV<<<dim3(16, 128, 1), 256, 0, stream>>>(Vb, VTg);
        k_flash<<<dim3(64, 4, 2), 256, 0, stream>>>(Qb, Kb, VTg, OP, Mp, Lp);
        k_fcomb<<<8192, 256, 0, stream>>>(OP, Mp, Lp, Qb);
        k_gemm_mfma2<64, false, float><<<gm64(4096, 512), 256, 0, stream>>>(4096, 512, 512, Qb, wob, T, 512, bo + l * 512);
        k_add_ln<<<4096, 256, 0, stream>>>(H, T, H, Hb, ln1g + l * 512, ln1b + l * 512);
        k_castT<<<gt(512, 2048), 256, 0, stream>>>(Wff1 + (size_t)l * 1048576, Wscr, 512, 2048);
        k_gemm_mfma2<128, true, ushort_t><<<gm128(4096, 2048), 256, 0, stream>>>(4096, 2048, 512, Hb, Wscr, FFHb, 2048, bff1 + l * 2048);
        k_castT<<<gt(2048, 512), 256, 0, stream>>>(Wff2 + (size_t)l * 1048576, Wscr, 2048, 512);
        k_gemm_mfma2<64, false, float><<<gm64(4096, 512), 256, 0, stream>>>(4096, 512, 2048, FFHb, Wscr, T, 512, bff2 + l * 512);
        k_add_ln<<<4096, 256, 0, stream>>>(H, T, H, Hb, ln2g + l * 512, ln2b + l * 512);
    }

    // 4. projection + mean -> seq (fp32)
    k_gemm_nn<false><<<g2(4096, 20), 256, 0, stream>>>(4096, 20, 512, H, 512, Wproj, 20, P, 20, bproj);
    k_colmean<<<20, 256, 0, stream>>>(P, 4096, 20, seqv);

    // 5. protein GCN
    hipMemsetAsync(ADJB, 0, (size_t)4096 * 128 * 4, stream);
    k_scatter_bits<<<256, 256, 0, stream>>>(edge_index, ADJB);
    k_spmm_bits<20, 1><<<16, 256, 0, stream>>>(ADJB, Xoh, 20, pt0, 20);
    k_gemm_nn<true ><<<g2(4096, 128), 256, 0, stream>>>(4096, 128, 20, pt0, 20, gW1, 128, ph1, 128, gb1);
    k_spmm_bits<32, 4><<<64, 256, 0, stream>>>(ADJB, ph1, 128, pt1, 128);
    k_gemm_nn<true ><<<g2(4096, 64), 256, 0, stream>>>(4096, 64, 128, pt1, 128, gW2, 64, ph2, 64, gb2);
    k_spmm_bits<32, 2><<<32, 256, 0, stream>>>(ADJB, ph2, 64, pt2, 64);
    k_gemm_nn<false><<<g2(4096, 20), 256, 0, stream>>>(4096, 20, 64, pt2, 64, gW3, 20, pgo, 20, gb3);
    k_colmean<<<20, 256, 0, stream>>>(pgo, 4096, 20, protv);

    // 6. fusion head
    k_fusion<<<1, 128, 0, stream>>>(subv, protv, seqv, Wtime, btime, Woutw, boutw, t_ptr, lo_ptr, out);
}

// Round 13
// 1038.116 us; speedup vs baseline: 9.0511x; 1.2126x over previous
//
#include <hip/hip_runtime.h>
#include <math.h>

typedef unsigned short ushort_t;
typedef __attribute__((ext_vector_type(8))) short bf16x8;
typedef __attribute__((ext_vector_type(4))) float f32x4;

// ---------- helpers ----------
__device__ inline float bf2f(unsigned u) { return __uint_as_float((u & 0xffffu) << 16); }
__device__ inline ushort_t f2bf(float f) {
    unsigned u = __float_as_uint(f);
    return (ushort_t)((u + 0x7fffu + ((u >> 16) & 1u)) >> 16);   // RNE
}
__device__ inline void stv(float* p, float v) { *p = v; }
__device__ inline void stv(ushort_t* p, float v) { *p = f2bf(v); }
__device__ inline int guard_int(int raw, int lo, int hi) {
    if (raw >= lo && raw <= hi) return raw;
    float f = __int_as_float(raw);
    int v = (int)f;
    return (v >= lo && v <= hi) ? v : lo;
}

// ---------- threefry2x32 (JAX partitionable, verified R7) ----------
__device__ inline void tf2x32(unsigned k0, unsigned k1, unsigned x0, unsigned x1,
                              unsigned& o0, unsigned& o1) {
    unsigned ks2 = k0 ^ k1 ^ 0x1BD11BDAu;
    x0 += k0; x1 += k1;
#define TFR(r) { x0 += x1; x1 = (x1 << (r)) | (x1 >> (32 - (r))); x1 ^= x0; }
    TFR(13) TFR(15) TFR(26) TFR(6)  x0 += k1;  x1 += ks2 + 1u;
    TFR(17) TFR(29) TFR(16) TFR(24) x0 += ks2; x1 += k0 + 2u;
    TFR(13) TFR(15) TFR(26) TFR(6)  x0 += k0;  x1 += k1 + 3u;
    TFR(17) TFR(29) TFR(16) TFR(24) x0 += k1;  x1 += ks2 + 4u;
    TFR(13) TFR(15) TFR(26) TFR(6)  x0 += ks2; x1 += k0 + 5u;
#undef TFR
    o0 = x0; o1 = x1;
}

__global__ void k_sentinel(float* __restrict__ out, float val, int n) {
    int i = blockIdx.x * 128 + threadIdx.x;
    if (i < n) out[i] = val;
}

// ---------- diffusion categorical sampling -> one-hot X ----------
__global__ __launch_bounds__(256) void k_sample(const float* __restrict__ x,
                                                const int* __restrict__ t_ptr,
                                                float* __restrict__ X) {
    int i = blockIdx.x * 256 + threadIdx.x;
    if (i >= 4096) return;
    int tval = guard_int(t_ptr[0], 0, 500);
    double tf = (double)tval / 500.0;
    const double sc = 0.008;
    const double PI_HALF = 1.5707963267948966;
    double num = cos((tf + sc) / (1.0 + sc) * PI_HALF);
    double den = cos(sc / (1.0 + sc) * PI_HALF);
    float ab = (float)((num * num) / (den * den));
    float phi = (1.0f - ab) / 20.0f;
    float xv[20]; float sx = 0.f;
    for (int j = 0; j < 20; ++j) { xv[j] = x[i * 20 + j]; sx += xv[j]; }
    float best = -1e30f; int bj = 0;
    for (int j = 0; j < 20; ++j) {
        float prob = fmaxf(ab * xv[j] + phi * sx, 0.0f);
        float lp = logf(prob + 1e-9f);
        unsigned m = (unsigned)(i * 20 + j);
        unsigned o0, o1;
        tf2x32(0u, 42u, 0u, m, o0, o1);
        unsigned bits = o0 ^ o1;
        float u = __uint_as_float((bits >> 9) | 0x3f800000u) - 1.0f;
        if (u < 1.1754943508222875e-38f) u = 1.1754943508222875e-38f;
        float gmb = -logf(-logf(u));
        float z = lp + gmb;
        if (z > best) { best = z; bj = j; }
    }
    for (int j = 0; j < 20; ++j) X[i * 20 + j] = (j == bj) ? 1.0f : 0.0f;
}

// ---------- small utility kernels ----------
__global__ __launch_bounds__(256) void k_gather_fp(const float* __restrict__ emb,
                                                   const int* __restrict__ idx,
                                                   float* __restrict__ out) {
    int i = blockIdx.x * 256 + threadIdx.x;
    if (i >= 256 * 20) return;
    int a = i / 20, d = i % 20;
    out[i] = emb[(size_t)idx[a] * 20 + d];
}

__global__ __launch_bounds__(256) void k_scatter_bits(const int* __restrict__ ei,
                                                      unsigned* __restrict__ bits) {
    int e = blockIdx.x * 256 + threadIdx.x;
    if (e >= 65536) return;
    int r = ei[e], c = ei[65536 + e];
    atomicOr(&bits[(size_t)r * 128 + (c >> 5)], 1u << (c & 31));
}

// column degree from bitmap: deg[c] = #rows with bit c set
__global__ __launch_bounds__(256) void k_degree(const unsigned* __restrict__ BITS,
                                                float* __restrict__ deg) {
    int i = blockIdx.x * 256 + threadIdx.x;
    if (i >= 4096 * 128) return;
    unsigned bits = BITS[i];
    int base = (i & 127) * 32;
    while (bits) { int b = __ffs(bits) - 1; bits &= bits - 1; atomicAdd(&deg[base + b], 1.0f); }
}

__global__ __launch_bounds__(256) void k_embed(const float* __restrict__ embw,
                                               const int* __restrict__ words,
                                               float* __restrict__ H,
                                               ushort_t* __restrict__ Hb) {
    int idx = blockIdx.x * 256 + threadIdx.x;
    if (idx >= 4096 * 512) return;
    int pos = idx >> 9, d = idx & 511;
    float e = embw[(size_t)words[pos] * 512 + d];
    float expo = (float)(d >> 1) * (1.0f / 256.0f);
    float ang = (float)pos * exp2f(-expo * 13.287712379549449f);
    float pe = (d & 1) ? cosf(ang) : sinf(ang);
    float v = e + pe;
    H[idx] = v; Hb[idx] = f2bf(v);
}

__global__ __launch_bounds__(256) void k_colmean(const float* __restrict__ M, int R, int C,
                                                 float* __restrict__ out) {
    __shared__ float red[256];
    int c = blockIdx.x, t = threadIdx.x;
    float s = 0.f;
    for (int r = t; r < R; r += 256) s += M[(size_t)r * C + c];
    red[t] = s; __syncthreads();
    for (int o = 128; o; o >>= 1) { if (t < o) red[t] += red[t + o]; __syncthreads(); }
    if (t == 0) out[c] = red[0] / (float)R;
}

// weighted column sum: out[c] = sum_r w[r] * M[r*C+c]   (C = gridDim.x)
__global__ __launch_bounds__(256) void k_wcolsum(const float* __restrict__ M, int R, int C,
                                                 const float* __restrict__ w,
                                                 float* __restrict__ out) {
    __shared__ float red[256];
    int c = blockIdx.x, t = threadIdx.x;
    float s = 0.f;
    for (int r = t; r < R; r += 256) s += w[r] * M[(size_t)r * C + c];
    red[t] = s; __syncthreads();
    for (int o = 128; o; o >>= 1) { if (t < o) red[t] += red[t + o]; __syncthreads(); }
    if (t == 0) out[c] = red[0];
}

// tiny matvec: out[t<20] = scale * (vec[0..D) . W[:,t]) + bias[t]
__global__ void k_matvec20(int D, float scale, const float* __restrict__ vec,
                           const float* __restrict__ W, const float* __restrict__ bias,
                           float* __restrict__ out) {
    int t = threadIdx.x;
    if (t >= 20) return;
    float s = 0.f;
    for (int d = 0; d < D; ++d) s += vec[d] * W[d * 20 + t];
    out[t] = s * scale + bias[t];
}

// ---------- weight cast+transpose: fp32 [K,N] -> bf16 [N,K] ----------
__global__ __launch_bounds__(256) void k_castT(const float* __restrict__ in,
                                               ushort_t* __restrict__ out,
                                               int Kd, int Nd) {
    __shared__ float t[32][33];
    int bx = blockIdx.x * 32, by = blockIdx.y * 32;
    int tx = threadIdx.x & 31, ty = threadIdx.x >> 5;
#pragma unroll
    for (int i = 0; i < 4; ++i)
        t[ty + i * 8][tx] = in[(size_t)(by + ty + i * 8) * Nd + bx + tx];
    __syncthreads();
#pragma unroll
    for (int i = 0; i < 4; ++i)
        out[(size_t)(bx + ty + i * 8) * Kd + by + tx] = f2bf(t[tx][ty + i * 8]);
}

// ---------- bf16 transpose: in [4096][ld] (512-col slice) -> out [512][4096] ----------
__global__ __launch_bounds__(256) void k_transposeV(const ushort_t* __restrict__ in, int ldin,
                                                    ushort_t* __restrict__ out) {
    __shared__ ushort_t t[32][33];
    int bx = blockIdx.x * 32;
    int by = blockIdx.y * 32;
    int tx = threadIdx.x & 31, ty = threadIdx.x >> 5;
#pragma unroll
    for (int i = 0; i < 4; ++i)
        t[ty + i * 8][tx] = in[(size_t)(by + ty + i * 8) * ldin + bx + tx];
    __syncthreads();
#pragma unroll
    for (int i = 0; i < 4; ++i)
        out[(size_t)(bx + ty + i * 8) * 4096 + by + tx] = t[tx][ty + i * 8];
}

// ---------- MFMA bf16 GEMM: BM=128 x BN tile, lda-parametrized A ----------
template<int BN, bool RELU, typename TC>
__global__ __launch_bounds__(256) void k_gemm_mfma2(int M, int N, int K, int lda,
        const ushort_t* __restrict__ A,
        const ushort_t* __restrict__ Bt,
        TC* __restrict__ C, int ldc,
        const float* __restrict__ bias) {
    constexpr int NJ = BN / 32;
    __shared__ ushort_t As[128][40];
    __shared__ ushort_t Bs[BN][40];
    int tid = threadIdx.x;
    int lane = tid & 63, wave = tid >> 6;
    int wr = wave >> 1, wc = wave & 1;
    int lrow = lane & 15, lq = lane >> 4;
    int br = blockIdx.y * 128, bc = blockIdx.x * BN;
    f32x4 acc[4][NJ];
#pragma unroll
    for (int i = 0; i < 4; ++i)
#pragma unroll
        for (int j = 0; j < NJ; ++j) { acc[i][j][0] = 0.f; acc[i][j][1] = 0.f; acc[i][j][2] = 0.f; acc[i][j][3] = 0.f; }
    int sr = tid >> 2, sseg = tid & 3;
    for (int k0 = 0; k0 < K; k0 += 32) {
#pragma unroll
        for (int it = 0; it < 2; ++it)
            *(uint4*)&As[sr + it * 64][sseg * 8] = *(const uint4*)&A[(size_t)(br + sr + it * 64) * lda + k0 + sseg * 8];
#pragma unroll
        for (int it = 0; it < BN / 64; ++it)
            *(uint4*)&Bs[sr + it * 64][sseg * 8] = *(const uint4*)&Bt[(size_t)(bc + sr + it * 64) * K + k0 + sseg * 8];
        __syncthreads();
        bf16x8 af[4], bfr[NJ];
#pragma unroll
        for (int i = 0; i < 4; ++i) af[i] = *(const bf16x8*)&As[wr * 64 + i * 16 + lrow][lq * 8];
#pragma unroll
        for (int j = 0; j < NJ; ++j) bfr[j] = *(const bf16x8*)&Bs[wc * (BN / 2) + j * 16 + lrow][lq * 8];
#pragma unroll
        for (int i = 0; i < 4; ++i)
#pragma unroll
            for (int j = 0; j < NJ; ++j)
                acc[i][j] = __builtin_amdgcn_mfma_f32_16x16x32_bf16(af[i], bfr[j], acc[i][j], 0, 0, 0);
        __syncthreads();
    }
#pragma unroll
    for (int i = 0; i < 4; ++i)
#pragma unroll
        for (int j = 0; j < NJ; ++j) {
            int col = bc + wc * (BN / 2) + j * 16 + lrow;
            float bv = bias ? bias[col] : 0.f;
#pragma unroll
            for (int r = 0; r < 4; ++r) {
                int row = br + wr * 64 + i * 16 + lq * 4 + r;
                float v = acc[i][j][r] + bv;
                if (RELU) v = fmaxf(v, 0.f);
                stv(&C[(size_t)row * ldc + col], v);
            }
        }
}

// ---------- fp32 GEMM (small/odd shapes) ----------
template<bool RELU>
__global__ __launch_bounds__(256) void k_gemm_nn(int M, int N, int K,
        const float* __restrict__ A, int lda,
        const float* __restrict__ B, int ldb,
        float* __restrict__ C, int ldc,
        const float* __restrict__ bias) {
    __shared__ float As[16][65];
    __shared__ float Bs[16][65];
    int tid = threadIdx.x;
    int tx = tid & 15, ty = tid >> 4;
    int br = blockIdx.y * 64, bc = blockIdx.x * 64;
    float acc[4][4] = {};
    for (int k0 = 0; k0 < K; k0 += 16) {
#pragma unroll
        for (int c0 = 0; c0 < 4; ++c0) {
            int r = (tid >> 4) + c0 * 16, kk = tid & 15;
            int gr = br + r, gk = k0 + kk;
            As[kk][r] = (gr < M && gk < K) ? A[(size_t)gr * lda + gk] : 0.f;
        }
#pragma unroll
        for (int c0 = 0; c0 < 4; ++c0) {
            int col = tid & 63, kk = (tid >> 6) + c0 * 4;
            int gc = bc + col, gk = k0 + kk;
            Bs[kk][col] = (gc < N && gk < K) ? B[(size_t)gk * ldb + gc] : 0.f;
        }
        __syncthreads();
#pragma unroll
        for (int kk = 0; kk < 16; ++kk) {
            float av[4], bv[4];
#pragma unroll
            for (int i2 = 0; i2 < 4; ++i2) av[i2] = As[kk][ty + 16 * i2];
#pragma unroll
            for (int j2 = 0; j2 < 4; ++j2) bv[j2] = Bs[kk][tx + 16 * j2];
#pragma unroll
            for (int i2 = 0; i2 < 4; ++i2)
#pragma unroll
                for (int j2 = 0; j2 < 4; ++j2) acc[i2][j2] += av[i2] * bv[j2];
        }
        __syncthreads();
    }
#pragma unroll
    for (int i2 = 0; i2 < 4; ++i2)
#pragma unroll
        for (int j2 = 0; j2 < 4; ++j2) {
            int r = br + ty + 16 * i2, c = bc + tx + 16 * j2;
            if (r < M && c < N) {
                float v = acc[i2][j2];
                if (bias) v += bias[c];
                if (RELU) v = fmaxf(v, 0.f);
                C[(size_t)r * ldc + c] = v;
            }
        }
}

// ---------- SpMM wave-per-(row,chunk): C[4096,*] = BITS @ B ----------
template<int NC, int CH>
__global__ __launch_bounds__(256) void k_spmm_wave(
        const unsigned* __restrict__ BITS,
        const float* __restrict__ B, int ldb,
        float* __restrict__ C, int ldc) {
    int gw = blockIdx.x * 4 + (threadIdx.x >> 6);
    int lane = threadIdx.x & 63;
    int row = gw / CH, cb = (gw % CH) * NC;
    if (row >= 4096) return;
    float acc[NC];
#pragma unroll
    for (int j = 0; j < NC; ++j) acc[j] = 0.f;
    const unsigned* bw = &BITS[(size_t)row * 128];
#pragma unroll
    for (int i = 0; i < 2; ++i) {
        int wd = lane * 2 + i;
        unsigned bits = bw[wd];
        int base = wd * 32;
        while (bits) {
            int b = __ffs(bits) - 1; bits &= bits - 1;
            const float* br = &B[(size_t)(base + b) * ldb + cb];
#pragma unroll
            for (int j = 0; j < NC; ++j) acc[j] += br[j];
        }
    }
#pragma unroll
    for (int j = 0; j < NC; ++j) {
#pragma unroll
        for (int off = 1; off < 64; off <<= 1) acc[j] += __shfl_xor(acc[j], off, 64);
    }
    if (lane == 0)
#pragma unroll
        for (int j = 0; j < NC; ++j) C[(size_t)row * ldc + cb + j] = acc[j];
}

// ---------- MFMA flash: split-K (grid.z=2), ld-parametrized, partials out ----------
__global__ __launch_bounds__(256) void k_flash(const ushort_t* __restrict__ Qg, int ldq,
                                               const ushort_t* __restrict__ Kg, int ldk,
                                               const ushort_t* __restrict__ VTg,
                                               ushort_t* __restrict__ OP,
                                               float* __restrict__ Mp,
                                               float* __restrict__ Lp) {
    __shared__ ushort_t Ks[32][136];
    __shared__ ushort_t Vt[128][40];
    __shared__ ushort_t Ps[4][16][40];
    __shared__ float    as_[4][16];
    __shared__ float    ls_[4][16];
    const int tid = threadIdx.x;
    const int lane = tid & 63, wid = tid >> 6;
    const int lrow = lane & 15, lq = lane >> 4;
    const int qb = blockIdx.x * 64, hh = blockIdx.y, z = blockIdx.z;
    const float scale = 0.08838834764831845f;   // 1/sqrt(128)
    bf16x8 qf[4];
    {
        const ushort_t* qrow = &Qg[(size_t)(qb + wid * 16 + lrow) * ldq + hh * 128 + lq * 8];
#pragma unroll
        for (int s = 0; s < 4; ++s) qf[s] = *(const bf16x8*)&qrow[s * 32];
    }
    f32x4 o[8];
#pragma unroll
    for (int ct = 0; ct < 8; ++ct) { o[ct][0] = 0.f; o[ct][1] = 0.f; o[ct][2] = 0.f; o[ct][3] = 0.f; }
    float m = -INFINITY, l = 0.f;
    for (int kt = z * 64; kt < z * 64 + 64; ++kt) {
#pragma unroll
        for (int i = 0; i < 2; ++i) {
            int sid = tid + i * 256;
            int r = sid >> 4, sg = sid & 15;
            *(uint4*)&Ks[r][sg * 8] = *(const uint4*)&Kg[(size_t)(kt * 32 + r) * ldk + hh * 128 + sg * 8];
            int d = sid >> 2, c8 = sid & 3;
            *(uint4*)&Vt[d][c8 * 8] = *(const uint4*)&VTg[(size_t)(hh * 128 + d) * 4096 + kt * 32 + c8 * 8];
        }
        __syncthreads();
        f32x4 sa[2];
#pragma unroll
        for (int c = 0; c < 2; ++c) { sa[c][0] = 0.f; sa[c][1] = 0.f; sa[c][2] = 0.f; sa[c][3] = 0.f; }
#pragma unroll
        for (int c = 0; c < 2; ++c)
#pragma unroll
            for (int st = 0; st < 4; ++st) {
                bf16x8 kf = *(const bf16x8*)&Ks[c * 16 + lrow][st * 32 + lq * 8];
                sa[c] = __builtin_amdgcn_mfma_f32_16x16x32_bf16(kf, qf[st], sa[c], 0, 0, 0);
            }
        float s[8];
        float tm = -INFINITY;
#pragma unroll
        for (int c = 0; c < 2; ++c)
#pragma unroll
            for (int r = 0; r < 4; ++r) { float v = sa[c][r] * scale; s[c * 4 + r] = v; tm = fmaxf(tm, v); }
        tm = fmaxf(tm, __shfl_xor(tm, 16));
        tm = fmaxf(tm, __shfl_xor(tm, 32));
        float mn = fmaxf(m, tm);
        float a = expf(m - mn);
        float su = 0.f;
        float p[8];
#pragma unroll
        for (int i = 0; i < 8; ++i) { p[i] = expf(s[i] - mn); su += p[i]; }
        su += __shfl_xor(su, 16);
        su += __shfl_xor(su, 32);
        m = mn; l = l * a + su;
#pragma unroll
        for (int c = 0; c < 2; ++c)
#pragma unroll
            for (int r = 0; r < 4; ++r)
                Ps[wid][lrow][c * 16 + lq * 4 + r] = f2bf(p[c * 4 + r]);
        if (lq == 0) as_[wid][lrow] = a;
        __builtin_amdgcn_s_waitcnt(0);
        float av[4];
#pragma unroll
        for (int r = 0; r < 4; ++r) av[r] = as_[wid][lq * 4 + r];
#pragma unroll
        for (int ct = 0; ct < 8; ++ct)
#pragma unroll
            for (int r = 0; r < 4; ++r) o[ct][r] *= av[r];
        bf16x8 pf = *(const bf16x8*)&Ps[wid][lrow][lq * 8];
#pragma unroll
        for (int ct = 0; ct < 8; ++ct) {
            bf16x8 vf = *(const bf16x8*)&Vt[ct * 16 + lrow][lq * 8];
            o[ct] = __builtin_amdgcn_mfma_f32_16x16x32_bf16(pf, vf, o[ct], 0, 0, 0);
        }
        __syncthreads();
    }
    if (lq == 0) {
        Mp[(size_t)(z * 4 + hh) * 4096 + qb + wid * 16 + lrow] = m;
        Lp[(size_t)(z * 4 + hh) * 4096 + qb + wid * 16 + lrow] = l;
    }
    ushort_t* ob = OP + (size_t)z * 2097152;
#pragma unroll
    for (int ct = 0; ct < 8; ++ct)
#pragma unroll
        for (int r = 0; r < 4; ++r)
            ob[(size_t)(qb + wid * 16 + lq * 4 + r) * 512 + hh * 128 + ct * 16 + lrow] = f2bf(o[ct][r]);
}

// ---------- flash split-K combine -> Ob ----------
__global__ __launch_bounds__(256) void k_fcomb(const ushort_t* __restrict__ OP,
                                               const float* __restrict__ Mp,
                                               const float* __restrict__ Lp,
                                               ushort_t* __restrict__ Ob) {
    int idx = blockIdx.x * 256 + threadIdx.x;
    if (idx >= 4096 * 512) return;
    int row = idx >> 9, col = idx & 511;
    int hh = col >> 7;
    float m0 = Mp[hh * 4096 + row], m1 = Mp[(4 + hh) * 4096 + row];
    float l0 = Lp[hh * 4096 + row], l1 = Lp[(4 + hh) * 4096 + row];
    float mm = fmaxf(m0, m1);
    float w0 = expf(m0 - mm), w1 = expf(m1 - mm);
    float denom = l0 * w0 + l1 * w1;
    float o0 = bf2f(OP[idx]), o1 = bf2f(OP[2097152 + idx]);
    Ob[idx] = f2bf((o0 * w0 + o1 * w1) / denom);
}

// ---------- residual add + layernorm: writes fp32 H and bf16 Hb ----------
__global__ __launch_bounds__(256) void k_add_ln(const float* __restrict__ A,
                                                const float* __restrict__ B,
                                                float* __restrict__ O,
                                                ushort_t* __restrict__ Ob,
                                                const float* __restrict__ g,
                                                const float* __restrict__ b) {
    __shared__ float xr[512];
    __shared__ float red[256];
    int row = blockIdx.x, t = threadIdx.x;
    const float* a = A + (size_t)row * 512;
    const float* bb = B + (size_t)row * 512;
    float ls = 0.f;
    for (int j = t; j < 512; j += 256) { float v = a[j] + bb[j]; xr[j] = v; ls += v; }
    red[t] = ls; __syncthreads();
    for (int o = 128; o; o >>= 1) { if (t < o) red[t] += red[t + o]; __syncthreads(); }
    float mean = red[0] / 512.0f; __syncthreads();
    float lv = 0.f;
    for (int j = t; j < 512; j += 256) { float d = xr[j] - mean; lv += d * d; }
    red[t] = lv; __syncthreads();
    for (int o = 128; o; o >>= 1) { if (t < o) red[t] += red[t + o]; __syncthreads(); }
    float inv = 1.0f / sqrtf(red[0] / 512.0f + 1e-5f);
    float* o_ = O + (size_t)row * 512;
    ushort_t* ob = Ob + (size_t)row * 512;
    for (int j = t; j < 512; j += 256) {
        float v = (xr[j] - mean) * inv * g[j] + b[j];
        o_[j] = v; ob[j] = f2bf(v);
    }
}

// ---------- fusion head ----------
__global__ __launch_bounds__(128) void k_fusion(const float* __restrict__ subv,
                                                const float* __restrict__ protv,
                                                const float* __restrict__ seqv,
                                                const float* __restrict__ Wtime,
                                                const float* __restrict__ btime,
                                                const float* __restrict__ Wout,
                                                const float* __restrict__ bout,
                                                const int* __restrict__ t_ptr,
                                                const int* __restrict__ lo_ptr,
                                                float* __restrict__ out) {
    __shared__ float cat[80];
    int t = threadIdx.x;
    int tval = guard_int(t_ptr[0], 0, 500);
    int L    = guard_int(lo_ptr[0], 0, 3);
    float tf = (float)((double)tval / 500.0);
    if (t < 20) {
        cat[t] = subv[t];
        cat[20 + t] = protv[t];
        cat[40 + t] = seqv[t];
        cat[60 + t] = tf * Wtime[t] + btime[t];
    }
    __syncthreads();
    for (int j = 0; j < L; ++j) {
        float acc = 0.f;
        if (t < 80) {
            for (int i2 = 0; i2 < 80; ++i2)
                acc += fmaxf(cat[i2], 0.f) * Wout[(size_t)j * 6400 + i2 * 80 + t];
            acc += bout[j * 80 + t];
        }
        __syncthreads();
        if (t < 80) cat[t] = acc;
        __syncthreads();
    }
    if (t < 80) out[t] = fmaxf(cat[t], 0.f);
    if (t < 20) out[80 + t] = seqv[t];
}

// ---------- launch ----------
extern "C" void kernel_launch(void* const* d_in, const int* in_sizes, int n_in,
                              void* d_out, int out_size, void* d_ws, size_t ws_size,
                              hipStream_t stream) {
    static const int EXP[39] = {
        81920, 65536, 200000, 2097152, 2560, 128, 8192, 64, 1280, 20,
        524288, 1024, 524288, 1024, 524288, 1024, 524288, 1024, 1024, 1024,
        2097152, 4096, 2097152, 1024, 1024, 1024, 10240, 20, 19200, 240,
        20, 20, 256, 4096, 4096, 131072, 1, 1, 1 };
    float code = 0.f;
    if (n_in != 39) code = 900.f;
    else {
        for (int i = 0; i < 39; ++i)
            if (in_sizes[i] != EXP[i]) { code = 500.f + 4.f * (float)i; break; }
    }
    const size_t REQ = (size_t)46 * 1024 * 1024;
    if (code == 0.f && ws_size < REQ) code = (float)(ws_size >> 20);
    float* out = (float*)d_out;
    if (code != 0.f) {
        k_sentinel<<<1, 128, 0, stream>>>(out, -code, out_size);
        return;
    }

    const float* x_in   = (const float*)d_in[0];
    const float* adjs_in= (const float*)d_in[1];
    const float* embfp  = (const float*)d_in[2];
    const float* embw   = (const float*)d_in[3];
    const float* gW1 = (const float*)d_in[4];  const float* gb1 = (const float*)d_in[5];
    const float* gW2 = (const float*)d_in[6];  const float* gb2 = (const float*)d_in[7];
    const float* gW3 = (const float*)d_in[8];  const float* gb3 = (const float*)d_in[9];
    const float* Wq  = (const float*)d_in[10]; const float* bq  = (const float*)d_in[11];
    const float* Wk  = (const float*)d_in[12]; const float* bk  = (const float*)d_in[13];
    const float* Wv  = (const float*)d_in[14]; const float* bv  = (const float*)d_in[15];
    const float* Wo  = (const float*)d_in[16]; const float* bo  = (const float*)d_in[17];
    const float* ln1g= (const float*)d_in[18]; const float* ln1b= (const float*)d_in[19];
    const float* Wff1= (const float*)d_in[20]; const float* bff1= (const float*)d_in[21];
    const float* Wff2= (const float*)d_in[22]; const float* bff2= (const float*)d_in[23];
    const float* ln2g= (const float*)d_in[24]; const float* ln2b= (const float*)d_in[25];
    const float* Wproj=(const float*)d_in[26]; const float* bproj=(const float*)d_in[27];
    const float* Woutw=(const float*)d_in[28]; const float* boutw=(const float*)d_in[29];
    const float* Wtime=(const float*)d_in[30]; const float* btime=(const float*)d_in[31];
    const int* fingerprints = (const int*)d_in[32];
    const int* words        = (const int*)d_in[33];
    const int* edge_index   = (const int*)d_in[35];
    const int* t_ptr        = (const int*)d_in[36];
    const int* lo_ptr       = (const int*)d_in[37];

    // ---- workspace (46 MiB) ----
    // [0,2) misc | [2,10) H fp32 | [10,14) Hb | [14,26) QKVb bf16 [4096][1536]
    // [26,30) Ob bf16 | [30,38) T fp32 / OP partials | [38,42) Wscr | [42,46) VTg
    // FFHb [4096][2048] bf16 aliases [14,30). Protein: ADJB at [26,28), temps at [14,26).
    char* wsb = (char*)d_ws;
    float*    misc = (float*)wsb;
    float*    H    = (float*)(wsb + ((size_t)2  << 20));
    ushort_t* Hb   = (ushort_t*)(wsb + ((size_t)10 << 20));
    ushort_t* QKVb = (ushort_t*)(wsb + ((size_t)14 << 20));
    ushort_t* Ob   = (ushort_t*)(wsb + ((size_t)26 << 20));
    ushort_t* FFHb = (ushort_t*)(wsb + ((size_t)14 << 20));
    float*    T    = (float*)(wsb + ((size_t)30 << 20));
    ushort_t* OP   = (ushort_t*)(wsb + ((size_t)30 << 20));
    ushort_t* Wscr = (ushort_t*)(wsb + ((size_t)38 << 20));
    ushort_t* VTg  = (ushort_t*)(wsb + ((size_t)42 << 20));
    unsigned* ADJB = (unsigned*)(wsb + ((size_t)26 << 20));
    float* pt0  = (float*)(wsb + ((size_t)14 << 20));     // [4096][20]
    float* ph1  = pt0 + 81920;                            // [4096][128]
    float* pt1  = ph1 + 524288;                           // [4096][128]
    float* ph2  = pt1 + 524288;                           // [4096][64]
    float* Xoh  = misc;
    float* fpv  = misc + 81920;
    float* st0  = misc + 87040;
    float* sh1  = misc + 92160;
    float* st1  = misc + 124928;
    float* sh2  = misc + 157696;
    float* st2  = misc + 174080;
    float* sgo  = misc + 190464;
    float* subv = misc + 277504;
    float* protv= misc + 277536;
    float* seqv = misc + 277568;
    float* hmean= misc + 280000;     // 512
    float* wsum = misc + 281000;     // 64
    float* deg  = misc + 282000;     // 4096
    float* bqkv = misc + 287000;     // 1536
    float* Mp   = misc + 300000;
    float* Lp   = misc + 360000;

    auto g2 = [](int M, int N) { return dim3((unsigned)((N + 63) / 64), (unsigned)((M + 63) / 64), 1); };
    auto gm64  = [](int M, int N) { return dim3((unsigned)(N / 64), (unsigned)(M / 128), 1); };
    auto gm128 = [](int M, int N) { return dim3((unsigned)(N / 128), (unsigned)(M / 128), 1); };
    auto gt = [](int Kd, int Nd) { return dim3((unsigned)(Nd / 32), (unsigned)(Kd / 32), 1); };

    // 1. diffusion sampling
    k_sample<<<16, 256, 0, stream>>>(x_in, t_ptr, Xoh);

    // 2. substrate GCN (fp32, small)
    k_gather_fp<<<20, 256, 0, stream>>>(embfp, fingerprints, fpv);
    k_gemm_nn<false><<<g2(256, 20), 256, 0, stream>>>(256, 20, 256, adjs_in, 256, fpv, 20, st0, 20, nullptr);
    k_gemm_nn<true ><<<g2(256, 128), 256, 0, stream>>>(256, 128, 20, st0, 20, gW1, 128, sh1, 128, gb1);
    k_gemm_nn<false><<<g2(256, 128), 256, 0, stream>>>(256, 128, 256, adjs_in, 256, sh1, 128, st1, 128, nullptr);
    k_gemm_nn<true ><<<g2(256, 64), 256, 0, stream>>>(256, 64, 128, st1, 128, gW2, 64, sh2, 64, gb2);
    k_gemm_nn<false><<<g2(256, 64), 256, 0, stream>>>(256, 64, 256, adjs_in, 256, sh2, 64, st2, 64, nullptr);
    k_gemm_nn<false><<<g2(256, 20), 256, 0, stream>>>(256, 20, 64, st2, 64, gW3, 20, sgo, 20, gb3);
    k_colmean<<<20, 256, 0, stream>>>(sgo, 256, 20, subv);

    // 3. transformer
    k_embed<<<8192, 256, 0, stream>>>(embw, words, H, Hb);
    for (int l = 0; l < 2; ++l) {
        // weights -> bf16 [N,K]: rows 0-511 Wq^T, 512-1023 Wk^T, 1024-1535 Wv^T, 1536-2047 Wo^T
        k_castT<<<gt(512, 512), 256, 0, stream>>>(Wq + (size_t)l * 262144, Wscr, 512, 512);
        k_castT<<<gt(512, 512), 256, 0, stream>>>(Wk + (size_t)l * 262144, Wscr + 262144, 512, 512);
        k_castT<<<gt(512, 512), 256, 0, stream>>>(Wv + (size_t)l * 262144, Wscr + 524288, 512, 512);
        k_castT<<<gt(512, 512), 256, 0, stream>>>(Wo + (size_t)l * 262144, Wscr + 786432, 512, 512);
        hipMemcpyAsync(bqkv,        bq + l * 512, 2048, hipMemcpyDeviceToDevice, stream);
        hipMemcpyAsync(bqkv + 512,  bk + l * 512, 2048, hipMemcpyDeviceToDevice, stream);
        hipMemcpyAsync(bqkv + 1024, bv + l * 512, 2048, hipMemcpyDeviceToDevice, stream);
        // fused QKV GEMM: [4096,1536]
        k_gemm_mfma2<64, false, ushort_t><<<gm64(4096, 1536), 256, 0, stream>>>(4096, 1536, 512, 512, Hb, Wscr, QKVb, 1536, bqkv);
        k_transposeV<<<dim3(16, 128, 1), 256, 0, stream>>>(QKVb + 1024, 1536, VTg);
        k_flash<<<dim3(64, 4, 2), 256, 0, stream>>>(QKVb, 1536, QKVb + 512, 1536, VTg, OP, Mp, Lp);
        k_fcomb<<<8192, 256, 0, stream>>>(OP, Mp, Lp, Ob);
        k_gemm_mfma2<64, false, float><<<gm64(4096, 512), 256, 0, stream>>>(4096, 512, 512, 512, Ob, Wscr + 786432, T, 512, bo + l * 512);
        k_add_ln<<<4096, 256, 0, stream>>>(H, T, H, Hb, ln1g + l * 512, ln1b + l * 512);
        k_castT<<<gt(512, 2048), 256, 0, stream>>>(Wff1 + (size_t)l * 1048576, Wscr, 512, 2048);
        k_gemm_mfma2<128, true, ushort_t><<<gm128(4096, 2048), 256, 0, stream>>>(4096, 2048, 512, 512, Hb, Wscr, FFHb, 2048, bff1 + l * 2048);
        k_castT<<<gt(2048, 512), 256, 0, stream>>>(Wff2 + (size_t)l * 1048576, Wscr, 2048, 512);
        k_gemm_mfma2<64, false, float><<<gm64(4096, 512), 256, 0, stream>>>(4096, 512, 2048, 2048, FFHb, Wscr, T, 512, bff2 + l * 512);
        k_add_ln<<<4096, 256, 0, stream>>>(H, T, H, Hb, ln2g + l * 512, ln2b + l * 512);
    }

    // 4. seq = mean(H) @ Wproj + bproj   (exact linearity)
    k_colmean<<<512, 256, 0, stream>>>(H, 4096, 512, hmean);
    k_matvec20<<<1, 32, 0, stream>>>(512, 1.0f, hmean, Wproj, bproj, seqv);

    // 5. protein GCN (bitmap SpMM wave-parallel + degree-trick tail)
    hipMemsetAsync(ADJB, 0, (size_t)4096 * 128 * 4, stream);
    hipMemsetAsync(deg, 0, 4096 * 4, stream);
    k_scatter_bits<<<256, 256, 0, stream>>>(edge_index, ADJB);
    k_spmm_wave<20, 1><<<1024, 256, 0, stream>>>(ADJB, Xoh, 20, pt0, 20);
    k_gemm_nn<true ><<<g2(4096, 128), 256, 0, stream>>>(4096, 128, 20, pt0, 20, gW1, 128, ph1, 128, gb1);
    k_spmm_wave<32, 4><<<4096, 256, 0, stream>>>(ADJB, ph1, 128, pt1, 128);
    k_gemm_nn<true ><<<g2(4096, 64), 256, 0, stream>>>(4096, 64, 128, pt1, 128, gW2, 64, ph2, 64, gb2);
    k_degree<<<2048, 256, 0, stream>>>(ADJB, deg);
    k_wcolsum<<<64, 256, 0, stream>>>(ph2, 4096, 64, deg, wsum);
    k_matvec20<<<1, 32, 0, stream>>>(64, 1.0f / 4096.0f, wsum, gW3, gb3, protv);

    // 6. fusion head
    k_fusion<<<1, 128, 0, stream>>>(subv, protv, seqv, Wtime, btime, Woutw, boutw, t_ptr, lo_ptr, out);
}

// Round 14
// 948.932 us; speedup vs baseline: 9.9017x; 1.0940x over previous
//
#include <hip/hip_runtime.h>
#include <math.h>

typedef unsigned short ushort_t;
typedef __attribute__((ext_vector_type(8))) short bf16x8;
typedef __attribute__((ext_vector_type(4))) float f32x4;

// ---------- helpers ----------
__device__ inline float bf2f(unsigned u) { return __uint_as_float((u & 0xffffu) << 16); }
__device__ inline ushort_t f2bf(float f) {
    unsigned u = __float_as_uint(f);
    return (ushort_t)((u + 0x7fffu + ((u >> 16) & 1u)) >> 16);   // RNE
}
__device__ inline void stv(float* p, float v) { *p = v; }
__device__ inline void stv(ushort_t* p, float v) { *p = f2bf(v); }
__device__ inline int guard_int(int raw, int lo, int hi) {
    if (raw >= lo && raw <= hi) return raw;
    float f = __int_as_float(raw);
    int v = (int)f;
    return (v >= lo && v <= hi) ? v : lo;
}

// ---------- threefry2x32 (JAX partitionable, verified R7) ----------
__device__ inline void tf2x32(unsigned k0, unsigned k1, unsigned x0, unsigned x1,
                              unsigned& o0, unsigned& o1) {
    unsigned ks2 = k0 ^ k1 ^ 0x1BD11BDAu;
    x0 += k0; x1 += k1;
#define TFR(r) { x0 += x1; x1 = (x1 << (r)) | (x1 >> (32 - (r))); x1 ^= x0; }
    TFR(13) TFR(15) TFR(26) TFR(6)  x0 += k1;  x1 += ks2 + 1u;
    TFR(17) TFR(29) TFR(16) TFR(24) x0 += ks2; x1 += k0 + 2u;
    TFR(13) TFR(15) TFR(26) TFR(6)  x0 += k0;  x1 += k1 + 3u;
    TFR(17) TFR(29) TFR(16) TFR(24) x0 += k1;  x1 += ks2 + 4u;
    TFR(13) TFR(15) TFR(26) TFR(6)  x0 += ks2; x1 += k0 + 5u;
#undef TFR
    o0 = x0; o1 = x1;
}

__global__ void k_sentinel(float* __restrict__ out, float val, int n) {
    int i = blockIdx.x * 128 + threadIdx.x;
    if (i < n) out[i] = val;
}

// ---------- diffusion categorical sampling -> one-hot X ----------
__global__ __launch_bounds__(256) void k_sample(const float* __restrict__ x,
                                                const int* __restrict__ t_ptr,
                                                float* __restrict__ X) {
    int i = blockIdx.x * 256 + threadIdx.x;
    if (i >= 4096) return;
    int tval = guard_int(t_ptr[0], 0, 500);
    double tf = (double)tval / 500.0;
    const double sc = 0.008;
    const double PI_HALF = 1.5707963267948966;
    double num = cos((tf + sc) / (1.0 + sc) * PI_HALF);
    double den = cos(sc / (1.0 + sc) * PI_HALF);
    float ab = (float)((num * num) / (den * den));
    float phi = (1.0f - ab) / 20.0f;
    float xv[20]; float sx = 0.f;
    for (int j = 0; j < 20; ++j) { xv[j] = x[i * 20 + j]; sx += xv[j]; }
    float best = -1e30f; int bj = 0;
    for (int j = 0; j < 20; ++j) {
        float prob = fmaxf(ab * xv[j] + phi * sx, 0.0f);
        float lp = logf(prob + 1e-9f);
        unsigned m = (unsigned)(i * 20 + j);
        unsigned o0, o1;
        tf2x32(0u, 42u, 0u, m, o0, o1);
        unsigned bits = o0 ^ o1;
        float u = __uint_as_float((bits >> 9) | 0x3f800000u) - 1.0f;
        if (u < 1.1754943508222875e-38f) u = 1.1754943508222875e-38f;
        float gmb = -logf(-logf(u));
        float z = lp + gmb;
        if (z > best) { best = z; bj = j; }
    }
    for (int j = 0; j < 20; ++j) X[i * 20 + j] = (j == bj) ? 1.0f : 0.0f;
}

// ---------- small utility kernels ----------
__global__ __launch_bounds__(256) void k_gather_fp(const float* __restrict__ emb,
                                                   const int* __restrict__ idx,
                                                   float* __restrict__ out) {
    int i = blockIdx.x * 256 + threadIdx.x;
    if (i >= 256 * 20) return;
    int a = i / 20, d = i % 20;
    out[i] = emb[(size_t)idx[a] * 20 + d];
}

__global__ __launch_bounds__(256) void k_scatter_bits(const int* __restrict__ ei,
                                                      unsigned* __restrict__ bits) {
    int e = blockIdx.x * 256 + threadIdx.x;
    if (e >= 65536) return;
    int r = ei[e], c = ei[65536 + e];
    atomicOr(&bits[(size_t)r * 128 + (c >> 5)], 1u << (c & 31));
}

// column degree from bitmap: deg[c] = #rows with bit c set
__global__ __launch_bounds__(256) void k_degree(const unsigned* __restrict__ BITS,
                                                float* __restrict__ deg) {
    int i = blockIdx.x * 256 + threadIdx.x;
    if (i >= 4096 * 128) return;
    unsigned bits = BITS[i];
    int base = (i & 127) * 32;
    while (bits) { int b = __ffs(bits) - 1; bits &= bits - 1; atomicAdd(&deg[base + b], 1.0f); }
}

__global__ __launch_bounds__(256) void k_embed(const float* __restrict__ embw,
                                               const int* __restrict__ words,
                                               float* __restrict__ H,
                                               ushort_t* __restrict__ Hb) {
    int idx = blockIdx.x * 256 + threadIdx.x;
    if (idx >= 4096 * 512) return;
    int pos = idx >> 9, d = idx & 511;
    float e = embw[(size_t)words[pos] * 512 + d];
    float expo = (float)(d >> 1) * (1.0f / 256.0f);
    float ang = (float)pos * exp2f(-expo * 13.287712379549449f);
    float pe = (d & 1) ? cosf(ang) : sinf(ang);
    float v = e + pe;
    H[idx] = v; Hb[idx] = f2bf(v);
}

__global__ __launch_bounds__(256) void k_colmean(const float* __restrict__ M, int R, int C,
                                                 float* __restrict__ out) {
    __shared__ float red[256];
    int c = blockIdx.x, t = threadIdx.x;
    float s = 0.f;
    for (int r = t; r < R; r += 256) s += M[(size_t)r * C + c];
    red[t] = s; __syncthreads();
    for (int o = 128; o; o >>= 1) { if (t < o) red[t] += red[t + o]; __syncthreads(); }
    if (t == 0) out[c] = red[0] / (float)R;
}

// weighted column sum: out[c] = sum_r w[r] * M[r*C+c]   (C = gridDim.x)
__global__ __launch_bounds__(256) void k_wcolsum(const float* __restrict__ M, int R, int C,
                                                 const float* __restrict__ w,
                                                 float* __restrict__ out) {
    __shared__ float red[256];
    int c = blockIdx.x, t = threadIdx.x;
    float s = 0.f;
    for (int r = t; r < R; r += 256) s += w[r] * M[(size_t)r * C + c];
    red[t] = s; __syncthreads();
    for (int o = 128; o; o >>= 1) { if (t < o) red[t] += red[t + o]; __syncthreads(); }
    if (t == 0) out[c] = red[0];
}

// parallel matvec: block c computes out[c] = scale*(vec . W[:,c]) + bias[c]
// (R13 fix: the 32-thread serial version was latency-bound at 135 us)
__global__ __launch_bounds__(256) void k_matvec20(int D, float scale,
                                                  const float* __restrict__ vec,
                                                  const float* __restrict__ W,
                                                  const float* __restrict__ bias,
                                                  float* __restrict__ out) {
    __shared__ float red[256];
    int c = blockIdx.x, t = threadIdx.x;
    float s = 0.f;
    for (int d = t; d < D; d += 256) s += vec[d] * W[(size_t)d * 20 + c];
    red[t] = s; __syncthreads();
    for (int o = 128; o; o >>= 1) { if (t < o) red[t] += red[t + o]; __syncthreads(); }
    if (t == 0) out[c] = red[0] * scale + bias[c];
}

// ---------- weight cast+transpose: fp32 [K,N] -> bf16 [N,K] ----------
__global__ __launch_bounds__(256) void k_castT(const float* __restrict__ in,
                                               ushort_t* __restrict__ out,
                                               int Kd, int Nd) {
    __shared__ float t[32][33];
    int bx = blockIdx.x * 32, by = blockIdx.y * 32;
    int tx = threadIdx.x & 31, ty = threadIdx.x >> 5;
#pragma unroll
    for (int i = 0; i < 4; ++i)
        t[ty + i * 8][tx] = in[(size_t)(by + ty + i * 8) * Nd + bx + tx];
    __syncthreads();
#pragma unroll
    for (int i = 0; i < 4; ++i)
        out[(size_t)(bx + ty + i * 8) * Kd + by + tx] = f2bf(t[tx][ty + i * 8]);
}

// ---------- bf16 transpose: in [4096][ld] (512-col slice) -> out [512][4096] ----------
__global__ __launch_bounds__(256) void k_transposeV(const ushort_t* __restrict__ in, int ldin,
                                                    ushort_t* __restrict__ out) {
    __shared__ ushort_t t[32][33];
    int bx = blockIdx.x * 32;
    int by = blockIdx.y * 32;
    int tx = threadIdx.x & 31, ty = threadIdx.x >> 5;
#pragma unroll
    for (int i = 0; i < 4; ++i)
        t[ty + i * 8][tx] = in[(size_t)(by + ty + i * 8) * ldin + bx + tx];
    __syncthreads();
#pragma unroll
    for (int i = 0; i < 4; ++i)
        out[(size_t)(bx + ty + i * 8) * 4096 + by + tx] = t[tx][ty + i * 8];
}

// ---------- MFMA bf16 GEMM: BM=128 x BN tile, lda-parametrized A ----------
template<int BN, bool RELU, typename TC>
__global__ __launch_bounds__(256) void k_gemm_mfma2(int M, int N, int K, int lda,
        const ushort_t* __restrict__ A,
        const ushort_t* __restrict__ Bt,
        TC* __restrict__ C, int ldc,
        const float* __restrict__ bias) {
    constexpr int NJ = BN / 32;
    __shared__ ushort_t As[128][40];
    __shared__ ushort_t Bs[BN][40];
    int tid = threadIdx.x;
    int lane = tid & 63, wave = tid >> 6;
    int wr = wave >> 1, wc = wave & 1;
    int lrow = lane & 15, lq = lane >> 4;
    int br = blockIdx.y * 128, bc = blockIdx.x * BN;
    f32x4 acc[4][NJ];
#pragma unroll
    for (int i = 0; i < 4; ++i)
#pragma unroll
        for (int j = 0; j < NJ; ++j) { acc[i][j][0] = 0.f; acc[i][j][1] = 0.f; acc[i][j][2] = 0.f; acc[i][j][3] = 0.f; }
    int sr = tid >> 2, sseg = tid & 3;
    for (int k0 = 0; k0 < K; k0 += 32) {
#pragma unroll
        for (int it = 0; it < 2; ++it)
            *(uint4*)&As[sr + it * 64][sseg * 8] = *(const uint4*)&A[(size_t)(br + sr + it * 64) * lda + k0 + sseg * 8];
#pragma unroll
        for (int it = 0; it < BN / 64; ++it)
            *(uint4*)&Bs[sr + it * 64][sseg * 8] = *(const uint4*)&Bt[(size_t)(bc + sr + it * 64) * K + k0 + sseg * 8];
        __syncthreads();
        bf16x8 af[4], bfr[NJ];
#pragma unroll
        for (int i = 0; i < 4; ++i) af[i] = *(const bf16x8*)&As[wr * 64 + i * 16 + lrow][lq * 8];
#pragma unroll
        for (int j = 0; j < NJ; ++j) bfr[j] = *(const bf16x8*)&Bs[wc * (BN / 2) + j * 16 + lrow][lq * 8];
#pragma unroll
        for (int i = 0; i < 4; ++i)
#pragma unroll
            for (int j = 0; j < NJ; ++j)
                acc[i][j] = __builtin_amdgcn_mfma_f32_16x16x32_bf16(af[i], bfr[j], acc[i][j], 0, 0, 0);
        __syncthreads();
    }
#pragma unroll
    for (int i = 0; i < 4; ++i)
#pragma unroll
        for (int j = 0; j < NJ; ++j) {
            int col = bc + wc * (BN / 2) + j * 16 + lrow;
            float bv = bias ? bias[col] : 0.f;
#pragma unroll
            for (int r = 0; r < 4; ++r) {
                int row = br + wr * 64 + i * 16 + lq * 4 + r;
                float v = acc[i][j][r] + bv;
                if (RELU) v = fmaxf(v, 0.f);
                stv(&C[(size_t)row * ldc + col], v);
            }
        }
}

// ---------- fp32 GEMM (small/odd shapes) ----------
template<bool RELU>
__global__ __launch_bounds__(256) void k_gemm_nn(int M, int N, int K,
        const float* __restrict__ A, int lda,
        const float* __restrict__ B, int ldb,
        float* __restrict__ C, int ldc,
        const float* __restrict__ bias) {
    __shared__ float As[16][65];
    __shared__ float Bs[16][65];
    int tid = threadIdx.x;
    int tx = tid & 15, ty = tid >> 4;
    int br = blockIdx.y * 64, bc = blockIdx.x * 64;
    float acc[4][4] = {};
    for (int k0 = 0; k0 < K; k0 += 16) {
#pragma unroll
        for (int c0 = 0; c0 < 4; ++c0) {
            int r = (tid >> 4) + c0 * 16, kk = tid & 15;
            int gr = br + r, gk = k0 + kk;
            As[kk][r] = (gr < M && gk < K) ? A[(size_t)gr * lda + gk] : 0.f;
        }
#pragma unroll
        for (int c0 = 0; c0 < 4; ++c0) {
            int col = tid & 63, kk = (tid >> 6) + c0 * 4;
            int gc = bc + col, gk = k0 + kk;
            Bs[kk][col] = (gc < N && gk < K) ? B[(size_t)gk * ldb + gc] : 0.f;
        }
        __syncthreads();
#pragma unroll
        for (int kk = 0; kk < 16; ++kk) {
            float av[4], bv[4];
#pragma unroll
            for (int i2 = 0; i2 < 4; ++i2) av[i2] = As[kk][ty + 16 * i2];
#pragma unroll
            for (int j2 = 0; j2 < 4; ++j2) bv[j2] = Bs[kk][tx + 16 * j2];
#pragma unroll
            for (int i2 = 0; i2 < 4; ++i2)
#pragma unroll
                for (int j2 = 0; j2 < 4; ++j2) acc[i2][j2] += av[i2] * bv[j2];
        }
        __syncthreads();
    }
#pragma unroll
    for (int i2 = 0; i2 < 4; ++i2)
#pragma unroll
        for (int j2 = 0; j2 < 4; ++j2) {
            int r = br + ty + 16 * i2, c = bc + tx + 16 * j2;
            if (r < M && c < N) {
                float v = acc[i2][j2];
                if (bias) v += bias[c];
                if (RELU) v = fmaxf(v, 0.f);
                C[(size_t)r * ldc + c] = v;
            }
        }
}

// ---------- SpMM wave-per-(row,chunk): C[4096,*] = BITS @ B ----------
template<int NC, int CH>
__global__ __launch_bounds__(256) void k_spmm_wave(
        const unsigned* __restrict__ BITS,
        const float* __restrict__ B, int ldb,
        float* __restrict__ C, int ldc) {
    int gw = blockIdx.x * 4 + (threadIdx.x >> 6);
    int lane = threadIdx.x & 63;
    int row = gw / CH, cb = (gw % CH) * NC;
    if (row >= 4096) return;
    float acc[NC];
#pragma unroll
    for (int j = 0; j < NC; ++j) acc[j] = 0.f;
    const unsigned* bw = &BITS[(size_t)row * 128];
#pragma unroll
    for (int i = 0; i < 2; ++i) {
        int wd = lane * 2 + i;
        unsigned bits = bw[wd];
        int base = wd * 32;
        while (bits) {
            int b = __ffs(bits) - 1; bits &= bits - 1;
            const float* br = &B[(size_t)(base + b) * ldb + cb];
#pragma unroll
            for (int j = 0; j < NC; ++j) acc[j] += br[j];
        }
    }
#pragma unroll
    for (int j = 0; j < NC; ++j) {
#pragma unroll
        for (int off = 1; off < 64; off <<= 1) acc[j] += __shfl_xor(acc[j], off, 64);
    }
    if (lane == 0)
#pragma unroll
        for (int j = 0; j < NC; ++j) C[(size_t)row * ldc + cb + j] = acc[j];
}

// ---------- MFMA flash: split-K (grid.z=2), ld-parametrized, partials out ----------
__global__ __launch_bounds__(256) void k_flash(const ushort_t* __restrict__ Qg, int ldq,
                                               const ushort_t* __restrict__ Kg, int ldk,
                                               const ushort_t* __restrict__ VTg,
                                               ushort_t* __restrict__ OP,
                                               float* __restrict__ Mp,
                                               float* __restrict__ Lp) {
    __shared__ ushort_t Ks[32][136];
    __shared__ ushort_t Vt[128][40];
    __shared__ ushort_t Ps[4][16][40];
    __shared__ float    as_[4][16];
    __shared__ float    ls_[4][16];
    const int tid = threadIdx.x;
    const int lane = tid & 63, wid = tid >> 6;
    const int lrow = lane & 15, lq = lane >> 4;
    const int qb = blockIdx.x * 64, hh = blockIdx.y, z = blockIdx.z;
    const float scale = 0.08838834764831845f;   // 1/sqrt(128)
    bf16x8 qf[4];
    {
        const ushort_t* qrow = &Qg[(size_t)(qb + wid * 16 + lrow) * ldq + hh * 128 + lq * 8];
#pragma unroll
        for (int s = 0; s < 4; ++s) qf[s] = *(const bf16x8*)&qrow[s * 32];
    }
    f32x4 o[8];
#pragma unroll
    for (int ct = 0; ct < 8; ++ct) { o[ct][0] = 0.f; o[ct][1] = 0.f; o[ct][2] = 0.f; o[ct][3] = 0.f; }
    float m = -INFINITY, l = 0.f;
    for (int kt = z * 64; kt < z * 64 + 64; ++kt) {
#pragma unroll
        for (int i = 0; i < 2; ++i) {
            int sid = tid + i * 256;
            int r = sid >> 4, sg = sid & 15;
            *(uint4*)&Ks[r][sg * 8] = *(const uint4*)&Kg[(size_t)(kt * 32 + r) * ldk + hh * 128 + sg * 8];
            int d = sid >> 2, c8 = sid & 3;
            *(uint4*)&Vt[d][c8 * 8] = *(const uint4*)&VTg[(size_t)(hh * 128 + d) * 4096 + kt * 32 + c8 * 8];
        }
        __syncthreads();
        f32x4 sa[2];
#pragma unroll
        for (int c = 0; c < 2; ++c) { sa[c][0] = 0.f; sa[c][1] = 0.f; sa[c][2] = 0.f; sa[c][3] = 0.f; }
#pragma unroll
        for (int c = 0; c < 2; ++c)
#pragma unroll
            for (int st = 0; st < 4; ++st) {
                bf16x8 kf = *(const bf16x8*)&Ks[c * 16 + lrow][st * 32 + lq * 8];
                sa[c] = __builtin_amdgcn_mfma_f32_16x16x32_bf16(kf, qf[st], sa[c], 0, 0, 0);
            }
        float s[8];
        float tm = -INFINITY;
#pragma unroll
        for (int c = 0; c < 2; ++c)
#pragma unroll
            for (int r = 0; r < 4; ++r) { float v = sa[c][r] * scale; s[c * 4 + r] = v; tm = fmaxf(tm, v); }
        tm = fmaxf(tm, __shfl_xor(tm, 16));
        tm = fmaxf(tm, __shfl_xor(tm, 32));
        float mn = fmaxf(m, tm);
        float a = expf(m - mn);
        float su = 0.f;
        float p[8];
#pragma unroll
        for (int i = 0; i < 8; ++i) { p[i] = expf(s[i] - mn); su += p[i]; }
        su += __shfl_xor(su, 16);
        su += __shfl_xor(su, 32);
        m = mn; l = l * a + su;
#pragma unroll
        for (int c = 0; c < 2; ++c)
#pragma unroll
            for (int r = 0; r < 4; ++r)
                Ps[wid][lrow][c * 16 + lq * 4 + r] = f2bf(p[c * 4 + r]);
        if (lq == 0) as_[wid][lrow] = a;
        __builtin_amdgcn_s_waitcnt(0);
        float av[4];
#pragma unroll
        for (int r = 0; r < 4; ++r) av[r] = as_[wid][lq * 4 + r];
#pragma unroll
        for (int ct = 0; ct < 8; ++ct)
#pragma unroll
            for (int r = 0; r < 4; ++r) o[ct][r] *= av[r];
        bf16x8 pf = *(const bf16x8*)&Ps[wid][lrow][lq * 8];
#pragma unroll
        for (int ct = 0; ct < 8; ++ct) {
            bf16x8 vf = *(const bf16x8*)&Vt[ct * 16 + lrow][lq * 8];
            o[ct] = __builtin_amdgcn_mfma_f32_16x16x32_bf16(pf, vf, o[ct], 0, 0, 0);
        }
        __syncthreads();
    }
    if (lq == 0) {
        Mp[(size_t)(z * 4 + hh) * 4096 + qb + wid * 16 + lrow] = m;
        Lp[(size_t)(z * 4 + hh) * 4096 + qb + wid * 16 + lrow] = l;
    }
    ushort_t* ob = OP + (size_t)z * 2097152;
#pragma unroll
    for (int ct = 0; ct < 8; ++ct)
#pragma unroll
        for (int r = 0; r < 4; ++r)
            ob[(size_t)(qb + wid * 16 + lq * 4 + r) * 512 + hh * 128 + ct * 16 + lrow] = f2bf(o[ct][r]);
}

// ---------- flash split-K combine -> Ob ----------
__global__ __launch_bounds__(256) void k_fcomb(const ushort_t* __restrict__ OP,
                                               const float* __restrict__ Mp,
                                               const float* __restrict__ Lp,
                                               ushort_t* __restrict__ Ob) {
    int idx = blockIdx.x * 256 + threadIdx.x;
    if (idx >= 4096 * 512) return;
    int row = idx >> 9, col = idx & 511;
    int hh = col >> 7;
    float m0 = Mp[hh * 4096 + row], m1 = Mp[(4 + hh) * 4096 + row];
    float l0 = Lp[hh * 4096 + row], l1 = Lp[(4 + hh) * 4096 + row];
    float mm = fmaxf(m0, m1);
    float w0 = expf(m0 - mm), w1 = expf(m1 - mm);
    float denom = l0 * w0 + l1 * w1;
    float o0 = bf2f(OP[idx]), o1 = bf2f(OP[2097152 + idx]);
    Ob[idx] = f2bf((o0 * w0 + o1 * w1) / denom);
}

// ---------- residual add + layernorm: writes fp32 H and bf16 Hb ----------
__global__ __launch_bounds__(256) void k_add_ln(const float* __restrict__ A,
                                                const float* __restrict__ B,
                                                float* __restrict__ O,
                                                ushort_t* __restrict__ Ob,
                                                const float* __restrict__ g,
                                                const float* __restrict__ b) {
    __shared__ float xr[512];
    __shared__ float red[256];
    int row = blockIdx.x, t = threadIdx.x;
    const float* a = A + (size_t)row * 512;
    const float* bb = B + (size_t)row * 512;
    float ls = 0.f;
    for (int j = t; j < 512; j += 256) { float v = a[j] + bb[j]; xr[j] = v; ls += v; }
    red[t] = ls; __syncthreads();
    for (int o = 128; o; o >>= 1) { if (t < o) red[t] += red[t + o]; __syncthreads(); }
    float mean = red[0] / 512.0f; __syncthreads();
    float lv = 0.f;
    for (int j = t; j < 512; j += 256) { float d = xr[j] - mean; lv += d * d; }
    red[t] = lv; __syncthreads();
    for (int o = 128; o; o >>= 1) { if (t < o) red[t] += red[t + o]; __syncthreads(); }
    float inv = 1.0f / sqrtf(red[0] / 512.0f + 1e-5f);
    float* o_ = O + (size_t)row * 512;
    ushort_t* ob = Ob + (size_t)row * 512;
    for (int j = t; j < 512; j += 256) {
        float v = (xr[j] - mean) * inv * g[j] + b[j];
        o_[j] = v; ob[j] = f2bf(v);
    }
}

// ---------- fusion head ----------
__global__ __launch_bounds__(128) void k_fusion(const float* __restrict__ subv,
                                                const float* __restrict__ protv,
                                                const float* __restrict__ seqv,
                                                const float* __restrict__ Wtime,
                                                const float* __restrict__ btime,
                                                const float* __restrict__ Wout,
                                                const float* __restrict__ bout,
                                                const int* __restrict__ t_ptr,
                                                const int* __restrict__ lo_ptr,
                                                float* __restrict__ out) {
    __shared__ float cat[80];
    int t = threadIdx.x;
    int tval = guard_int(t_ptr[0], 0, 500);
    int L    = guard_int(lo_ptr[0], 0, 3);
    float tf = (float)((double)tval / 500.0);
    if (t < 20) {
        cat[t] = subv[t];
        cat[20 + t] = protv[t];
        cat[40 + t] = seqv[t];
        cat[60 + t] = tf * Wtime[t] + btime[t];
    }
    __syncthreads();
    for (int j = 0; j < L; ++j) {
        float acc = 0.f;
        if (t < 80) {
            for (int i2 = 0; i2 < 80; ++i2)
                acc += fmaxf(cat[i2], 0.f) * Wout[(size_t)j * 6400 + i2 * 80 + t];
            acc += bout[j * 80 + t];
        }
        __syncthreads();
        if (t < 80) cat[t] = acc;
        __syncthreads();
    }
    if (t < 80) out[t] = fmaxf(cat[t], 0.f);
    if (t < 20) out[80 + t] = seqv[t];
}

// ---------- launch ----------
extern "C" void kernel_launch(void* const* d_in, const int* in_sizes, int n_in,
                              void* d_out, int out_size, void* d_ws, size_t ws_size,
                              hipStream_t stream) {
    static const int EXP[39] = {
        81920, 65536, 200000, 2097152, 2560, 128, 8192, 64, 1280, 20,
        524288, 1024, 524288, 1024, 524288, 1024, 524288, 1024, 1024, 1024,
        2097152, 4096, 2097152, 1024, 1024, 1024, 10240, 20, 19200, 240,
        20, 20, 256, 4096, 4096, 131072, 1, 1, 1 };
    float code = 0.f;
    if (n_in != 39) code = 900.f;
    else {
        for (int i = 0; i < 39; ++i)
            if (in_sizes[i] != EXP[i]) { code = 500.f + 4.f * (float)i; break; }
    }
    const size_t REQ = (size_t)46 * 1024 * 1024;
    if (code == 0.f && ws_size < REQ) code = (float)(ws_size >> 20);
    float* out = (float*)d_out;
    if (code != 0.f) {
        k_sentinel<<<1, 128, 0, stream>>>(out, -code, out_size);
        return;
    }

    const float* x_in   = (const float*)d_in[0];
    const float* adjs_in= (const float*)d_in[1];
    const float* embfp  = (const float*)d_in[2];
    const float* embw   = (const float*)d_in[3];
    const float* gW1 = (const float*)d_in[4];  const float* gb1 = (const float*)d_in[5];
    const float* gW2 = (const float*)d_in[6];  const float* gb2 = (const float*)d_in[7];
    const float* gW3 = (const float*)d_in[8];  const float* gb3 = (const float*)d_in[9];
    const float* Wq  = (const float*)d_in[10]; const float* bq  = (const float*)d_in[11];
    const float* Wk  = (const float*)d_in[12]; const float* bk  = (const float*)d_in[13];
    const float* Wv  = (const float*)d_in[14]; const float* bv  = (const float*)d_in[15];
    const float* Wo  = (const float*)d_in[16]; const float* bo  = (const float*)d_in[17];
    const float* ln1g= (const float*)d_in[18]; const float* ln1b= (const float*)d_in[19];
    const float* Wff1= (const float*)d_in[20]; const float* bff1= (const float*)d_in[21];
    const float* Wff2= (const float*)d_in[22]; const float* bff2= (const float*)d_in[23];
    const float* ln2g= (const float*)d_in[24]; const float* ln2b= (const float*)d_in[25];
    const float* Wproj=(const float*)d_in[26]; const float* bproj=(const float*)d_in[27];
    const float* Woutw=(const float*)d_in[28]; const float* boutw=(const float*)d_in[29];
    const float* Wtime=(const float*)d_in[30]; const float* btime=(const float*)d_in[31];
    const int* fingerprints = (const int*)d_in[32];
    const int* words        = (const int*)d_in[33];
    const int* edge_index   = (const int*)d_in[35];
    const int* t_ptr        = (const int*)d_in[36];
    const int* lo_ptr       = (const int*)d_in[37];

    // ---- workspace (46 MiB) ----
    char* wsb = (char*)d_ws;
    float*    misc = (float*)wsb;
    float*    H    = (float*)(wsb + ((size_t)2  << 20));
    ushort_t* Hb   = (ushort_t*)(wsb + ((size_t)10 << 20));
    ushort_t* QKVb = (ushort_t*)(wsb + ((size_t)14 << 20));
    ushort_t* Ob   = (ushort_t*)(wsb + ((size_t)26 << 20));
    ushort_t* FFHb = (ushort_t*)(wsb + ((size_t)14 << 20));
    float*    T    = (float*)(wsb + ((size_t)30 << 20));
    ushort_t* OP   = (ushort_t*)(wsb + ((size_t)30 << 20));
    ushort_t* Wscr = (ushort_t*)(wsb + ((size_t)38 << 20));
    ushort_t* VTg  = (ushort_t*)(wsb + ((size_t)42 << 20));
    unsigned* ADJB = (unsigned*)(wsb + ((size_t)26 << 20));
    float* pt0  = (float*)(wsb + ((size_t)14 << 20));
    float* ph1  = pt0 + 81920;
    float* pt1  = ph1 + 524288;
    float* ph2  = pt1 + 524288;
    float* Xoh  = misc;
    float* fpv  = misc + 81920;
    float* st0  = misc + 87040;
    float* sh1  = misc + 92160;
    float* st1  = misc + 124928;
    float* sh2  = misc + 157696;
    float* st2  = misc + 174080;
    float* sgo  = misc + 190464;
    float* subv = misc + 277504;
    float* protv= misc + 277536;
    float* seqv = misc + 277568;
    float* hmean= misc + 280000;
    float* wsum = misc + 281000;
    float* deg  = misc + 282000;
    float* bqkv = misc + 287000;
    float* Mp   = misc + 300000;
    float* Lp   = misc + 360000;

    auto g2 = [](int M, int N) { return dim3((unsigned)((N + 63) / 64), (unsigned)((M + 63) / 64), 1); };
    auto gm64  = [](int M, int N) { return dim3((unsigned)(N / 64), (unsigned)(M / 128), 1); };
    auto gm128 = [](int M, int N) { return dim3((unsigned)(N / 128), (unsigned)(M / 128), 1); };
    auto gt = [](int Kd, int Nd) { return dim3((unsigned)(Nd / 32), (unsigned)(Kd / 32), 1); };

    // 1. diffusion sampling
    k_sample<<<16, 256, 0, stream>>>(x_in, t_ptr, Xoh);

    // 2. substrate GCN (fp32, small)
    k_gather_fp<<<20, 256, 0, stream>>>(embfp, fingerprints, fpv);
    k_gemm_nn<false><<<g2(256, 20), 256, 0, stream>>>(256, 20, 256, adjs_in, 256, fpv, 20, st0, 20, nullptr);
    k_gemm_nn<true ><<<g2(256, 128), 256, 0, stream>>>(256, 128, 20, st0, 20, gW1, 128, sh1, 128, gb1);
    k_gemm_nn<false><<<g2(256, 128), 256, 0, stream>>>(256, 128, 256, adjs_in, 256, sh1, 128, st1, 128, nullptr);
    k_gemm_nn<true ><<<g2(256, 64), 256, 0, stream>>>(256, 64, 128, st1, 128, gW2, 64, sh2, 64, gb2);
    k_gemm_nn<false><<<g2(256, 64), 256, 0, stream>>>(256, 64, 256, adjs_in, 256, sh2, 64, st2, 64, nullptr);
    k_gemm_nn<false><<<g2(256, 20), 256, 0, stream>>>(256, 20, 64, st2, 64, gW3, 20, sgo, 20, gb3);
    k_colmean<<<20, 256, 0, stream>>>(sgo, 256, 20, subv);

    // 3. transformer
    k_embed<<<8192, 256, 0, stream>>>(embw, words, H, Hb);
    for (int l = 0; l < 2; ++l) {
        k_castT<<<gt(512, 512), 256, 0, stream>>>(Wq + (size_t)l * 262144, Wscr, 512, 512);
        k_castT<<<gt(512, 512), 256, 0, stream>>>(Wk + (size_t)l * 262144, Wscr + 262144, 512, 512);
        k_castT<<<gt(512, 512), 256, 0, stream>>>(Wv + (size_t)l * 262144, Wscr + 524288, 512, 512);
        k_castT<<<gt(512, 512), 256, 0, stream>>>(Wo + (size_t)l * 262144, Wscr + 786432, 512, 512);
        hipMemcpyAsync(bqkv,        bq + l * 512, 2048, hipMemcpyDeviceToDevice, stream);
        hipMemcpyAsync(bqkv + 512,  bk + l * 512, 2048, hipMemcpyDeviceToDevice, stream);
        hipMemcpyAsync(bqkv + 1024, bv + l * 512, 2048, hipMemcpyDeviceToDevice, stream);
        k_gemm_mfma2<64, false, ushort_t><<<gm64(4096, 1536), 256, 0, stream>>>(4096, 1536, 512, 512, Hb, Wscr, QKVb, 1536, bqkv);
        k_transposeV<<<dim3(16, 128, 1), 256, 0, stream>>>(QKVb + 1024, 1536, VTg);
        k_flash<<<dim3(64, 4, 2), 256, 0, stream>>>(QKVb, 1536, QKVb + 512, 1536, VTg, OP, Mp, Lp);
        k_fcomb<<<8192, 256, 0, stream>>>(OP, Mp, Lp, Ob);
        k_gemm_mfma2<64, false, float><<<gm64(4096, 512), 256, 0, stream>>>(4096, 512, 512, 512, Ob, Wscr + 786432, T, 512, bo + l * 512);
        k_add_ln<<<4096, 256, 0, stream>>>(H, T, H, Hb, ln1g + l * 512, ln1b + l * 512);
        k_castT<<<gt(512, 2048), 256, 0, stream>>>(Wff1 + (size_t)l * 1048576, Wscr, 512, 2048);
        k_gemm_mfma2<128, true, ushort_t><<<gm128(4096, 2048), 256, 0, stream>>>(4096, 2048, 512, 512, Hb, Wscr, FFHb, 2048, bff1 + l * 2048);
        k_castT<<<gt(2048, 512), 256, 0, stream>>>(Wff2 + (size_t)l * 1048576, Wscr, 2048, 512);
        k_gemm_mfma2<64, false, float><<<gm64(4096, 512), 256, 0, stream>>>(4096, 512, 2048, 2048, FFHb, Wscr, T, 512, bff2 + l * 512);
        k_add_ln<<<4096, 256, 0, stream>>>(H, T, H, Hb, ln2g + l * 512, ln2b + l * 512);
    }

    // 4. seq = mean(H) @ Wproj + bproj   (exact linearity; parallel matvec)
    k_colmean<<<512, 256, 0, stream>>>(H, 4096, 512, hmean);
    k_matvec20<<<20, 256, 0, stream>>>(512, 1.0f, hmean, Wproj, bproj, seqv);

    // 5. protein GCN (bitmap SpMM wave-parallel + degree-trick tail)
    hipMemsetAsync(ADJB, 0, (size_t)4096 * 128 * 4, stream);
    hipMemsetAsync(deg, 0, 4096 * 4, stream);
    k_scatter_bits<<<256, 256, 0, stream>>>(edge_index, ADJB);
    k_spmm_wave<20, 1><<<1024, 256, 0, stream>>>(ADJB, Xoh, 20, pt0, 20);
    k_gemm_nn<true ><<<g2(4096, 128), 256, 0, stream>>>(4096, 128, 20, pt0, 20, gW1, 128, ph1, 128, gb1);
    k_spmm_wave<32, 4><<<4096, 256, 0, stream>>>(ADJB, ph1, 128, pt1, 128);
    k_gemm_nn<true ><<<g2(4096, 64), 256, 0, stream>>>(4096, 64, 128, pt1, 128, gW2, 64, ph2, 64, gb2);
    k_degree<<<2048, 256, 0, stream>>>(ADJB, deg);
    k_wcolsum<<<64, 256, 0, stream>>>(ph2, 4096, 64, deg, wsum);
    k_matvec20<<<20, 256, 0, stream>>>(64, 1.0f / 4096.0f, wsum, gW3, gb3, protv);

    // 6. fusion head
    k_fusion<<<1, 128, 0, stream>>>(subv, protv, seqv, Wtime, btime, Woutw, boutw, t_ptr, lo_ptr, out);
}

// Round 15
// 869.984 us; speedup vs baseline: 10.8003x; 1.0907x over previous
//
#include <hip/hip_runtime.h>
#include <math.h>

typedef unsigned short ushort_t;
typedef __attribute__((ext_vector_type(8))) short bf16x8;
typedef __attribute__((ext_vector_type(4))) float f32x4;

// ---------- helpers ----------
__device__ inline float bf2f(unsigned u) { return __uint_as_float((u & 0xffffu) << 16); }
__device__ inline ushort_t f2bf(float f) {
    unsigned u = __float_as_uint(f);
    return (ushort_t)((u + 0x7fffu + ((u >> 16) & 1u)) >> 16);   // RNE
}
__device__ inline void stv(float* p, float v) { *p = v; }
__device__ inline void stv(ushort_t* p, float v) { *p = f2bf(v); }
__device__ inline int guard_int(int raw, int lo, int hi) {
    if (raw >= lo && raw <= hi) return raw;
    float f = __int_as_float(raw);
    int v = (int)f;
    return (v >= lo && v <= hi) ? v : lo;
}

// ---------- threefry2x32 (JAX partitionable, verified R7) ----------
__device__ inline void tf2x32(unsigned k0, unsigned k1, unsigned x0, unsigned x1,
                              unsigned& o0, unsigned& o1) {
    unsigned ks2 = k0 ^ k1 ^ 0x1BD11BDAu;
    x0 += k0; x1 += k1;
#define TFR(r) { x0 += x1; x1 = (x1 << (r)) | (x1 >> (32 - (r))); x1 ^= x0; }
    TFR(13) TFR(15) TFR(26) TFR(6)  x0 += k1;  x1 += ks2 + 1u;
    TFR(17) TFR(29) TFR(16) TFR(24) x0 += ks2; x1 += k0 + 2u;
    TFR(13) TFR(15) TFR(26) TFR(6)  x0 += k0;  x1 += k1 + 3u;
    TFR(17) TFR(29) TFR(16) TFR(24) x0 += k1;  x1 += ks2 + 4u;
    TFR(13) TFR(15) TFR(26) TFR(6)  x0 += ks2; x1 += k0 + 5u;
#undef TFR
    o0 = x0; o1 = x1;
}

__global__ void k_sentinel(float* __restrict__ out, float val, int n) {
    int i = blockIdx.x * 128 + threadIdx.x;
    if (i < n) out[i] = val;
}

// ---------- diffusion categorical sampling -> one-hot X ----------
__global__ __launch_bounds__(256) void k_sample(const float* __restrict__ x,
                                                const int* __restrict__ t_ptr,
                                                float* __restrict__ X) {
    int i = blockIdx.x * 256 + threadIdx.x;
    if (i >= 4096) return;
    int tval = guard_int(t_ptr[0], 0, 500);
    double tf = (double)tval / 500.0;
    const double sc = 0.008;
    const double PI_HALF = 1.5707963267948966;
    double num = cos((tf + sc) / (1.0 + sc) * PI_HALF);
    double den = cos(sc / (1.0 + sc) * PI_HALF);
    float ab = (float)((num * num) / (den * den));
    float phi = (1.0f - ab) / 20.0f;
    float xv[20]; float sx = 0.f;
    for (int j = 0; j < 20; ++j) { xv[j] = x[i * 20 + j]; sx += xv[j]; }
    float best = -1e30f; int bj = 0;
    for (int j = 0; j < 20; ++j) {
        float prob = fmaxf(ab * xv[j] + phi * sx, 0.0f);
        float lp = logf(prob + 1e-9f);
        unsigned m = (unsigned)(i * 20 + j);
        unsigned o0, o1;
        tf2x32(0u, 42u, 0u, m, o0, o1);
        unsigned bits = o0 ^ o1;
        float u = __uint_as_float((bits >> 9) | 0x3f800000u) - 1.0f;
        if (u < 1.1754943508222875e-38f) u = 1.1754943508222875e-38f;
        float gmb = -logf(-logf(u));
        float z = lp + gmb;
        if (z > best) { best = z; bj = j; }
    }
    for (int j = 0; j < 20; ++j) X[i * 20 + j] = (j == bj) ? 1.0f : 0.0f;
}

// ---------- small utility kernels ----------
__global__ __launch_bounds__(256) void k_gather_fp(const float* __restrict__ emb,
                                                   const int* __restrict__ idx,
                                                   float* __restrict__ out) {
    int i = blockIdx.x * 256 + threadIdx.x;
    if (i >= 256 * 20) return;
    int a = i / 20, d = i % 20;
    out[i] = emb[(size_t)idx[a] * 20 + d];
}

__global__ __launch_bounds__(256) void k_scatter_bits(const int* __restrict__ ei,
                                                      unsigned* __restrict__ bits) {
    int e = blockIdx.x * 256 + threadIdx.x;
    if (e >= 65536) return;
    int r = ei[e], c = ei[65536 + e];
    atomicOr(&bits[(size_t)r * 128 + (c >> 5)], 1u << (c & 31));
}

__global__ __launch_bounds__(256) void k_degree(const unsigned* __restrict__ BITS,
                                                float* __restrict__ deg) {
    int i = blockIdx.x * 256 + threadIdx.x;
    if (i >= 4096 * 128) return;
    unsigned bits = BITS[i];
    int base = (i & 127) * 32;
    while (bits) { int b = __ffs(bits) - 1; bits &= bits - 1; atomicAdd(&deg[base + b], 1.0f); }
}

__global__ __launch_bounds__(256) void k_embed(const float* __restrict__ embw,
                                               const int* __restrict__ words,
                                               float* __restrict__ H,
                                               ushort_t* __restrict__ Hb) {
    int idx = blockIdx.x * 256 + threadIdx.x;
    if (idx >= 4096 * 512) return;
    int pos = idx >> 9, d = idx & 511;
    float e = embw[(size_t)words[pos] * 512 + d];
    float expo = (float)(d >> 1) * (1.0f / 256.0f);
    float ang = (float)pos * exp2f(-expo * 13.287712379549449f);
    float pe = (d & 1) ? cosf(ang) : sinf(ang);
    float v = e + pe;
    H[idx] = v; Hb[idx] = f2bf(v);
}

__global__ __launch_bounds__(256) void k_colmean(const float* __restrict__ M, int R, int C,
                                                 float* __restrict__ out) {
    __shared__ float red[256];
    int c = blockIdx.x, t = threadIdx.x;
    float s = 0.f;
    for (int r = t; r < R; r += 256) s += M[(size_t)r * C + c];
    red[t] = s; __syncthreads();
    for (int o = 128; o; o >>= 1) { if (t < o) red[t] += red[t + o]; __syncthreads(); }
    if (t == 0) out[c] = red[0] / (float)R;
}

__global__ __launch_bounds__(256) void k_wcolsum(const float* __restrict__ M, int R, int C,
                                                 const float* __restrict__ w,
                                                 float* __restrict__ out) {
    __shared__ float red[256];
    int c = blockIdx.x, t = threadIdx.x;
    float s = 0.f;
    for (int r = t; r < R; r += 256) s += w[r] * M[(size_t)r * C + c];
    red[t] = s; __syncthreads();
    for (int o = 128; o; o >>= 1) { if (t < o) red[t] += red[t + o]; __syncthreads(); }
    if (t == 0) out[c] = red[0];
}

// parallel matvec: block c -> out[c] = scale*(vec . W[:,c]) + bias[c]
__global__ __launch_bounds__(256) void k_matvec20(int D, float scale,
                                                  const float* __restrict__ vec,
                                                  const float* __restrict__ W,
                                                  const float* __restrict__ bias,
                                                  float* __restrict__ out) {
    __shared__ float red[256];
    int c = blockIdx.x, t = threadIdx.x;
    float s = 0.f;
    for (int d = t; d < D; d += 256) s += vec[d] * W[(size_t)d * 20 + c];
    red[t] = s; __syncthreads();
    for (int o = 128; o; o >>= 1) { if (t < o) red[t] += red[t + o]; __syncthreads(); }
    if (t == 0) out[c] = red[0] * scale + bias[c];
}

// gather 3 bias vectors into contiguous bqkv[1536]
__global__ void k_gather3(const float* __restrict__ a, const float* __restrict__ b,
                          const float* __restrict__ c, float* __restrict__ out) {
    int i = blockIdx.x * 256 + threadIdx.x;
    if (i >= 1536) return;
    out[i] = (i < 512) ? a[i] : (i < 1024) ? b[i - 512] : c[i - 1024];
}

// ---------- weight cast+transpose: fp32 [K,N] -> bf16 [N,K] ----------
__global__ __launch_bounds__(256) void k_castT(const float* __restrict__ in,
                                               ushort_t* __restrict__ out,
                                               int Kd, int Nd) {
    __shared__ float t[32][33];
    int bx = blockIdx.x * 32, by = blockIdx.y * 32;
    int tx = threadIdx.x & 31, ty = threadIdx.x >> 5;
#pragma unroll
    for (int i = 0; i < 4; ++i)
        t[ty + i * 8][tx] = in[(size_t)(by + ty + i * 8) * Nd + bx + tx];
    __syncthreads();
#pragma unroll
    for (int i = 0; i < 4; ++i)
        out[(size_t)(bx + ty + i * 8) * Kd + by + tx] = f2bf(t[tx][ty + i * 8]);
}

// batched: 4x [512,512] fp32 -> bf16 [512,512] transposed, z selects matrix
__global__ __launch_bounds__(256) void k_castT4(const float* __restrict__ in0,
                                                const float* __restrict__ in1,
                                                const float* __restrict__ in2,
                                                const float* __restrict__ in3,
                                                ushort_t* __restrict__ out) {
    __shared__ float t[32][33];
    int z = blockIdx.z;
    const float* in = (z == 0) ? in0 : (z == 1) ? in1 : (z == 2) ? in2 : in3;
    ushort_t* o = out + (size_t)z * 262144;
    int bx = blockIdx.x * 32, by = blockIdx.y * 32;
    int tx = threadIdx.x & 31, ty = threadIdx.x >> 5;
#pragma unroll
    for (int i = 0; i < 4; ++i)
        t[ty + i * 8][tx] = in[(size_t)(by + ty + i * 8) * 512 + bx + tx];
    __syncthreads();
#pragma unroll
    for (int i = 0; i < 4; ++i)
        o[(size_t)(bx + ty + i * 8) * 512 + by + tx] = f2bf(t[tx][ty + i * 8]);
}

// ---------- bf16 transpose: in [4096][ld] (512-col slice) -> out [512][4096] ----------
__global__ __launch_bounds__(256) void k_transposeV(const ushort_t* __restrict__ in, int ldin,
                                                    ushort_t* __restrict__ out) {
    __shared__ ushort_t t[32][33];
    int bx = blockIdx.x * 32;
    int by = blockIdx.y * 32;
    int tx = threadIdx.x & 31, ty = threadIdx.x >> 5;
#pragma unroll
    for (int i = 0; i < 4; ++i)
        t[ty + i * 8][tx] = in[(size_t)(by + ty + i * 8) * ldin + bx + tx];
    __syncthreads();
#pragma unroll
    for (int i = 0; i < 4; ++i)
        out[(size_t)(bx + ty + i * 8) * 4096 + by + tx] = t[tx][ty + i * 8];
}

// ---------- MFMA bf16 GEMM: BM=128 x BN tile ----------
template<int BN, bool RELU, typename TC>
__global__ __launch_bounds__(256) void k_gemm_mfma2(int M, int N, int K, int lda,
        const ushort_t* __restrict__ A,
        const ushort_t* __restrict__ Bt,
        TC* __restrict__ C, int ldc,
        const float* __restrict__ bias) {
    constexpr int NJ = BN / 32;
    __shared__ ushort_t As[128][40];
    __shared__ ushort_t Bs[BN][40];
    int tid = threadIdx.x;
    int lane = tid & 63, wave = tid >> 6;
    int wr = wave >> 1, wc = wave & 1;
    int lrow = lane & 15, lq = lane >> 4;
    int br = blockIdx.y * 128, bc = blockIdx.x * BN;
    f32x4 acc[4][NJ];
#pragma unroll
    for (int i = 0; i < 4; ++i)
#pragma unroll
        for (int j = 0; j < NJ; ++j) { acc[i][j][0] = 0.f; acc[i][j][1] = 0.f; acc[i][j][2] = 0.f; acc[i][j][3] = 0.f; }
    int sr = tid >> 2, sseg = tid & 3;
    for (int k0 = 0; k0 < K; k0 += 32) {
#pragma unroll
        for (int it = 0; it < 2; ++it)
            *(uint4*)&As[sr + it * 64][sseg * 8] = *(const uint4*)&A[(size_t)(br + sr + it * 64) * lda + k0 + sseg * 8];
#pragma unroll
        for (int it = 0; it < BN / 64; ++it)
            *(uint4*)&Bs[sr + it * 64][sseg * 8] = *(const uint4*)&Bt[(size_t)(bc + sr + it * 64) * K + k0 + sseg * 8];
        __syncthreads();
        bf16x8 af[4], bfr[NJ];
#pragma unroll
        for (int i = 0; i < 4; ++i) af[i] = *(const bf16x8*)&As[wr * 64 + i * 16 + lrow][lq * 8];
#pragma unroll
        for (int j = 0; j < NJ; ++j) bfr[j] = *(const bf16x8*)&Bs[wc * (BN / 2) + j * 16 + lrow][lq * 8];
#pragma unroll
        for (int i = 0; i < 4; ++i)
#pragma unroll
            for (int j = 0; j < NJ; ++j)
                acc[i][j] = __builtin_amdgcn_mfma_f32_16x16x32_bf16(af[i], bfr[j], acc[i][j], 0, 0, 0);
        __syncthreads();
    }
#pragma unroll
    for (int i = 0; i < 4; ++i)
#pragma unroll
        for (int j = 0; j < NJ; ++j) {
            int col = bc + wc * (BN / 2) + j * 16 + lrow;
            float bv = bias ? bias[col] : 0.f;
#pragma unroll
            for (int r = 0; r < 4; ++r) {
                int row = br + wr * 64 + i * 16 + lq * 4 + r;
                float v = acc[i][j][r] + bv;
                if (RELU) v = fmaxf(v, 0.f);
                stv(&C[(size_t)row * ldc + col], v);
            }
        }
}

// ---------- fp32 GEMM (small/odd shapes) ----------
template<bool RELU>
__global__ __launch_bounds__(256) void k_gemm_nn(int M, int N, int K,
        const float* __restrict__ A, int lda,
        const float* __restrict__ B, int ldb,
        float* __restrict__ C, int ldc,
        const float* __restrict__ bias) {
    __shared__ float As[16][65];
    __shared__ float Bs[16][65];
    int tid = threadIdx.x;
    int tx = tid & 15, ty = tid >> 4;
    int br = blockIdx.y * 64, bc = blockIdx.x * 64;
    float acc[4][4] = {};
    for (int k0 = 0; k0 < K; k0 += 16) {
#pragma unroll
        for (int c0 = 0; c0 < 4; ++c0) {
            int r = (tid >> 4) + c0 * 16, kk = tid & 15;
            int gr = br + r, gk = k0 + kk;
            As[kk][r] = (gr < M && gk < K) ? A[(size_t)gr * lda + gk] : 0.f;
        }
#pragma unroll
        for (int c0 = 0; c0 < 4; ++c0) {
            int col = tid & 63, kk = (tid >> 6) + c0 * 4;
            int gc = bc + col, gk = k0 + kk;
            Bs[kk][col] = (gc < N && gk < K) ? B[(size_t)gk * ldb + gc] : 0.f;
        }
        __syncthreads();
#pragma unroll
        for (int kk = 0; kk < 16; ++kk) {
            float av[4], bv[4];
#pragma unroll
            for (int i2 = 0; i2 < 4; ++i2) av[i2] = As[kk][ty + 16 * i2];
#pragma unroll
            for (int j2 = 0; j2 < 4; ++j2) bv[j2] = Bs[kk][tx + 16 * j2];
#pragma unroll
            for (int i2 = 0; i2 < 4; ++i2)
#pragma unroll
                for (int j2 = 0; j2 < 4; ++j2) acc[i2][j2] += av[i2] * bv[j2];
        }
        __syncthreads();
    }
#pragma unroll
    for (int i2 = 0; i2 < 4; ++i2)
#pragma unroll
        for (int j2 = 0; j2 < 4; ++j2) {
            int r = br + ty + 16 * i2, c = bc + tx + 16 * j2;
            if (r < M && c < N) {
                float v = acc[i2][j2];
                if (bias) v += bias[c];
                if (RELU) v = fmaxf(v, 0.f);
                C[(size_t)r * ldc + c] = v;
            }
        }
}

// ---------- SpMM wave-per-(row,chunk) ----------
template<int NC, int CH>
__global__ __launch_bounds__(256) void k_spmm_wave(
        const unsigned* __restrict__ BITS,
        const float* __restrict__ B, int ldb,
        float* __restrict__ C, int ldc) {
    int gw = blockIdx.x * 4 + (threadIdx.x >> 6);
    int lane = threadIdx.x & 63;
    int row = gw / CH, cb = (gw % CH) * NC;
    if (row >= 4096) return;
    float acc[NC];
#pragma unroll
    for (int j = 0; j < NC; ++j) acc[j] = 0.f;
    const unsigned* bw = &BITS[(size_t)row * 128];
#pragma unroll
    for (int i = 0; i < 2; ++i) {
        int wd = lane * 2 + i;
        unsigned bits = bw[wd];
        int base = wd * 32;
        while (bits) {
            int b = __ffs(bits) - 1; bits &= bits - 1;
            const float* br = &B[(size_t)(base + b) * ldb + cb];
#pragma unroll
            for (int j = 0; j < NC; ++j) acc[j] += br[j];
        }
    }
#pragma unroll
    for (int j = 0; j < NC; ++j) {
#pragma unroll
        for (int off = 1; off < 64; off <<= 1) acc[j] += __shfl_xor(acc[j], off, 64);
    }
    if (lane == 0)
#pragma unroll
        for (int j = 0; j < NC; ++j) C[(size_t)row * ldc + cb + j] = acc[j];
}

// ---------- MFMA flash: split-K z=3 (43/43/42 tiles), rescale-skip ----------
__global__ __launch_bounds__(256) void k_flash(const ushort_t* __restrict__ Qg, int ldq,
                                               const ushort_t* __restrict__ Kg, int ldk,
                                               const ushort_t* __restrict__ VTg,
                                               ushort_t* __restrict__ OP0,
                                               ushort_t* __restrict__ OP12,
                                               float* __restrict__ Mp,
                                               float* __restrict__ Lp) {
    __shared__ ushort_t Ks[32][136];
    __shared__ ushort_t Vt[128][40];
    __shared__ ushort_t Ps[4][16][40];
    __shared__ float    as_[4][16];
    __shared__ float    ls_[4][16];
    const int tid = threadIdx.x;
    const int lane = tid & 63, wid = tid >> 6;
    const int lrow = lane & 15, lq = lane >> 4;
    const int qb = blockIdx.x * 64, hh = blockIdx.y, z = blockIdx.z;
    const int kt0 = z * 43, kt1 = (z == 2) ? 128 : kt0 + 43;
    const float scale = 0.08838834764831845f;   // 1/sqrt(128)
    bf16x8 qf[4];
    {
        const ushort_t* qrow = &Qg[(size_t)(qb + wid * 16 + lrow) * ldq + hh * 128 + lq * 8];
#pragma unroll
        for (int s = 0; s < 4; ++s) qf[s] = *(const bf16x8*)&qrow[s * 32];
    }
    f32x4 o[8];
#pragma unroll
    for (int ct = 0; ct < 8; ++ct) { o[ct][0] = 0.f; o[ct][1] = 0.f; o[ct][2] = 0.f; o[ct][3] = 0.f; }
    float m = -INFINITY, l = 0.f;
    for (int kt = kt0; kt < kt1; ++kt) {
#pragma unroll
        for (int i = 0; i < 2; ++i) {
            int sid = tid + i * 256;
            int r = sid >> 4, sg = sid & 15;
            *(uint4*)&Ks[r][sg * 8] = *(const uint4*)&Kg[(size_t)(kt * 32 + r) * ldk + hh * 128 + sg * 8];
            int d = sid >> 2, c8 = sid & 3;
            *(uint4*)&Vt[d][c8 * 8] = *(const uint4*)&VTg[(size_t)(hh * 128 + d) * 4096 + kt * 32 + c8 * 8];
        }
        __syncthreads();
        f32x4 sa[2];
#pragma unroll
        for (int c = 0; c < 2; ++c) { sa[c][0] = 0.f; sa[c][1] = 0.f; sa[c][2] = 0.f; sa[c][3] = 0.f; }
#pragma unroll
        for (int c = 0; c < 2; ++c)
#pragma unroll
            for (int st = 0; st < 4; ++st) {
                bf16x8 kf = *(const bf16x8*)&Ks[c * 16 + lrow][st * 32 + lq * 8];
                sa[c] = __builtin_amdgcn_mfma_f32_16x16x32_bf16(kf, qf[st], sa[c], 0, 0, 0);
            }
        float s[8];
        float tm = -INFINITY;
#pragma unroll
        for (int c = 0; c < 2; ++c)
#pragma unroll
            for (int r = 0; r < 4; ++r) { float v = sa[c][r] * scale; s[c * 4 + r] = v; tm = fmaxf(tm, v); }
        tm = fmaxf(tm, __shfl_xor(tm, 16));
        tm = fmaxf(tm, __shfl_xor(tm, 32));
        bool up = tm > m;
        float mn = up ? tm : m;
        float a = up ? __expf(m - mn) : 1.0f;   // first tile: exp(-inf)=0
        float su = 0.f;
        float p[8];
#pragma unroll
        for (int i = 0; i < 8; ++i) { p[i] = __expf(s[i] - mn); su += p[i]; }
        su += __shfl_xor(su, 16);
        su += __shfl_xor(su, 32);
        m = mn; l = l * a + su;
#pragma unroll
        for (int c = 0; c < 2; ++c)
#pragma unroll
            for (int r = 0; r < 4; ++r)
                Ps[wid][lrow][c * 16 + lq * 4 + r] = f2bf(p[c * 4 + r]);
        if (__any(up)) {        // skip O-rescale when no row's max moved (a==1 exact)
            if (lq == 0) as_[wid][lrow] = a;
            __builtin_amdgcn_s_waitcnt(0);
            float av[4];
#pragma unroll
            for (int r = 0; r < 4; ++r) av[r] = as_[wid][lq * 4 + r];
#pragma unroll
            for (int ct = 0; ct < 8; ++ct)
#pragma unroll
                for (int r = 0; r < 4; ++r) o[ct][r] *= av[r];
        } else {
            __builtin_amdgcn_s_waitcnt(0);      // Ps visibility for pf read below
        }
        bf16x8 pf = *(const bf16x8*)&Ps[wid][lrow][lq * 8];
#pragma unroll
        for (int ct = 0; ct < 8; ++ct) {
            bf16x8 vf = *(const bf16x8*)&Vt[ct * 16 + lrow][lq * 8];
            o[ct] = __builtin_amdgcn_mfma_f32_16x16x32_bf16(pf, vf, o[ct], 0, 0, 0);
        }
        __syncthreads();
    }
    if (lq == 0) {
        Mp[(size_t)(z * 4 + hh) * 4096 + qb + wid * 16 + lrow] = m;
        Lp[(size_t)(z * 4 + hh) * 4096 + qb + wid * 16 + lrow] = l;
    }
    ushort_t* ob = (z == 0) ? OP0 : OP12 + (size_t)(z - 1) * 2097152;
#pragma unroll
    for (int ct = 0; ct < 8; ++ct)
#pragma unroll
        for (int r = 0; r < 4; ++r)
            ob[(size_t)(qb + wid * 16 + lq * 4 + r) * 512 + hh * 128 + ct * 16 + lrow] = f2bf(o[ct][r]);
}

// ---------- flash split-K combine (3 partials), in-place over OP0 ----------
__global__ __launch_bounds__(256) void k_fcomb(ushort_t* __restrict__ OP0,
                                               const ushort_t* __restrict__ OP12,
                                               const float* __restrict__ Mp,
                                               const float* __restrict__ Lp) {
    int idx = blockIdx.x * 256 + threadIdx.x;
    if (idx >= 4096 * 512) return;
    int row = idx >> 9, col = idx & 511;
    int hh = col >> 7;
    float m0 = Mp[hh * 4096 + row], m1 = Mp[(4 + hh) * 4096 + row], m2 = Mp[(8 + hh) * 4096 + row];
    float l0 = Lp[hh * 4096 + row], l1 = Lp[(4 + hh) * 4096 + row], l2 = Lp[(8 + hh) * 4096 + row];
    float mm = fmaxf(m0, fmaxf(m1, m2));
    float w0 = __expf(m0 - mm), w1 = __expf(m1 - mm), w2 = __expf(m2 - mm);
    float denom = l0 * w0 + l1 * w1 + l2 * w2;
    float o0 = bf2f(OP0[idx]), o1 = bf2f(OP12[idx]), o2 = bf2f(OP12[2097152 + idx]);
    OP0[idx] = f2bf((o0 * w0 + o1 * w1 + o2 * w2) / denom);
}

// ---------- residual add + layernorm ----------
__global__ __launch_bounds__(256) void k_add_ln(const float* __restrict__ A,
                                                const float* __restrict__ B,
                                                float* __restrict__ O,
                                                ushort_t* __restrict__ Ob,
                                                const float* __restrict__ g,
                                                const float* __restrict__ b) {
    __shared__ float xr[512];
    __shared__ float red[256];
    int row = blockIdx.x, t = threadIdx.x;
    const float* a = A + (size_t)row * 512;
    const float* bb = B + (size_t)row * 512;
    float ls = 0.f;
    for (int j = t; j < 512; j += 256) { float v = a[j] + bb[j]; xr[j] = v; ls += v; }
    red[t] = ls; __syncthreads();
    for (int o = 128; o; o >>= 1) { if (t < o) red[t] += red[t + o]; __syncthreads(); }
    float mean = red[0] / 512.0f; __syncthreads();
    float lv = 0.f;
    for (int j = t; j < 512; j += 256) { float d = xr[j] - mean; lv += d * d; }
    red[t] = lv; __syncthreads();
    for (int o = 128; o; o >>= 1) { if (t < o) red[t] += red[t + o]; __syncthreads(); }
    float inv = 1.0f / sqrtf(red[0] / 512.0f + 1e-5f);
    float* o_ = O + (size_t)row * 512;
    ushort_t* ob = Ob + (size_t)row * 512;
    for (int j = t; j < 512; j += 256) {
        float v = (xr[j] - mean) * inv * g[j] + b[j];
        o_[j] = v; ob[j] = f2bf(v);
    }
}

// ---------- fusion head ----------
__global__ __launch_bounds__(128) void k_fusion(const float* __restrict__ subv,
                                                const float* __restrict__ protv,
                                                const float* __restrict__ seqv,
                                                const float* __restrict__ Wtime,
                                                const float* __restrict__ btime,
                                                const float* __restrict__ Wout,
                                                const float* __restrict__ bout,
                                                const int* __restrict__ t_ptr,
                                                const int* __restrict__ lo_ptr,
                                                float* __restrict__ out) {
    __shared__ float cat[80];
    int t = threadIdx.x;
    int tval = guard_int(t_ptr[0], 0, 500);
    int L    = guard_int(lo_ptr[0], 0, 3);
    float tf = (float)((double)tval / 500.0);
    if (t < 20) {
        cat[t] = subv[t];
        cat[20 + t] = protv[t];
        cat[40 + t] = seqv[t];
        cat[60 + t] = tf * Wtime[t] + btime[t];
    }
    __syncthreads();
    for (int j = 0; j < L; ++j) {
        float acc = 0.f;
        if (t < 80) {
            for (int i2 = 0; i2 < 80; ++i2)
                acc += fmaxf(cat[i2], 0.f) * Wout[(size_t)j * 6400 + i2 * 80 + t];
            acc += bout[j * 80 + t];
        }
        __syncthreads();
        if (t < 80) cat[t] = acc;
        __syncthreads();
    }
    if (t < 80) out[t] = fmaxf(cat[t], 0.f);
    if (t < 20) out[80 + t] = seqv[t];
}

// ---------- launch ----------
extern "C" void kernel_launch(void* const* d_in, const int* in_sizes, int n_in,
                              void* d_out, int out_size, void* d_ws, size_t ws_size,
                              hipStream_t stream) {
    static const int EXP[39] = {
        81920, 65536, 200000, 2097152, 2560, 128, 8192, 64, 1280, 20,
        524288, 1024, 524288, 1024, 524288, 1024, 524288, 1024, 1024, 1024,
        2097152, 4096, 2097152, 1024, 1024, 1024, 10240, 20, 19200, 240,
        20, 20, 256, 4096, 4096, 131072, 1, 1, 1 };
    float code = 0.f;
    if (n_in != 39) code = 900.f;
    else {
        for (int i = 0; i < 39; ++i)
            if (in_sizes[i] != EXP[i]) { code = 500.f + 4.f * (float)i; break; }
    }
    const size_t REQ = (size_t)46 * 1024 * 1024;
    if (code == 0.f && ws_size < REQ) code = (float)(ws_size >> 20);
    float* out = (float*)d_out;
    if (code != 0.f) {
        k_sentinel<<<1, 128, 0, stream>>>(out, -code, out_size);
        return;
    }

    const float* x_in   = (const float*)d_in[0];
    const float* adjs_in= (const float*)d_in[1];
    const float* embfp  = (const float*)d_in[2];
    const float* embw   = (const float*)d_in[3];
    const float* gW1 = (const float*)d_in[4];  const float* gb1 = (const float*)d_in[5];
    const float* gW2 = (const float*)d_in[6];  const float* gb2 = (const float*)d_in[7];
    const float* gW3 = (const float*)d_in[8];  const float* gb3 = (const float*)d_in[9];
    const float* Wq  = (const float*)d_in[10]; const float* bq  = (const float*)d_in[11];
    const float* Wk  = (const float*)d_in[12]; const float* bk  = (const float*)d_in[13];
    const float* Wv  = (const float*)d_in[14]; const float* bv  = (const float*)d_in[15];
    const float* Wo  = (const float*)d_in[16]; const float* bo  = (const float*)d_in[17];
    const float* ln1g= (const float*)d_in[18]; const float* ln1b= (const float*)d_in[19];
    const float* Wff1= (const float*)d_in[20]; const float* bff1= (const float*)d_in[21];
    const float* Wff2= (const float*)d_in[22]; const float* bff2= (const float*)d_in[23];
    const float* ln2g= (const float*)d_in[24]; const float* ln2b= (const float*)d_in[25];
    const float* Wproj=(const float*)d_in[26]; const float* bproj=(const float*)d_in[27];
    const float* Woutw=(const float*)d_in[28]; const float* boutw=(const float*)d_in[29];
    const float* Wtime=(const float*)d_in[30]; const float* btime=(const float*)d_in[31];
    const int* fingerprints = (const int*)d_in[32];
    const int* words        = (const int*)d_in[33];
    const int* edge_index   = (const int*)d_in[35];
    const int* t_ptr        = (const int*)d_in[36];
    const int* lo_ptr       = (const int*)d_in[37];

    // ---- workspace (46 MiB) ----
    char* wsb = (char*)d_ws;
    float*    misc = (float*)wsb;
    float*    H    = (float*)(wsb + ((size_t)2  << 20));
    ushort_t* Hb   = (ushort_t*)(wsb + ((size_t)10 << 20));
    ushort_t* QKVb = (ushort_t*)(wsb + ((size_t)14 << 20));
    ushort_t* Ob   = (ushort_t*)(wsb + ((size_t)26 << 20));   // also flash partial z=0
    ushort_t* FFHb = (ushort_t*)(wsb + ((size_t)14 << 20));
    float*    T    = (float*)(wsb + ((size_t)30 << 20));
    ushort_t* OP12 = (ushort_t*)(wsb + ((size_t)30 << 20));   // partials z=1,2 (alias T)
    ushort_t* Wscr = (ushort_t*)(wsb + ((size_t)38 << 20));
    ushort_t* VTg  = (ushort_t*)(wsb + ((size_t)42 << 20));
    unsigned* ADJB = (unsigned*)(wsb + ((size_t)26 << 20));
    float* pt0  = (float*)(wsb + ((size_t)14 << 20));
    float* ph1  = pt0 + 81920;
    float* pt1  = ph1 + 524288;
    float* ph2  = pt1 + 524288;
    float* Xoh  = misc;
    float* fpv  = misc + 81920;
    float* st0  = misc + 87040;
    float* sh1  = misc + 92160;
    float* st1  = misc + 124928;
    float* sh2  = misc + 157696;
    float* st2  = misc + 174080;
    float* sgo  = misc + 190464;
    float* subv = misc + 277504;
    float* protv= misc + 277536;
    float* seqv = misc + 277568;
    float* hmean= misc + 280000;
    float* wsum = misc + 281000;
    float* deg  = misc + 282000;
    float* bqkv = misc + 287000;
    float* Mp   = misc + 300000;     // 12*4096 = 49152 floats
    float* Lp   = misc + 360000;     // 49152 floats

    auto g2 = [](int M, int N) { return dim3((unsigned)((N + 63) / 64), (unsigned)((M + 63) / 64), 1); };
    auto gm64  = [](int M, int N) { return dim3((unsigned)(N / 64), (unsigned)(M / 128), 1); };
    auto gm128 = [](int M, int N) { return dim3((unsigned)(N / 128), (unsigned)(M / 128), 1); };
    auto gt = [](int Kd, int Nd) { return dim3((unsigned)(Nd / 32), (unsigned)(Kd / 32), 1); };

    // 1. diffusion sampling
    k_sample<<<16, 256, 0, stream>>>(x_in, t_ptr, Xoh);

    // 2. substrate GCN (fp32, small)
    k_gather_fp<<<20, 256, 0, stream>>>(embfp, fingerprints, fpv);
    k_gemm_nn<false><<<g2(256, 20), 256, 0, stream>>>(256, 20, 256, adjs_in, 256, fpv, 20, st0, 20, nullptr);
    k_gemm_nn<true ><<<g2(256, 128), 256, 0, stream>>>(256, 128, 20, st0, 20, gW1, 128, sh1, 128, gb1);
    k_gemm_nn<false><<<g2(256, 128), 256, 0, stream>>>(256, 128, 256, adjs_in, 256, sh1, 128, st1, 128, nullptr);
    k_gemm_nn<true ><<<g2(256, 64), 256, 0, stream>>>(256, 64, 128, st1, 128, gW2, 64, sh2, 64, gb2);
    k_gemm_nn<false><<<g2(256, 64), 256, 0, stream>>>(256, 64, 256, adjs_in, 256, sh2, 64, st2, 64, nullptr);
    k_gemm_nn<false><<<g2(256, 20), 256, 0, stream>>>(256, 20, 64, st2, 64, gW3, 20, sgo, 20, gb3);
    k_colmean<<<20, 256, 0, stream>>>(sgo, 256, 20, subv);

    // 3. transformer
    k_embed<<<8192, 256, 0, stream>>>(embw, words, H, Hb);
    for (int l = 0; l < 2; ++l) {
        k_castT4<<<dim3(16, 16, 4), 256, 0, stream>>>(Wq + (size_t)l * 262144, Wk + (size_t)l * 262144,
                                                      Wv + (size_t)l * 262144, Wo + (size_t)l * 262144, Wscr);
        k_gather3<<<6, 256, 0, stream>>>(bq + l * 512, bk + l * 512, bv + l * 512, bqkv);
        k_gemm_mfma2<64, false, ushort_t><<<gm64(4096, 1536), 256, 0, stream>>>(4096, 1536, 512, 512, Hb, Wscr, QKVb, 1536, bqkv);
        k_transposeV<<<dim3(16, 128, 1), 256, 0, stream>>>(QKVb + 1024, 1536, VTg);
        k_flash<<<dim3(64, 4, 3), 256, 0, stream>>>(QKVb, 1536, QKVb + 512, 1536, VTg, Ob, OP12, Mp, Lp);
        k_fcomb<<<8192, 256, 0, stream>>>(Ob, OP12, Mp, Lp);
        k_gemm_mfma2<64, false, float><<<gm64(4096, 512), 256, 0, stream>>>(4096, 512, 512, 512, Ob, Wscr + 786432, T, 512, bo + l * 512);
        k_add_ln<<<4096, 256, 0, stream>>>(H, T, H, Hb, ln1g + l * 512, ln1b + l * 512);
        k_castT<<<gt(512, 2048), 256, 0, stream>>>(Wff1 + (size_t)l * 1048576, Wscr, 512, 2048);
        k_gemm_mfma2<128, true, ushort_t><<<gm128(4096, 2048), 256, 0, stream>>>(4096, 2048, 512, 512, Hb, Wscr, FFHb, 2048, bff1 + l * 2048);
        k_castT<<<gt(2048, 512), 256, 0, stream>>>(Wff2 + (size_t)l * 1048576, Wscr, 2048, 512);
        k_gemm_mfma2<64, false, float><<<gm64(4096, 512), 256, 0, stream>>>(4096, 512, 2048, 2048, FFHb, Wscr, T, 512, bff2 + l * 512);
        k_add_ln<<<4096, 256, 0, stream>>>(H, T, H, Hb, ln2g + l * 512, ln2b + l * 512);
    }

    // 4. seq = mean(H) @ Wproj + bproj
    k_colmean<<<512, 256, 0, stream>>>(H, 4096, 512, hmean);
    k_matvec20<<<20, 256, 0, stream>>>(512, 1.0f, hmean, Wproj, bproj, seqv);

    // 5. protein GCN
    hipMemsetAsync(ADJB, 0, (size_t)4096 * 128 * 4, stream);
    hipMemsetAsync(deg, 0, 4096 * 4, stream);
    k_scatter_bits<<<256, 256, 0, stream>>>(edge_index, ADJB);
    k_spmm_wave<20, 1><<<1024, 256, 0, stream>>>(ADJB, Xoh, 20, pt0, 20);
    k_gemm_nn<true ><<<g2(4096, 128), 256, 0, stream>>>(4096, 128, 20, pt0, 20, gW1, 128, ph1, 128, gb1);
    k_spmm_wave<32, 4><<<4096, 256, 0, stream>>>(ADJB, ph1, 128, pt1, 128);
    k_gemm_nn<true ><<<g2(4096, 64), 256, 0, stream>>>(4096, 64, 128, pt1, 128, gW2, 64, ph2, 64, gb2);
    k_degree<<<2048, 256, 0, stream>>>(ADJB, deg);
    k_wcolsum<<<64, 256, 0, stream>>>(ph2, 4096, 64, deg, wsum);
    k_matvec20<<<20, 256, 0, stream>>>(64, 1.0f / 4096.0f, wsum, gW3, gb3, protv);

    // 6. fusion head
    k_fusion<<<1, 128, 0, stream>>>(subv, protv, seqv, Wtime, btime, Woutw, boutw, t_ptr, lo_ptr, out);
}